// Round 2
// baseline (864.453 us; speedup 1.0000x reference)
//
#include <hip/hip_runtime.h>
#include <stdint.h>

#define NN 50000
#define EE 800000
#define FIN 256
#define HD 128
#define DD 32
#define KK 25000
#define SLOPEF 0.4f
#define NEGF (-1e9f)
#define ATT_OFF 34
#define STR_OFF (34 + EE * 4)
#define CW 128             // LDS-cached edges per node (deg ~Poisson(16); recompute fallback)

// atomic-free CSR build: 64 node-ranges x 4 edge-chunks, LDS counting only
#define NCB 64             // node-range blocks
#define ECB 4              // edge chunks
#define CH0 782            // ceil(NN/NCB)
#define CH1 391            // ceil(KK/NCB)
#define ECHUNK4 (EE / ECB / 4)   // int4s per edge chunk = 50000

// ---------- helpers ----------
__device__ __forceinline__ unsigned fkey(float x) {
    unsigned u = __float_as_uint(x);
    return (u & 0x80000000u) ? ~u : (u | 0x80000000u);   // monotone float->uint
}
__device__ __forceinline__ float unfkey(unsigned k) {
    unsigned u = (k & 0x80000000u) ? (k ^ 0x80000000u) : ~k;
    return __uint_as_float(u);
}
__device__ __forceinline__ float lrelu(float v) { return v > 0.f ? v : SLOPEF * v; }

// ---------- pointer bundle ----------
struct P {
    // inputs
    const float *feature, *strength, *W0, *b0, *al0, *ar0, *Wc0, *bc0;
    const float *W1, *b1, *al1, *ar1, *gW, *gb, *cW, *cb;
    const int *src, *dst;
    // zeroed scratch
    double *Zacc, *racc;
    int *cnt;
    unsigned *gmaxk, *rs;         // rs[0]=pivot key, rs[1]=ties needed, rs[2]=hi bin, rs[3]=hi remaining
    unsigned *binsHi, *binsLo;
    // other scratch
    unsigned *keys;
    int *degc_i, *degc_o, *degc1;  // per-(chunk,node) counts [ECB][n]
    int *ens, *end_;               // slot-mapped edge endpoints (layer 1)
    int *csr_src, *off0, *off1, *sel, *slot, *list, *bsum, *boff;
    float *z0, *el0, *er0, *q4, *m0f, *s0f, *b0wc, *hc, *score, *xk, *z1;
    float *el1, *er1, *m1f, *s1f, *res, *g, *tscale;
    float *out;                    // d_out (float32)
};

// ---------- fp32 tiled GEMM body: C[M,128] = A[M,Kd] @ B[Kd,128] ----------
// ELR epilogue: el/er for this block's 2 heads from acc regs; optional q4.
#define BM 128
#define BN 64
#define BK 16
__device__ void gemm_body(
    const float* __restrict__ A, const float* __restrict__ B, float* __restrict__ C,
    int M, int Kd,
    const float* __restrict__ al, const float* __restrict__ ar,
    float* __restrict__ el, float* __restrict__ er,
    const float* __restrict__ Wc, float* __restrict__ q4,
    int bx, int by) {
    __shared__ float As[BK][BM + 4];
    __shared__ float Bs[BK][BN];
    int bm = by * BM, bn = bx * BN;
    int tid = threadIdx.x;
    int tr = tid >> 4, tc = tid & 15;
    int lrow = tid >> 1;
    int arow = (bm + lrow < M) ? (bm + lrow) : -1;
    float acc[8][4] = {};
    for (int k0 = 0; k0 < Kd; k0 += BK) {
        {
            int col = (tid & 1) << 3;
            float4 v0 = {0.f,0.f,0.f,0.f}, v1 = {0.f,0.f,0.f,0.f};
            if (arow >= 0) {
                const float* ap = A + (size_t)arow * Kd + k0 + col;
                v0 = *(const float4*)ap; v1 = *(const float4*)(ap + 4);
            }
            As[col + 0][lrow] = v0.x; As[col + 1][lrow] = v0.y;
            As[col + 2][lrow] = v0.z; As[col + 3][lrow] = v0.w;
            As[col + 4][lrow] = v1.x; As[col + 5][lrow] = v1.y;
            As[col + 6][lrow] = v1.z; As[col + 7][lrow] = v1.w;
        }
        {
            int kr = tid >> 4, col = (tid & 15) << 2;
            float4 v = *(const float4*)(B + (size_t)(k0 + kr) * HD + bn + col);
            *(float4*)&Bs[kr][col] = v;
        }
        __syncthreads();
#pragma unroll
        for (int kk = 0; kk < BK; kk++) {
            float a[8], b[4];
#pragma unroll
            for (int i = 0; i < 8; i++) a[i] = As[kk][tr * 8 + i];
#pragma unroll
            for (int j = 0; j < 4; j++) b[j] = Bs[kk][tc * 4 + j];
#pragma unroll
            for (int i = 0; i < 8; i++)
#pragma unroll
                for (int j = 0; j < 4; j++) acc[i][j] = fmaf(a[i], b[j], acc[i][j]);
        }
        __syncthreads();
    }
#pragma unroll
    for (int i = 0; i < 8; i++) {
        int gr = bm + tr * 8 + i;
        if (gr < M) {
            float4 v = {acc[i][0], acc[i][1], acc[i][2], acc[i][3]};
            *(float4*)(C + (size_t)gr * HD + bn + tc * 4) = v;
        }
    }
    // epilogue: heads 2*bx, 2*bx+1; 8-lane tree reduce per (row, head)
    int head = bx * 2 + (tc >> 3);
    int dbase = (tc & 7) * 4;
    const float* alh = al + head * 32 + dbase;
    const float* arh = ar + head * 32 + dbase;
    float a0 = alh[0], a1 = alh[1], a2 = alh[2], a3 = alh[3];
    float r0 = arh[0], r1 = arh[1], r2 = arh[2], r3 = arh[3];
    float w0 = 0.f, w1 = 0.f, w2 = 0.f, w3 = 0.f;
    if (Wc) {
        const float* wch = Wc + head * 32 + dbase;
        w0 = wch[0]; w1 = wch[1]; w2 = wch[2]; w3 = wch[3];
    }
#pragma unroll
    for (int i = 0; i < 8; i++) {
        int gr = bm + tr * 8 + i;
        float pe = acc[i][0]*a0 + acc[i][1]*a1 + acc[i][2]*a2 + acc[i][3]*a3;
        float pr = acc[i][0]*r0 + acc[i][1]*r1 + acc[i][2]*r2 + acc[i][3]*r3;
        float pq = acc[i][0]*w0 + acc[i][1]*w1 + acc[i][2]*w2 + acc[i][3]*w3;
#pragma unroll
        for (int o = 1; o < 8; o <<= 1) {
            pe += __shfl_xor(pe, o); pr += __shfl_xor(pr, o); pq += __shfl_xor(pq, o);
        }
        if ((tc & 7) == 0 && gr < M) {
            el[gr * 4 + head] = pe; er[gr * 4 + head] = pr;
            if (Wc) q4[gr * 4 + head] = pq;
        }
    }
}

// ---------- MERGED: gemm0 || atomic-free degree count || b0.Wc0 prep ----------
// Count blocks (r = node range of CH0, c = edge chunk): stream chunk's src/dst
// with int4 loads, LDS-count in-range nodes, store per-(chunk,range) counts
// coalesced. Zero global atomics (R1 showed atomics cost ~write-through, not
// contention).
#define G0B 782            // 2 x 391 gemm blocks
__global__ __launch_bounds__(256) void k_g0deg(P p) {
    int blk = blockIdx.x;
    if (blk < G0B) {
        gemm_body(p.feature, p.W0, p.z0, NN, FIN, p.al0, p.ar0, p.el0, p.er0,
                  p.Wc0, p.q4, blk & 1, blk >> 1);
    } else if (blk < G0B + NCB * ECB) {
        int cb = blk - G0B;
        int r = cb & (NCB - 1), c = cb >> 6;
        int base = r * CH0;
        __shared__ unsigned cnti[CH0], cnto[CH0];
        for (int v = threadIdx.x; v < CH0; v += 256) { cnti[v] = 0u; cnto[v] = 0u; }
        __syncthreads();
        const int4* s4 = (const int4*)p.src;
        const int4* d4 = (const int4*)p.dst;
        int j0 = c * ECHUNK4, j1 = j0 + ECHUNK4;
        for (int j = j0 + (int)threadIdx.x; j < j1; j += 256) {
            int4 dv = d4[j], sv = s4[j];
            unsigned t;
            t = (unsigned)(dv.x - base); if (t < (unsigned)CH0) atomicAdd(&cnti[t], 1u);
            t = (unsigned)(dv.y - base); if (t < (unsigned)CH0) atomicAdd(&cnti[t], 1u);
            t = (unsigned)(dv.z - base); if (t < (unsigned)CH0) atomicAdd(&cnti[t], 1u);
            t = (unsigned)(dv.w - base); if (t < (unsigned)CH0) atomicAdd(&cnti[t], 1u);
            t = (unsigned)(sv.x - base); if (t < (unsigned)CH0) atomicAdd(&cnto[t], 1u);
            t = (unsigned)(sv.y - base); if (t < (unsigned)CH0) atomicAdd(&cnto[t], 1u);
            t = (unsigned)(sv.z - base); if (t < (unsigned)CH0) atomicAdd(&cnto[t], 1u);
            t = (unsigned)(sv.w - base); if (t < (unsigned)CH0) atomicAdd(&cnto[t], 1u);
        }
        __syncthreads();
        for (int v = threadIdx.x; v < CH0; v += 256) {
            int node = base + v;
            if (node < NN) {
                p.degc_i[(size_t)c * NN + node] = (int)cnti[v];
                p.degc_o[(size_t)c * NN + node] = (int)cnto[v];
            }
        }
    } else {
        int l = threadIdx.x;
        if (l < 64) {
            float t = p.b0[l] * p.Wc0[l] + p.b0[l + 64] * p.Wc0[l + 64];
#pragma unroll
            for (int o = 1; o < 64; o <<= 1) t += __shfl_xor(t, o);
            if (l == 0) p.b0wc[0] = t;
        }
    }
}

// ---------- edge slot-mapping for layer 1 (edge-parallel, coalesced) ----------
__global__ void k_emap(P p) {
    int e = blockIdx.x * blockDim.x + threadIdx.x;
    if (e >= EE) return;
    int ns = p.slot[p.src[e]], nd = p.slot[p.dst[e]];
    if (ns < 0) nd = -1;               // nd == -1 marks invalid edge
    p.ens[e] = ns;
    p.end_[e] = nd;
}

// ---------- MERGED: gemm1 || layer-1 degree count (atomic-free) ----------
#define G1B 392            // 2 x 196 gemm blocks
__global__ __launch_bounds__(256) void k_g1deg(P p) {
    int blk = blockIdx.x;
    if (blk < G1B) {
        gemm_body(p.xk, p.W1, p.z1, KK, HD, p.al1, p.ar1, p.el1, p.er1,
                  nullptr, nullptr, blk & 1, blk >> 1);
    } else {
        int cb = blk - G1B;
        int r = cb & (NCB - 1), c = cb >> 6;
        int base = r * CH1;
        __shared__ unsigned cnt1[CH1];
        for (int v = threadIdx.x; v < CH1; v += 256) cnt1[v] = 0u;
        __syncthreads();
        const int4* d4 = (const int4*)p.end_;
        int j0 = c * ECHUNK4, j1 = j0 + ECHUNK4;
        for (int j = j0 + (int)threadIdx.x; j < j1; j += 256) {
            int4 dv = d4[j];
            unsigned t;
            t = (unsigned)(dv.x - base); if (t < (unsigned)CH1) atomicAdd(&cnt1[t], 1u);
            t = (unsigned)(dv.y - base); if (t < (unsigned)CH1) atomicAdd(&cnt1[t], 1u);
            t = (unsigned)(dv.z - base); if (t < (unsigned)CH1) atomicAdd(&cnt1[t], 1u);
            t = (unsigned)(dv.w - base); if (t < (unsigned)CH1) atomicAdd(&cnt1[t], 1u);
        }
        __syncthreads();
        for (int v = threadIdx.x; v < CH1; v += 256) {
            int node = base + v;
            if (node < KK) p.degc1[(size_t)c * KK + node] = (int)cnt1[v];
        }
    }
}

// ---------- two-level exclusive scan (node degree = sum over ECB chunks) ----------
__global__ __launch_bounds__(256) void k_bsum(const int* __restrict__ deg,
                                              int* __restrict__ bsum, int n, int nn) {
    int i = blockIdx.x * 256 + threadIdx.x;
    int v = 0;
    if (i < n) {
#pragma unroll
        for (int c = 0; c < ECB; c++) v += deg[(size_t)c * nn + i];
    }
    int lane = threadIdx.x & 63, w = threadIdx.x >> 6;
    __shared__ int ws[4];
#pragma unroll
    for (int o = 1; o < 64; o <<= 1) v += __shfl_xor(v, o);
    if (lane == 0) ws[w] = v;
    __syncthreads();
    if (threadIdx.x == 0) bsum[blockIdx.x] = ws[0] + ws[1] + ws[2] + ws[3];
}
__global__ __launch_bounds__(256) void k_bscan(const int* __restrict__ bsum, int nb,
                                               int* __restrict__ boff,
                                               int* __restrict__ off, int n) {
    __shared__ int ws[4];
    __shared__ int wo[5];
    int t = threadIdx.x;
    int v = (t < nb) ? bsum[t] : 0;
    int lane = t & 63, w = t >> 6;
    int incl = v;
    for (int o = 1; o < 64; o <<= 1) { int u = __shfl_up(incl, o); if (lane >= o) incl += u; }
    if (lane == 63) ws[w] = incl;
    __syncthreads();
    if (t == 0) { int a = 0; for (int i = 0; i < 4; i++) { wo[i] = a; a += ws[i]; } wo[4] = a; }
    __syncthreads();
    if (t < nb) boff[t] = wo[w] + incl - v;
    if (t == 0) off[n] = wo[4];
}
__global__ __launch_bounds__(256) void k_fscan(const int* __restrict__ deg,
                                               const int* __restrict__ boff,
                                               int* __restrict__ off, int n, int nn) {
    __shared__ int ws[4];
    __shared__ int wo[4];
    int i = blockIdx.x * 256 + threadIdx.x;
    int v = 0;
    if (i < n) {
#pragma unroll
        for (int c = 0; c < ECB; c++) v += deg[(size_t)c * nn + i];
    }
    int lane = threadIdx.x & 63, w = threadIdx.x >> 6;
    int incl = v;
    for (int o = 1; o < 64; o <<= 1) { int u = __shfl_up(incl, o); if (lane >= o) incl += u; }
    if (lane == 63) ws[w] = incl;
    __syncthreads();
    if (threadIdx.x == 0) { int a = 0; for (int k = 0; k < 4; k++) { wo[k] = a; a += ws[k]; } }
    __syncthreads();
    if (i < n) off[i] = boff[blockIdx.x] + wo[w] + incl - v;
}

// ---------- CSR scatters: range-owned, LDS cursors, contiguous writes ----------
__global__ __launch_bounds__(256) void k_scatter0(P p) {
    int cb = blockIdx.x;
    int r = cb & (NCB - 1), c = cb >> 6;
    int base = r * CH0;
    __shared__ unsigned cur[CH0];
    for (int v = threadIdx.x; v < CH0; v += 256) {
        int node = base + v;
        if (node < NN) {
            unsigned o = (unsigned)p.off0[node];
            for (int cc = 0; cc < c; cc++) o += (unsigned)p.degc_i[(size_t)cc * NN + node];
            cur[v] = o;
        }
    }
    __syncthreads();
    const int4* s4 = (const int4*)p.src;
    const int4* d4 = (const int4*)p.dst;
    int j0 = c * ECHUNK4, j1 = j0 + ECHUNK4;
    for (int j = j0 + (int)threadIdx.x; j < j1; j += 256) {
        int4 dv = d4[j], sv = s4[j];
        unsigned t, pos;
        t = (unsigned)(dv.x - base); if (t < (unsigned)CH0) { pos = atomicAdd(&cur[t], 1u); p.csr_src[pos] = sv.x; }
        t = (unsigned)(dv.y - base); if (t < (unsigned)CH0) { pos = atomicAdd(&cur[t], 1u); p.csr_src[pos] = sv.y; }
        t = (unsigned)(dv.z - base); if (t < (unsigned)CH0) { pos = atomicAdd(&cur[t], 1u); p.csr_src[pos] = sv.z; }
        t = (unsigned)(dv.w - base); if (t < (unsigned)CH0) { pos = atomicAdd(&cur[t], 1u); p.csr_src[pos] = sv.w; }
    }
}
__global__ __launch_bounds__(256) void k_scatter1(P p) {
    int cb = blockIdx.x;
    int r = cb & (NCB - 1), c = cb >> 6;
    int base = r * CH1;
    __shared__ unsigned cur[CH1];
    for (int v = threadIdx.x; v < CH1; v += 256) {
        int node = base + v;
        if (node < KK) {
            unsigned o = (unsigned)p.off1[node];
            for (int cc = 0; cc < c; cc++) o += (unsigned)p.degc1[(size_t)cc * KK + node];
            cur[v] = o;
        }
    }
    __syncthreads();
    const int4* s4 = (const int4*)p.ens;
    const int4* d4 = (const int4*)p.end_;
    int j0 = c * ECHUNK4, j1 = j0 + ECHUNK4;
    for (int j = j0 + (int)threadIdx.x; j < j1; j += 256) {
        int4 dv = d4[j], sv = s4[j];
        unsigned t, pos;
        t = (unsigned)(dv.x - base); if (t < (unsigned)CH1) { pos = atomicAdd(&cur[t], 1u); p.csr_src[pos] = sv.x; }
        t = (unsigned)(dv.y - base); if (t < (unsigned)CH1) { pos = atomicAdd(&cur[t], 1u); p.csr_src[pos] = sv.y; }
        t = (unsigned)(dv.z - base); if (t < (unsigned)CH1) { pos = atomicAdd(&cur[t], 1u); p.csr_src[pos] = sv.z; }
        t = (unsigned)(dv.w - base); if (t < (unsigned)CH1) { pos = atomicAdd(&cur[t], 1u); p.csr_src[pos] = sv.w; }
    }
}

// ---------- layer-0 softmax + SCALAR q-gather (all nodes) ----------
__global__ __launch_bounds__(256) void k_fgatlite(
    const int* __restrict__ off, const int* __restrict__ csrs,
    const float* __restrict__ el, const float* __restrict__ er,
    const float* __restrict__ q4, const int* __restrict__ degco,
    const float* __restrict__ b0wc,
    float* __restrict__ hc, float* __restrict__ m0f, float* __restrict__ s0f) {
    int wv = threadIdx.x >> 6, lane = threadIdx.x & 63;
    int v = blockIdx.x * 4 + wv;
    int b = off[v], e = off[v + 1], deg = e - b;
    int h = lane >> 4, sub = lane & 15;
    float erh = er[(size_t)v * 4 + h];
    float m = NEGF;
    for (int li = sub; li < deg; li += 16) {
        int s = csrs[b + li];
        m = fmaxf(m, lrelu(el[(size_t)s * 4 + h] + erh));
    }
#pragma unroll
    for (int o = 1; o < 16; o <<= 1) m = fmaxf(m, __shfl_xor(m, o));
    float ssum = 0.f, hq = 0.f;
    for (int li = sub; li < deg; li += 16) {
        int s = csrs[b + li];
        float ex = expf(lrelu(el[(size_t)s * 4 + h] + erh) - m);
        ssum += ex;
        hq = fmaf(ex, q4[(size_t)s * 4 + h], hq);
    }
#pragma unroll
    for (int o = 1; o < 16; o <<= 1) { ssum += __shfl_xor(ssum, o); hq += __shfl_xor(hq, o); }
    if (sub == 0) { m0f[v * 4 + h] = m; s0f[v * 4 + h] = ssum; }
    float t = hq / fmaxf(ssum, 1e-16f);     // uniform within head group
    t += __shfl_xor(t, 16);
    t += __shfl_xor(t, 32);                 // sum over 4 heads
    if (lane == 0) {
        int dv = degco[v] + degco[NN + v] + degco[2 * NN + v] + degco[3 * NN + v];
        hc[v] = (t + b0wc[0]) / sqrtf(fmaxf((float)dv, 1.f));
    }
}

// ---------- full x for SELECTED nodes only ----------
__global__ __launch_bounds__(256) void k_fgatx(
    const int* __restrict__ list, const float* __restrict__ tscale,
    const int* __restrict__ off, const int* __restrict__ csrs,
    const float* __restrict__ el, const float* __restrict__ er,
    const float* __restrict__ m0f, const float* __restrict__ s0f,
    const float* __restrict__ z, const float* __restrict__ b0,
    float* __restrict__ xk) {
    __shared__ int ssrc[4][CW];
    __shared__ float sexp[4][CW][4];
    int wv = threadIdx.x >> 6, lane = threadIdx.x & 63;
    int i = blockIdx.x * 4 + wv;
    int v = list[i];
    int b = off[v], e = off[v + 1], deg = e - b;
    int h = lane >> 4, sub = lane & 15;
    float erh = er[(size_t)v * 4 + h];
    float mh = m0f[v * 4 + h];
    for (int li = sub; li < deg; li += 16) {
        int s = csrs[b + li];
        if (h == 0 && li < CW) ssrc[wv][li] = s;
        if (li < CW) sexp[wv][li][h] = expf(lrelu(el[(size_t)s * 4 + h] + erh) - mh);
    }
    __syncthreads();
    int h0 = lane >> 5, h1 = h0 + 2;
    float s0 = s0f[v * 4 + h0], s1 = s0f[v * 4 + h1];
    float m0 = m0f[v * 4 + h0], m1 = m0f[v * 4 + h1];
    float er0v = er[(size_t)v * 4 + h0], er1v = er[(size_t)v * 4 + h1];
    int c0 = lane, c1 = lane + 64;
    float acc0 = 0.f, acc1 = 0.f;
    for (int li = 0; li < deg; li++) {
        int s; float w0, w1;
        if (li < CW) {
            s = ssrc[wv][li];
            w0 = sexp[wv][li][h0]; w1 = sexp[wv][li][h1];
        } else {
            s = csrs[b + li];
            w0 = expf(lrelu(el[(size_t)s * 4 + h0] + er0v) - m0);
            w1 = expf(lrelu(el[(size_t)s * 4 + h1] + er1v) - m1);
        }
        int su = __builtin_amdgcn_readfirstlane(s);
        const float* zr = z + (size_t)su * HD;
        acc0 = fmaf(w0, zr[c0], acc0);
        acc1 = fmaf(w1, zr[c1], acc1);
    }
    float ts = tscale[i];
    float* xr = xk + (size_t)i * HD;
    xr[c0] = (acc0 / fmaxf(s0, 1e-16f) + b0[c0]) * ts;
    xr[c1] = (acc1 / fmaxf(s1, 1e-16f) + b0[c1]) * ts;
}

// ---------- SAGPool score ----------
__global__ void k_score(P p) {
    int v = blockIdx.x * blockDim.x + threadIdx.x;
    if (v >= NN) return;
    int b = p.off0[v], en = p.off0[v + 1];
    float acc = 0.f;
    for (int i = b; i < en; i++) acc += p.hc[p.csr_src[i]];
    float dg = fmaxf((float)(en - b), 1.f);
    float sc = acc / sqrtf(dg) + p.bc0[0];
    p.score[v] = sc;
    p.keys[v] = fkey(sc);
}

// ---------- radix select: 2 x 16-bit passes ----------
__global__ void k_hist2(P p, int level) {
    int v = blockIdx.x * blockDim.x + threadIdx.x;
    if (v >= NN) return;
    unsigned key = p.keys[v];
    if (level == 0) atomicAdd(&p.binsHi[key >> 16], 1u);
    else if ((key >> 16) == p.rs[2]) atomicAdd(&p.binsLo[key & 0xFFFFu], 1u);
}
__global__ __launch_bounds__(1024) void k_rsel2(P p, int level) {
    const unsigned* bins = level ? p.binsLo : p.binsHi;
    int K = level ? (int)p.rs[3] : KK;
    __shared__ unsigned wsm[16];
    __shared__ unsigned wpre[17];
    int t = threadIdx.x;
    unsigned base = (unsigned)t * 64;
    const uint4* b4 = (const uint4*)(bins + base);
    unsigned S = 0;
#pragma unroll
    for (int i = 0; i < 16; i++) {
        uint4 u = b4[i];
        S += u.x + u.y + u.z + u.w;
    }
    int lane = t & 63, w = t >> 6;
    unsigned val = S;
    for (int o = 1; o < 64; o <<= 1) { unsigned u = __shfl_up(val, o); if (lane >= o) val += u; }
    if (lane == 63) wsm[w] = val;
    __syncthreads();
    if (t == 0) { unsigned a = 0; for (int i = 0; i < 16; i++) { wpre[i] = a; a += wsm[i]; } wpre[16] = a; }
    __syncthreads();
    unsigned incl = wpre[w] + val;
    unsigned running = wpre[16] - incl;    // keys in strictly higher bins
    for (int i = 63; i >= 0; i--) {
        unsigned c = bins[base + i];
        unsigned above = running;
        running += c;
        if ((int)above < K && (int)running >= K) {
            if (level == 0) { p.rs[2] = base + (unsigned)i; p.rs[3] = (unsigned)(K - (int)above); }
            else { p.rs[0] = (p.rs[2] << 16) | (base + (unsigned)i); p.rs[1] = (unsigned)(K - (int)above); }
        }
    }
}
__global__ void k_sel(P p) {
    int v = blockIdx.x * blockDim.x + threadIdx.x;
    if (v >= NN) return;
    p.sel[v] = (p.keys[v] > p.rs[0]) ? 1 : 0;
}
__global__ __launch_bounds__(1024) void k_ties(P p) {   // lowest-index ties (matches top_k)
    __shared__ int base;
    __shared__ int wsums[16];
    unsigned pivot = p.rs[0];
    int need = (int)p.rs[1];
    if (threadIdx.x == 0) base = 0;
    __syncthreads();
    for (int st = 0; st < NN; st += 1024) {
        int v = st + (int)threadIdx.x;
        int flag = (v < NN && p.keys[v] == pivot) ? 1 : 0;
        unsigned long long m = __ballot(flag);
        int lane = threadIdx.x & 63, w = threadIdx.x >> 6;
        int pre = __popcll(m & ((1ull << lane) - 1ull));
        if (lane == 0) wsums[w] = __popcll(m);
        __syncthreads();
        int woff = 0;
        for (int i = 0; i < w; i++) woff += wsums[i];
        int rank = base + woff + pre;
        if (flag && rank < need) p.sel[v] = 1;
        __syncthreads();
        if (threadIdx.x == 0) {
            int s = 0;
            for (int i = 0; i < 16; i++) s += wsums[i];
            base += s;
        }
        __syncthreads();
    }
}
__global__ void k_list(P p) {
    int v = blockIdx.x * blockDim.x + threadIdx.x;
    if (v >= NN) return;
    if (p.sel[v]) {
        int i = atomicAdd(p.cnt, 1);
        p.list[i] = v;
        p.slot[v] = i;
        p.tscale[i] = tanhf(p.score[v]);
    } else {
        p.slot[v] = -1;
    }
}

// ---------- layer-1 fused GAT (wave-per-node) + res/g epilogue ----------
__global__ __launch_bounds__(256) void k_fgat2(
    const int* __restrict__ off, const int* __restrict__ csrs,
    const float* __restrict__ el, const float* __restrict__ er,
    const float* __restrict__ z, const float* __restrict__ bias,
    float* __restrict__ mf, float* __restrict__ sf,
    const float* __restrict__ gW, const float* __restrict__ gb,
    float* __restrict__ res, float* __restrict__ g) {
    __shared__ int ssrc[4][CW];
    __shared__ float sexp[4][CW][4];
    int wv = threadIdx.x >> 6, lane = threadIdx.x & 63;
    int v = blockIdx.x * 4 + wv;
    int b = off[v], e = off[v + 1], deg = e - b;
    int h = lane >> 4, sub = lane & 15;
    float4 er4 = *(const float4*)(er + (size_t)v * 4);
    float erh = ((const float*)&er4)[h];
    float m = NEGF;
    for (int li = sub; li < deg; li += 16) {
        int s = csrs[b + li];
        if (h == 0 && li < CW) ssrc[wv][li] = s;
        m = fmaxf(m, lrelu(el[(size_t)s * 4 + h] + erh));
    }
#pragma unroll
    for (int o = 1; o < 16; o <<= 1) m = fmaxf(m, __shfl_xor(m, o));
    float ssum = 0.f;
    for (int li = sub; li < deg; li += 16) {
        int s = csrs[b + li];
        float x = expf(lrelu(el[(size_t)s * 4 + h] + erh) - m);
        if (li < CW) sexp[wv][li][h] = x;
        ssum += x;
    }
#pragma unroll
    for (int o = 1; o < 16; o <<= 1) ssum += __shfl_xor(ssum, o);
    if (sub == 0) { mf[v * 4 + h] = m; sf[v * 4 + h] = ssum; }
    __syncthreads();
    int h0 = lane >> 5, h1 = h0 + 2;
    float m0 = __shfl(m, h0 << 4), m1 = __shfl(m, h1 << 4);
    float s0 = __shfl(ssum, h0 << 4), s1 = __shfl(ssum, h1 << 4);
    int c0 = lane, c1 = lane + 64;
    float acc0 = 0.f, acc1 = 0.f;
    for (int li = 0; li < deg; li++) {
        int s; float w0, w1;
        if (li < CW) {
            s = ssrc[wv][li];
            w0 = sexp[wv][li][h0]; w1 = sexp[wv][li][h1];
        } else {
            s = csrs[b + li];
            w0 = expf(lrelu(el[(size_t)s * 4 + h0] + ((const float*)&er4)[h0]) - m0);
            w1 = expf(lrelu(el[(size_t)s * 4 + h1] + ((const float*)&er4)[h1]) - m1);
        }
        int su = __builtin_amdgcn_readfirstlane(s);
        const float* zr = z + (size_t)su * HD;
        acc0 = fmaf(w0, zr[c0], acc0);
        acc1 = fmaf(w1, zr[c1], acc1);
    }
    float xc0 = acc0 / fmaxf(s0, 1e-16f) + bias[c0];
    float xc1 = acc1 / fmaxf(s1, 1e-16f) + bias[c1];
    float t = xc0 + xc1;              // x[c]+x[c+64]
    t += __shfl_xor(t, 32);           // + x[c+32]+x[c+96]
    float pg = 0.f;
    if (lane < 32) {
        float r = 0.25f * t;
        res[(size_t)v * 32 + lane] = r;
        pg = r * gW[lane];
    }
#pragma unroll
    for (int o = 1; o < 32; o <<= 1) pg += __shfl_xor(pg, o);
    if (lane == 0) g[v] = pg + gb[0];
}

// per-edge alpha outputs: pure reads, writes atten+strength for ALL edges
__global__ void k_ealpha1(P p) {
    int e = blockIdx.x * blockDim.x + threadIdx.x;
    if (e >= EE) return;
    int ds = p.ens[e], dd = p.end_[e];
    float a[4] = {0.f, 0.f, 0.f, 0.f};
    float st = 0.f;
    if (dd >= 0) {
        float4 es = *(const float4*)(p.el1 + ds * 4);
        float4 ed = *(const float4*)(p.er1 + dd * 4);
        float l[4] = {lrelu(es.x + ed.x), lrelu(es.y + ed.y), lrelu(es.z + ed.z), lrelu(es.w + ed.w)};
#pragma unroll
        for (int h = 0; h < 4; h++) {
            float m = p.m1f[dd * 4 + h];
            float ex = expf(l[h] - m);
            a[h] = ex / fmaxf(p.s1f[dd * 4 + h], 1e-16f);
        }
        st = p.strength[e];
    }
    float* o = p.out + ATT_OFF + (size_t)e * 4;
    *(float2*)(o) = make_float2(a[0], a[1]);
    *(float2*)(o + 2) = make_float2(a[2], a[3]);
    p.out[STR_OFF + e] = st;
}

// ---------- readout ----------
__global__ void k_gmax(P p) {
    __shared__ float red[256];
    int t = threadIdx.x;
    float m = -3.4e38f;
    for (int i = blockIdx.x * 256 + t; i < KK; i += gridDim.x * 256) m = fmaxf(m, p.g[i]);
    red[t] = m;
    __syncthreads();
    for (int o = 128; o > 0; o >>= 1) { if (t < o) red[t] = fmaxf(red[t], red[t + o]); __syncthreads(); }
    if (t == 0) atomicMax(p.gmaxk, fkey(red[0]));   // memset-0 identity ok
}
#define WSUM_BLOCKS 104
__global__ __launch_bounds__(256) void k_wsum(P p) {
    __shared__ double vred[256];
    __shared__ double zred[8];
    int t = threadIdx.x, il = t >> 5, d = t & 31;
    float gm = unfkey(*p.gmaxk);
    double accv = 0.0, accw = 0.0;
    for (int i = blockIdx.x * 8 + il; i < KK; i += WSUM_BLOCKS * 8) {
        float w = expf(p.g[i] - gm);
        accv += (double)(w * p.res[(size_t)i * 32 + d]);
        if (d == 0) accw += (double)w;
    }
    vred[t] = accv;
    if (d == 0) zred[il] = accw;
    __syncthreads();
    if (il == 0) {
        double s = 0;
#pragma unroll
        for (int k2 = 0; k2 < 8; k2++) s += vred[k2 * 32 + d];
        atomicAdd(&p.racc[d], s);
    }
    if (t == 32) {
        double z2 = 0;
#pragma unroll
        for (int k2 = 0; k2 < 8; k2++) z2 += zred[k2];
        atomicAdd(p.Zacc, z2);
    }
}
__global__ void k_final(P p) {
    __shared__ float rb[32];
    int t = threadIdx.x;
    double Z = *p.Zacc;
    if (t < 32) {
        float r = (float)(p.racc[t] / Z);
        p.out[t] = r;
        rb[t] = r;
    }
    __syncthreads();
    if (t < 2) {
        float s = 0.f;
        for (int d = 0; d < 32; d++) s += rb[d] * p.cW[d * 2 + t];
        p.out[32 + t] = s + p.cb[t];
    }
}

// ---------- host ----------
extern "C" void kernel_launch(void* const* d_in, const int* in_sizes, int n_in,
                              void* d_out, int out_size, void* d_ws, size_t ws_size,
                              hipStream_t stream) {
    (void)in_sizes; (void)n_in; (void)out_size; (void)ws_size;
    P p;
    p.feature  = (const float*)d_in[0];
    p.strength = (const float*)d_in[1];
    p.W0  = (const float*)d_in[2];  p.b0  = (const float*)d_in[3];
    p.al0 = (const float*)d_in[4];  p.ar0 = (const float*)d_in[5];
    p.Wc0 = (const float*)d_in[6];  p.bc0 = (const float*)d_in[7];
    p.W1  = (const float*)d_in[8];  p.b1  = (const float*)d_in[9];
    p.al1 = (const float*)d_in[10]; p.ar1 = (const float*)d_in[11];
    p.gW  = (const float*)d_in[12]; p.gb  = (const float*)d_in[13];
    p.cW  = (const float*)d_in[14]; p.cb  = (const float*)d_in[15];
    p.src = (const int*)d_in[16];   p.dst = (const int*)d_in[17];
    p.out = (float*)d_out;

    char* ws = (char*)d_ws;
    size_t off = 0;
    auto alloc = [&](size_t bytes) -> void* {
        void* r = ws + off;
        off = (off + bytes + 255) & ~(size_t)255;
        return r;
    };
    // ---- zeroed region (must stay first/contiguous) ----
    p.Zacc  = (double*)alloc(8);
    p.racc  = (double*)alloc(32 * 8);
    p.cnt   = (int*)alloc(4);
    p.gmaxk = (unsigned*)alloc(4);
    p.rs    = (unsigned*)alloc(16);
    p.binsHi = (unsigned*)alloc(65536 * 4);
    p.binsLo = (unsigned*)alloc(65536 * 4);
    size_t zbytes = off;
    // ---- big buffers (no zeroing needed; fully overwritten) ----
    p.degc_i = (int*)alloc((size_t)ECB * NN * 4);
    p.degc_o = (int*)alloc((size_t)ECB * NN * 4);
    p.degc1  = (int*)alloc((size_t)ECB * KK * 4);
    p.ens    = (int*)alloc((size_t)EE * 4);
    p.end_   = (int*)alloc((size_t)EE * 4);
    p.z0 = (float*)alloc((size_t)NN * HD * 4);
    p.xk = (float*)alloc((size_t)KK * HD * 4);
    p.z1 = (float*)alloc((size_t)KK * HD * 4);
    p.csr_src = (int*)alloc((size_t)EE * 4);
    p.el0 = (float*)alloc((size_t)NN * 4 * 4);
    p.er0 = (float*)alloc((size_t)NN * 4 * 4);
    p.q4  = (float*)alloc((size_t)NN * 4 * 4);
    p.m0f = (float*)alloc((size_t)NN * 4 * 4);
    p.s0f = (float*)alloc((size_t)NN * 4 * 4);
    p.b0wc = (float*)alloc(4);
    p.off0 = (int*)alloc((size_t)(NN + 1) * 4);
    p.off1 = (int*)alloc((size_t)(KK + 1) * 4);
    p.bsum = (int*)alloc(256 * 4);
    p.boff = (int*)alloc(256 * 4);
    p.hc    = (float*)alloc((size_t)NN * 4);
    p.score = (float*)alloc((size_t)NN * 4);
    p.keys  = (unsigned*)alloc((size_t)NN * 4);
    p.sel   = (int*)alloc((size_t)NN * 4);
    p.slot  = (int*)alloc((size_t)NN * 4);
    p.list  = (int*)alloc((size_t)KK * 4);
    p.tscale = (float*)alloc((size_t)KK * 4);
    p.el1 = (float*)alloc((size_t)KK * 4 * 4);
    p.er1 = (float*)alloc((size_t)KK * 4 * 4);
    p.m1f = (float*)alloc((size_t)KK * 4 * 4);
    p.s1f = (float*)alloc((size_t)KK * 4 * 4);
    p.res = (float*)alloc((size_t)KK * DD * 4);
    p.g   = (float*)alloc((size_t)KK * 4);

    const int GB_E = (EE + 255) / 256;        // 3125
    const int GB_N = (NN + 255) / 256;        // 196
    const int GB_K = (KK + 255) / 256;        // 98

    hipMemsetAsync(d_ws, 0, zbytes, stream);

    // ---- GAT layer 0 (gemm0 || count || prep in one launch) ----
    k_g0deg<<<G0B + NCB * ECB + 1, 256, 0, stream>>>(p);
    k_bsum<<<GB_N, 256, 0, stream>>>(p.degc_i, p.bsum, NN, NN);
    k_bscan<<<1, 256, 0, stream>>>(p.bsum, GB_N, p.boff, p.off0, NN);
    k_fscan<<<GB_N, 256, 0, stream>>>(p.degc_i, p.boff, p.off0, NN, NN);
    k_scatter0<<<NCB * ECB, 256, 0, stream>>>(p);
    k_fgatlite<<<NN / 4, 256, 0, stream>>>(p.off0, p.csr_src, p.el0, p.er0, p.q4,
                                           p.degc_o, p.b0wc, p.hc, p.m0f, p.s0f);

    // ---- SAGPool ----
    k_score<<<GB_N, 256, 0, stream>>>(p);
    k_hist2<<<GB_N, 256, 0, stream>>>(p, 0);
    k_rsel2<<<1, 1024, 0, stream>>>(p, 0);
    k_hist2<<<GB_N, 256, 0, stream>>>(p, 1);
    k_rsel2<<<1, 1024, 0, stream>>>(p, 1);
    k_sel<<<GB_N, 256, 0, stream>>>(p);
    k_ties<<<1, 1024, 0, stream>>>(p);
    k_list<<<GB_N, 256, 0, stream>>>(p);
    k_emap<<<GB_E, 256, 0, stream>>>(p);
    k_fgatx<<<KK / 4, 256, 0, stream>>>(p.list, p.tscale, p.off0, p.csr_src,
                                        p.el0, p.er0, p.m0f, p.s0f, p.z0, p.b0, p.xk);

    // ---- GAT layer 1 (gemm1 || count1 in one launch) ----
    k_g1deg<<<G1B + NCB * ECB, 256, 0, stream>>>(p);
    k_bsum<<<GB_K, 256, 0, stream>>>(p.degc1, p.bsum, KK, KK);
    k_bscan<<<1, 256, 0, stream>>>(p.bsum, GB_K, p.boff, p.off1, KK);
    k_fscan<<<GB_K, 256, 0, stream>>>(p.degc1, p.boff, p.off1, KK, KK);
    k_scatter1<<<NCB * ECB, 256, 0, stream>>>(p);
    k_fgat2<<<KK / 4, 256, 0, stream>>>(p.off1, p.csr_src, p.el1, p.er1, p.z1, p.b1,
                                        p.m1f, p.s1f, p.gW, p.gb, p.res, p.g);
    k_ealpha1<<<GB_E, 256, 0, stream>>>(p);

    // ---- readout ----
    k_gmax<<<98, 256, 0, stream>>>(p);
    k_wsum<<<WSUM_BLOCKS, 256, 0, stream>>>(p);
    k_final<<<1, 64, 0, stream>>>(p);
}

// Round 3
// 629.956 us; speedup vs baseline: 1.3722x; 1.3722x over previous
//
#include <hip/hip_runtime.h>
#include <stdint.h>

#define NN 50000
#define EE 800000
#define FIN 256
#define HD 128
#define DD 32
#define KK 25000
#define SLOPEF 0.4f
#define NEGF (-1e9f)
#define ATT_OFF 34
#define STR_OFF (34 + EE * 4)
#define CW 128             // LDS-cached edges per node (deg ~Poisson(16); recompute fallback)

// counting-sort CSR build: per-block FULL-range LDS histogram, u8 packed counters.
// 32 chunks of 25K edges; Poisson(0.5) per node per chunk -> counts << 255.
#define BCH 32             // edge chunks (= count blocks per histogram)
#define EPC (EE / BCH)     // 25000 edges per chunk

// ---------- helpers ----------
__device__ __forceinline__ unsigned fkey(float x) {
    unsigned u = __float_as_uint(x);
    return (u & 0x80000000u) ? ~u : (u | 0x80000000u);   // monotone float->uint
}
__device__ __forceinline__ float unfkey(unsigned k) {
    unsigned u = (k & 0x80000000u) ? (k ^ 0x80000000u) : ~k;
    return __uint_as_float(u);
}
__device__ __forceinline__ float lrelu(float v) { return v > 0.f ? v : SLOPEF * v; }

// ---------- pointer bundle ----------
struct P {
    // inputs
    const float *feature, *strength, *W0, *b0, *al0, *ar0, *Wc0, *bc0;
    const float *W1, *b1, *al1, *ar1, *gW, *gb, *cW, *cb;
    const int *src, *dst;
    // zeroed scratch
    double *Zacc, *racc;
    int *cnt;
    unsigned *gmaxk, *rs;         // rs[0]=pivot key, rs[1]=ties needed, rs[2]=hi bin, rs[3]=hi remaining
    unsigned *binsHi, *binsLo;
    // other scratch
    unsigned *keys;
    unsigned char *degc_i, *degc_o, *degc1;  // per-(chunk,node) u8 counts [BCH][n]
    unsigned *cb0, *cb1;           // per-(chunk,node) CSR base cursors
    int *dsum;                     // out-degree totals
    int *ens, *end_;               // slot-mapped edge endpoints (layer 1)
    int *csr_src, *rank, *off0, *off1, *sel, *slot, *list, *bsum, *boff;
    float *z0, *el0, *er0, *q4, *m0f, *s0f, *b0wc, *hc, *score, *xk, *z1;
    float *el1, *er1, *m1f, *s1f, *res, *g, *tscale;
    float *out;                    // d_out (float32)
};

// ---------- fp32 tiled GEMM body: C[M,128] = A[M,Kd] @ B[Kd,128] ----------
// ELR epilogue: el/er for this block's 2 heads from acc regs; optional q4.
#define BM 128
#define BN 64
#define BK 16
__device__ void gemm_body(
    const float* __restrict__ A, const float* __restrict__ B, float* __restrict__ C,
    int M, int Kd,
    const float* __restrict__ al, const float* __restrict__ ar,
    float* __restrict__ el, float* __restrict__ er,
    const float* __restrict__ Wc, float* __restrict__ q4,
    int bx, int by) {
    __shared__ float As[BK][BM + 4];
    __shared__ float Bs[BK][BN];
    int bm = by * BM, bn = bx * BN;
    int tid = threadIdx.x;
    int tr = tid >> 4, tc = tid & 15;
    int lrow = tid >> 1;
    int arow = (bm + lrow < M) ? (bm + lrow) : -1;
    float acc[8][4] = {};
    for (int k0 = 0; k0 < Kd; k0 += BK) {
        {
            int col = (tid & 1) << 3;
            float4 v0 = {0.f,0.f,0.f,0.f}, v1 = {0.f,0.f,0.f,0.f};
            if (arow >= 0) {
                const float* ap = A + (size_t)arow * Kd + k0 + col;
                v0 = *(const float4*)ap; v1 = *(const float4*)(ap + 4);
            }
            As[col + 0][lrow] = v0.x; As[col + 1][lrow] = v0.y;
            As[col + 2][lrow] = v0.z; As[col + 3][lrow] = v0.w;
            As[col + 4][lrow] = v1.x; As[col + 5][lrow] = v1.y;
            As[col + 6][lrow] = v1.z; As[col + 7][lrow] = v1.w;
        }
        {
            int kr = tid >> 4, col = (tid & 15) << 2;
            float4 v = *(const float4*)(B + (size_t)(k0 + kr) * HD + bn + col);
            *(float4*)&Bs[kr][col] = v;
        }
        __syncthreads();
#pragma unroll
        for (int kk = 0; kk < BK; kk++) {
            float a[8], b[4];
#pragma unroll
            for (int i = 0; i < 8; i++) a[i] = As[kk][tr * 8 + i];
#pragma unroll
            for (int j = 0; j < 4; j++) b[j] = Bs[kk][tc * 4 + j];
#pragma unroll
            for (int i = 0; i < 8; i++)
#pragma unroll
                for (int j = 0; j < 4; j++) acc[i][j] = fmaf(a[i], b[j], acc[i][j]);
        }
        __syncthreads();
    }
#pragma unroll
    for (int i = 0; i < 8; i++) {
        int gr = bm + tr * 8 + i;
        if (gr < M) {
            float4 v = {acc[i][0], acc[i][1], acc[i][2], acc[i][3]};
            *(float4*)(C + (size_t)gr * HD + bn + tc * 4) = v;
        }
    }
    // epilogue: heads 2*bx, 2*bx+1; 8-lane tree reduce per (row, head)
    int head = bx * 2 + (tc >> 3);
    int dbase = (tc & 7) * 4;
    const float* alh = al + head * 32 + dbase;
    const float* arh = ar + head * 32 + dbase;
    float a0 = alh[0], a1 = alh[1], a2 = alh[2], a3 = alh[3];
    float r0 = arh[0], r1 = arh[1], r2 = arh[2], r3 = arh[3];
    float w0 = 0.f, w1 = 0.f, w2 = 0.f, w3 = 0.f;
    if (Wc) {
        const float* wch = Wc + head * 32 + dbase;
        w0 = wch[0]; w1 = wch[1]; w2 = wch[2]; w3 = wch[3];
    }
#pragma unroll
    for (int i = 0; i < 8; i++) {
        int gr = bm + tr * 8 + i;
        float pe = acc[i][0]*a0 + acc[i][1]*a1 + acc[i][2]*a2 + acc[i][3]*a3;
        float pr = acc[i][0]*r0 + acc[i][1]*r1 + acc[i][2]*r2 + acc[i][3]*r3;
        float pq = acc[i][0]*w0 + acc[i][1]*w1 + acc[i][2]*w2 + acc[i][3]*w3;
#pragma unroll
        for (int o = 1; o < 8; o <<= 1) {
            pe += __shfl_xor(pe, o); pr += __shfl_xor(pr, o); pq += __shfl_xor(pq, o);
        }
        if ((tc & 7) == 0 && gr < M) {
            el[gr * 4 + head] = pe; er[gr * 4 + head] = pr;
            if (Wc) q4[gr * 4 + head] = pq;
        }
    }
}

// ---------- layer-0 count: full-range u8 LDS histogram; rank = old field ----------
// blocks [0,BCH): dst counts (+rank); blocks [BCH,2*BCH): src counts.
__global__ __launch_bounds__(256) void k_count0(P p) {
    __shared__ unsigned hist[NN / 4];         // 12500 words = 50 KB, u8 counters
    int blk = blockIdx.x;
    int isD = blk < BCH;
    int c = isD ? blk : blk - BCH;
    for (int w = threadIdx.x; w < NN / 4; w += 256) hist[w] = 0u;
    __syncthreads();
    int j0 = c * EPC, j1 = j0 + EPC;
    if (isD) {
        for (int e = j0 + (int)threadIdx.x; e < j1; e += 256) {
            int d = p.dst[e];
            unsigned sh = (unsigned)(d & 3) * 8u;
            unsigned old = atomicAdd(&hist[d >> 2], 1u << sh);
            p.rank[e] = (int)((old >> sh) & 0xffu);
        }
    } else {
        for (int e = j0 + (int)threadIdx.x; e < j1; e += 256) {
            int s = p.src[e];
            atomicAdd(&hist[s >> 2], 1u << ((unsigned)(s & 3) * 8u));
        }
    }
    __syncthreads();
    unsigned* o32 = (unsigned*)((isD ? p.degc_i : p.degc_o) + (size_t)c * NN);
    for (int w = threadIdx.x; w < NN / 4; w += 256) o32[w] = hist[w];
}

// ---------- layer-1 count (slot-mapped dst; invalid edges skipped) ----------
__global__ __launch_bounds__(256) void k_count1(P p) {
    __shared__ unsigned hist[KK / 4];         // 6250 words = 25 KB
    int c = blockIdx.x;
    for (int w = threadIdx.x; w < KK / 4; w += 256) hist[w] = 0u;
    __syncthreads();
    int j0 = c * EPC, j1 = j0 + EPC;
    for (int e = j0 + (int)threadIdx.x; e < j1; e += 256) {
        int d = p.end_[e];
        if (d >= 0) {
            unsigned sh = (unsigned)(d & 3) * 8u;
            unsigned old = atomicAdd(&hist[d >> 2], 1u << sh);
            p.rank[e] = (int)((old >> sh) & 0xffu);
        }
    }
    __syncthreads();
    unsigned* o32 = (unsigned*)(p.degc1 + (size_t)c * KK);
    for (int w = threadIdx.x; w < KK / 4; w += 256) o32[w] = hist[w];
}

// ---------- edge slot-mapping for layer 1 (edge-parallel, coalesced) ----------
__global__ void k_emap(P p) {
    int e = blockIdx.x * blockDim.x + threadIdx.x;
    if (e >= EE) return;
    int ns = p.slot[p.src[e]], nd = p.slot[p.dst[e]];
    if (ns < 0) nd = -1;               // nd == -1 marks invalid edge
    p.ens[e] = ns;
    p.end_[e] = nd;
}

// ---------- two-level exclusive scan over node totals ----------
__global__ __launch_bounds__(256) void k_bsum(const unsigned char* __restrict__ deg,
                                              int* __restrict__ bsum, int n, int nn) {
    int i = blockIdx.x * 256 + threadIdx.x;
    int v = 0;
    if (i < n) {
#pragma unroll
        for (int c = 0; c < BCH; c++) v += deg[(size_t)c * nn + i];
    }
    int lane = threadIdx.x & 63, w = threadIdx.x >> 6;
    __shared__ int ws[4];
#pragma unroll
    for (int o = 1; o < 64; o <<= 1) v += __shfl_xor(v, o);
    if (lane == 0) ws[w] = v;
    __syncthreads();
    if (threadIdx.x == 0) bsum[blockIdx.x] = ws[0] + ws[1] + ws[2] + ws[3];
}
__global__ __launch_bounds__(256) void k_bscan(const int* __restrict__ bsum, int nb,
                                               int* __restrict__ boff,
                                               int* __restrict__ off, int n) {
    __shared__ int ws[4];
    __shared__ int wo[5];
    int t = threadIdx.x;
    int v = (t < nb) ? bsum[t] : 0;
    int lane = t & 63, w = t >> 6;
    int incl = v;
    for (int o = 1; o < 64; o <<= 1) { int u = __shfl_up(incl, o); if (lane >= o) incl += u; }
    if (lane == 63) ws[w] = incl;
    __syncthreads();
    if (t == 0) { int a = 0; for (int i = 0; i < 4; i++) { wo[i] = a; a += ws[i]; } wo[4] = a; }
    __syncthreads();
    if (t < nb) boff[t] = wo[w] + incl - v;
    if (t == 0) off[n] = wo[4];
}
// layer-0 final scan: off0 + per-chunk bases cb0 + out-degree totals dsum
__global__ __launch_bounds__(256) void k_fscan0(P p) {
    __shared__ int ws[4];
    __shared__ int wo[4];
    int i = blockIdx.x * 256 + threadIdx.x;
    int v = 0;
    if (i < NN) {
#pragma unroll
        for (int c = 0; c < BCH; c++) v += p.degc_i[(size_t)c * NN + i];
    }
    int lane = threadIdx.x & 63, w = threadIdx.x >> 6;
    int incl = v;
    for (int o = 1; o < 64; o <<= 1) { int u = __shfl_up(incl, o); if (lane >= o) incl += u; }
    if (lane == 63) ws[w] = incl;
    __syncthreads();
    if (threadIdx.x == 0) { int a = 0; for (int k = 0; k < 4; k++) { wo[k] = a; a += ws[k]; } }
    __syncthreads();
    if (i < NN) {
        int base = p.boff[blockIdx.x] + wo[w] + incl - v;
        p.off0[i] = base;
        unsigned run = (unsigned)base;
        int s = 0;
#pragma unroll
        for (int c = 0; c < BCH; c++) {
            p.cb0[(size_t)c * NN + i] = run;
            run += p.degc_i[(size_t)c * NN + i];
            s += p.degc_o[(size_t)c * NN + i];
        }
        p.dsum[i] = s;
    }
}
// layer-1 final scan: off1 + cb1
__global__ __launch_bounds__(256) void k_fscan1(P p) {
    __shared__ int ws[4];
    __shared__ int wo[4];
    int i = blockIdx.x * 256 + threadIdx.x;
    int v = 0;
    if (i < KK) {
#pragma unroll
        for (int c = 0; c < BCH; c++) v += p.degc1[(size_t)c * KK + i];
    }
    int lane = threadIdx.x & 63, w = threadIdx.x >> 6;
    int incl = v;
    for (int o = 1; o < 64; o <<= 1) { int u = __shfl_up(incl, o); if (lane >= o) incl += u; }
    if (lane == 63) ws[w] = incl;
    __syncthreads();
    if (threadIdx.x == 0) { int a = 0; for (int k = 0; k < 4; k++) { wo[k] = a; a += ws[k]; } }
    __syncthreads();
    if (i < KK) {
        int base = p.boff[blockIdx.x] + wo[w] + incl - v;
        p.off1[i] = base;
        unsigned run = (unsigned)base;
#pragma unroll
        for (int c = 0; c < BCH; c++) {
            p.cb1[(size_t)c * KK + i] = run;
            run += p.degc1[(size_t)c * KK + i];
        }
    }
}

// ---------- MERGED: gemm0 || CSR scatter0 || b0.Wc0 prep ----------
#define G0B 782            // 2 x 391 gemm blocks
#define GB_E 3125
__global__ __launch_bounds__(256) void k_g0sc(P p) {
    int blk = blockIdx.x;
    if (blk < G0B) {
        gemm_body(p.feature, p.W0, p.z0, NN, FIN, p.al0, p.ar0, p.el0, p.er0,
                  p.Wc0, p.q4, blk & 1, blk >> 1);
    } else if (blk < G0B + GB_E) {
        int e = (blk - G0B) * 256 + threadIdx.x;
        if (e < EE) {
            int c = e / EPC;
            int d = p.dst[e];
            unsigned pos = p.cb0[(size_t)c * NN + d] + (unsigned)p.rank[e];
            p.csr_src[pos] = p.src[e];
        }
    } else {
        int l = threadIdx.x;
        if (l < 64) {
            float t = p.b0[l] * p.Wc0[l] + p.b0[l + 64] * p.Wc0[l + 64];
#pragma unroll
            for (int o = 1; o < 64; o <<= 1) t += __shfl_xor(t, o);
            if (l == 0) p.b0wc[0] = t;
        }
    }
}

// ---------- MERGED: gemm1 || CSR scatter1 ----------
#define G1B 392            // 2 x 196 gemm blocks
__global__ __launch_bounds__(256) void k_g1sc(P p) {
    int blk = blockIdx.x;
    if (blk < G1B) {
        gemm_body(p.xk, p.W1, p.z1, KK, HD, p.al1, p.ar1, p.el1, p.er1,
                  nullptr, nullptr, blk & 1, blk >> 1);
    } else {
        int e = (blk - G1B) * 256 + threadIdx.x;
        if (e < EE) {
            int d = p.end_[e];
            if (d >= 0) {
                int c = e / EPC;
                unsigned pos = p.cb1[(size_t)c * KK + d] + (unsigned)p.rank[e];
                p.csr_src[pos] = p.ens[e];
            }
        }
    }
}

// ---------- layer-0 softmax + SCALAR q-gather (all nodes) ----------
__global__ __launch_bounds__(256) void k_fgatlite(
    const int* __restrict__ off, const int* __restrict__ csrs,
    const float* __restrict__ el, const float* __restrict__ er,
    const float* __restrict__ q4, const int* __restrict__ dsum,
    const float* __restrict__ b0wc,
    float* __restrict__ hc, float* __restrict__ m0f, float* __restrict__ s0f) {
    int wv = threadIdx.x >> 6, lane = threadIdx.x & 63;
    int v = blockIdx.x * 4 + wv;
    int b = off[v], e = off[v + 1], deg = e - b;
    int h = lane >> 4, sub = lane & 15;
    float erh = er[(size_t)v * 4 + h];
    float m = NEGF;
    for (int li = sub; li < deg; li += 16) {
        int s = csrs[b + li];
        m = fmaxf(m, lrelu(el[(size_t)s * 4 + h] + erh));
    }
#pragma unroll
    for (int o = 1; o < 16; o <<= 1) m = fmaxf(m, __shfl_xor(m, o));
    float ssum = 0.f, hq = 0.f;
    for (int li = sub; li < deg; li += 16) {
        int s = csrs[b + li];
        float ex = expf(lrelu(el[(size_t)s * 4 + h] + erh) - m);
        ssum += ex;
        hq = fmaf(ex, q4[(size_t)s * 4 + h], hq);
    }
#pragma unroll
    for (int o = 1; o < 16; o <<= 1) { ssum += __shfl_xor(ssum, o); hq += __shfl_xor(hq, o); }
    if (sub == 0) { m0f[v * 4 + h] = m; s0f[v * 4 + h] = ssum; }
    float t = hq / fmaxf(ssum, 1e-16f);     // uniform within head group
    t += __shfl_xor(t, 16);
    t += __shfl_xor(t, 32);                 // sum over 4 heads
    if (lane == 0)
        hc[v] = (t + b0wc[0]) / sqrtf(fmaxf((float)dsum[v], 1.f));
}

// ---------- full x for SELECTED nodes only ----------
__global__ __launch_bounds__(256) void k_fgatx(
    const int* __restrict__ list, const float* __restrict__ tscale,
    const int* __restrict__ off, const int* __restrict__ csrs,
    const float* __restrict__ el, const float* __restrict__ er,
    const float* __restrict__ m0f, const float* __restrict__ s0f,
    const float* __restrict__ z, const float* __restrict__ b0,
    float* __restrict__ xk) {
    __shared__ int ssrc[4][CW];
    __shared__ float sexp[4][CW][4];
    int wv = threadIdx.x >> 6, lane = threadIdx.x & 63;
    int i = blockIdx.x * 4 + wv;
    int v = list[i];
    int b = off[v], e = off[v + 1], deg = e - b;
    int h = lane >> 4, sub = lane & 15;
    float erh = er[(size_t)v * 4 + h];
    float mh = m0f[v * 4 + h];
    for (int li = sub; li < deg; li += 16) {
        int s = csrs[b + li];
        if (h == 0 && li < CW) ssrc[wv][li] = s;
        if (li < CW) sexp[wv][li][h] = expf(lrelu(el[(size_t)s * 4 + h] + erh) - mh);
    }
    __syncthreads();
    int h0 = lane >> 5, h1 = h0 + 2;
    float s0 = s0f[v * 4 + h0], s1 = s0f[v * 4 + h1];
    float m0 = m0f[v * 4 + h0], m1 = m0f[v * 4 + h1];
    float er0v = er[(size_t)v * 4 + h0], er1v = er[(size_t)v * 4 + h1];
    int c0 = lane, c1 = lane + 64;
    float acc0 = 0.f, acc1 = 0.f;
    for (int li = 0; li < deg; li++) {
        int s; float w0, w1;
        if (li < CW) {
            s = ssrc[wv][li];
            w0 = sexp[wv][li][h0]; w1 = sexp[wv][li][h1];
        } else {
            s = csrs[b + li];
            w0 = expf(lrelu(el[(size_t)s * 4 + h0] + er0v) - m0);
            w1 = expf(lrelu(el[(size_t)s * 4 + h1] + er1v) - m1);
        }
        int su = __builtin_amdgcn_readfirstlane(s);
        const float* zr = z + (size_t)su * HD;
        acc0 = fmaf(w0, zr[c0], acc0);
        acc1 = fmaf(w1, zr[c1], acc1);
    }
    float ts = tscale[i];
    float* xr = xk + (size_t)i * HD;
    xr[c0] = (acc0 / fmaxf(s0, 1e-16f) + b0[c0]) * ts;
    xr[c1] = (acc1 / fmaxf(s1, 1e-16f) + b0[c1]) * ts;
}

// ---------- SAGPool score ----------
__global__ void k_score(P p) {
    int v = blockIdx.x * blockDim.x + threadIdx.x;
    if (v >= NN) return;
    int b = p.off0[v], en = p.off0[v + 1];
    float acc = 0.f;
    for (int i = b; i < en; i++) acc += p.hc[p.csr_src[i]];
    float dg = fmaxf((float)(en - b), 1.f);
    float sc = acc / sqrtf(dg) + p.bc0[0];
    p.score[v] = sc;
    p.keys[v] = fkey(sc);
}

// ---------- radix select: 2 x 16-bit passes ----------
__global__ void k_hist2(P p, int level) {
    int v = blockIdx.x * blockDim.x + threadIdx.x;
    if (v >= NN) return;
    unsigned key = p.keys[v];
    if (level == 0) atomicAdd(&p.binsHi[key >> 16], 1u);
    else if ((key >> 16) == p.rs[2]) atomicAdd(&p.binsLo[key & 0xFFFFu], 1u);
}
__global__ __launch_bounds__(1024) void k_rsel2(P p, int level) {
    const unsigned* bins = level ? p.binsLo : p.binsHi;
    int K = level ? (int)p.rs[3] : KK;
    __shared__ unsigned wsm[16];
    __shared__ unsigned wpre[17];
    int t = threadIdx.x;
    unsigned base = (unsigned)t * 64;
    const uint4* b4 = (const uint4*)(bins + base);
    unsigned S = 0;
#pragma unroll
    for (int i = 0; i < 16; i++) {
        uint4 u = b4[i];
        S += u.x + u.y + u.z + u.w;
    }
    int lane = t & 63, w = t >> 6;
    unsigned val = S;
    for (int o = 1; o < 64; o <<= 1) { unsigned u = __shfl_up(val, o); if (lane >= o) val += u; }
    if (lane == 63) wsm[w] = val;
    __syncthreads();
    if (t == 0) { unsigned a = 0; for (int i = 0; i < 16; i++) { wpre[i] = a; a += wsm[i]; } wpre[16] = a; }
    __syncthreads();
    unsigned incl = wpre[w] + val;
    unsigned running = wpre[16] - incl;    // keys in strictly higher bins
    for (int i = 63; i >= 0; i--) {
        unsigned c = bins[base + i];
        unsigned above = running;
        running += c;
        if ((int)above < K && (int)running >= K) {
            if (level == 0) { p.rs[2] = base + (unsigned)i; p.rs[3] = (unsigned)(K - (int)above); }
            else { p.rs[0] = (p.rs[2] << 16) | (base + (unsigned)i); p.rs[1] = (unsigned)(K - (int)above); }
        }
    }
}
__global__ void k_sel(P p) {
    int v = blockIdx.x * blockDim.x + threadIdx.x;
    if (v >= NN) return;
    p.sel[v] = (p.keys[v] > p.rs[0]) ? 1 : 0;
}
__global__ __launch_bounds__(1024) void k_ties(P p) {   // lowest-index ties (matches top_k)
    __shared__ int base;
    __shared__ int wsums[16];
    unsigned pivot = p.rs[0];
    int need = (int)p.rs[1];
    if (threadIdx.x == 0) base = 0;
    __syncthreads();
    for (int st = 0; st < NN; st += 1024) {
        int v = st + (int)threadIdx.x;
        int flag = (v < NN && p.keys[v] == pivot) ? 1 : 0;
        unsigned long long m = __ballot(flag);
        int lane = threadIdx.x & 63, w = threadIdx.x >> 6;
        int pre = __popcll(m & ((1ull << lane) - 1ull));
        if (lane == 0) wsums[w] = __popcll(m);
        __syncthreads();
        int woff = 0;
        for (int i = 0; i < w; i++) woff += wsums[i];
        int rank = base + woff + pre;
        if (flag && rank < need) p.sel[v] = 1;
        __syncthreads();
        if (threadIdx.x == 0) {
            int s = 0;
            for (int i = 0; i < 16; i++) s += wsums[i];
            base += s;
        }
        __syncthreads();
    }
}
__global__ void k_list(P p) {
    int v = blockIdx.x * blockDim.x + threadIdx.x;
    if (v >= NN) return;
    if (p.sel[v]) {
        int i = atomicAdd(p.cnt, 1);
        p.list[i] = v;
        p.slot[v] = i;
        p.tscale[i] = tanhf(p.score[v]);
    } else {
        p.slot[v] = -1;
    }
}

// ---------- layer-1 fused GAT (wave-per-node) + res/g epilogue ----------
__global__ __launch_bounds__(256) void k_fgat2(
    const int* __restrict__ off, const int* __restrict__ csrs,
    const float* __restrict__ el, const float* __restrict__ er,
    const float* __restrict__ z, const float* __restrict__ bias,
    float* __restrict__ mf, float* __restrict__ sf,
    const float* __restrict__ gW, const float* __restrict__ gb,
    float* __restrict__ res, float* __restrict__ g) {
    __shared__ int ssrc[4][CW];
    __shared__ float sexp[4][CW][4];
    int wv = threadIdx.x >> 6, lane = threadIdx.x & 63;
    int v = blockIdx.x * 4 + wv;
    int b = off[v], e = off[v + 1], deg = e - b;
    int h = lane >> 4, sub = lane & 15;
    float4 er4 = *(const float4*)(er + (size_t)v * 4);
    float erh = ((const float*)&er4)[h];
    float m = NEGF;
    for (int li = sub; li < deg; li += 16) {
        int s = csrs[b + li];
        if (h == 0 && li < CW) ssrc[wv][li] = s;
        m = fmaxf(m, lrelu(el[(size_t)s * 4 + h] + erh));
    }
#pragma unroll
    for (int o = 1; o < 16; o <<= 1) m = fmaxf(m, __shfl_xor(m, o));
    float ssum = 0.f;
    for (int li = sub; li < deg; li += 16) {
        int s = csrs[b + li];
        float x = expf(lrelu(el[(size_t)s * 4 + h] + erh) - m);
        if (li < CW) sexp[wv][li][h] = x;
        ssum += x;
    }
#pragma unroll
    for (int o = 1; o < 16; o <<= 1) ssum += __shfl_xor(ssum, o);
    if (sub == 0) { mf[v * 4 + h] = m; sf[v * 4 + h] = ssum; }
    __syncthreads();
    int h0 = lane >> 5, h1 = h0 + 2;
    float m0 = __shfl(m, h0 << 4), m1 = __shfl(m, h1 << 4);
    float s0 = __shfl(ssum, h0 << 4), s1 = __shfl(ssum, h1 << 4);
    int c0 = lane, c1 = lane + 64;
    float acc0 = 0.f, acc1 = 0.f;
    for (int li = 0; li < deg; li++) {
        int s; float w0, w1;
        if (li < CW) {
            s = ssrc[wv][li];
            w0 = sexp[wv][li][h0]; w1 = sexp[wv][li][h1];
        } else {
            s = csrs[b + li];
            w0 = expf(lrelu(el[(size_t)s * 4 + h0] + ((const float*)&er4)[h0]) - m0);
            w1 = expf(lrelu(el[(size_t)s * 4 + h1] + ((const float*)&er4)[h1]) - m1);
        }
        int su = __builtin_amdgcn_readfirstlane(s);
        const float* zr = z + (size_t)su * HD;
        acc0 = fmaf(w0, zr[c0], acc0);
        acc1 = fmaf(w1, zr[c1], acc1);
    }
    float xc0 = acc0 / fmaxf(s0, 1e-16f) + bias[c0];
    float xc1 = acc1 / fmaxf(s1, 1e-16f) + bias[c1];
    float t = xc0 + xc1;              // x[c]+x[c+64]
    t += __shfl_xor(t, 32);           // + x[c+32]+x[c+96]
    float pg = 0.f;
    if (lane < 32) {
        float r = 0.25f * t;
        res[(size_t)v * 32 + lane] = r;
        pg = r * gW[lane];
    }
#pragma unroll
    for (int o = 1; o < 32; o <<= 1) pg += __shfl_xor(pg, o);
    if (lane == 0) g[v] = pg + gb[0];
}

// per-edge alpha outputs: pure reads, writes atten+strength for ALL edges
__global__ void k_ealpha1(P p) {
    int e = blockIdx.x * blockDim.x + threadIdx.x;
    if (e >= EE) return;
    int ds = p.ens[e], dd = p.end_[e];
    float a[4] = {0.f, 0.f, 0.f, 0.f};
    float st = 0.f;
    if (dd >= 0) {
        float4 es = *(const float4*)(p.el1 + ds * 4);
        float4 ed = *(const float4*)(p.er1 + dd * 4);
        float l[4] = {lrelu(es.x + ed.x), lrelu(es.y + ed.y), lrelu(es.z + ed.z), lrelu(es.w + ed.w)};
#pragma unroll
        for (int h = 0; h < 4; h++) {
            float m = p.m1f[dd * 4 + h];
            float ex = expf(l[h] - m);
            a[h] = ex / fmaxf(p.s1f[dd * 4 + h], 1e-16f);
        }
        st = p.strength[e];
    }
    float* o = p.out + ATT_OFF + (size_t)e * 4;
    *(float2*)(o) = make_float2(a[0], a[1]);
    *(float2*)(o + 2) = make_float2(a[2], a[3]);
    p.out[STR_OFF + e] = st;
}

// ---------- readout ----------
__global__ void k_gmax(P p) {
    __shared__ float red[256];
    int t = threadIdx.x;
    float m = -3.4e38f;
    for (int i = blockIdx.x * 256 + t; i < KK; i += gridDim.x * 256) m = fmaxf(m, p.g[i]);
    red[t] = m;
    __syncthreads();
    for (int o = 128; o > 0; o >>= 1) { if (t < o) red[t] = fmaxf(red[t], red[t + o]); __syncthreads(); }
    if (t == 0) atomicMax(p.gmaxk, fkey(red[0]));   // memset-0 identity ok
}
#define WSUM_BLOCKS 104
__global__ __launch_bounds__(256) void k_wsum(P p) {
    __shared__ double vred[256];
    __shared__ double zred[8];
    int t = threadIdx.x, il = t >> 5, d = t & 31;
    float gm = unfkey(*p.gmaxk);
    double accv = 0.0, accw = 0.0;
    for (int i = blockIdx.x * 8 + il; i < KK; i += WSUM_BLOCKS * 8) {
        float w = expf(p.g[i] - gm);
        accv += (double)(w * p.res[(size_t)i * 32 + d]);
        if (d == 0) accw += (double)w;
    }
    vred[t] = accv;
    if (d == 0) zred[il] = accw;
    __syncthreads();
    if (il == 0) {
        double s = 0;
#pragma unroll
        for (int k2 = 0; k2 < 8; k2++) s += vred[k2 * 32 + d];
        atomicAdd(&p.racc[d], s);
    }
    if (t == 32) {
        double z2 = 0;
#pragma unroll
        for (int k2 = 0; k2 < 8; k2++) z2 += zred[k2];
        atomicAdd(p.Zacc, z2);
    }
}
__global__ void k_final(P p) {
    __shared__ float rb[32];
    int t = threadIdx.x;
    double Z = *p.Zacc;
    if (t < 32) {
        float r = (float)(p.racc[t] / Z);
        p.out[t] = r;
        rb[t] = r;
    }
    __syncthreads();
    if (t < 2) {
        float s = 0.f;
        for (int d = 0; d < 32; d++) s += rb[d] * p.cW[d * 2 + t];
        p.out[32 + t] = s + p.cb[t];
    }
}

// ---------- host ----------
extern "C" void kernel_launch(void* const* d_in, const int* in_sizes, int n_in,
                              void* d_out, int out_size, void* d_ws, size_t ws_size,
                              hipStream_t stream) {
    (void)in_sizes; (void)n_in; (void)out_size; (void)ws_size;
    P p;
    p.feature  = (const float*)d_in[0];
    p.strength = (const float*)d_in[1];
    p.W0  = (const float*)d_in[2];  p.b0  = (const float*)d_in[3];
    p.al0 = (const float*)d_in[4];  p.ar0 = (const float*)d_in[5];
    p.Wc0 = (const float*)d_in[6];  p.bc0 = (const float*)d_in[7];
    p.W1  = (const float*)d_in[8];  p.b1  = (const float*)d_in[9];
    p.al1 = (const float*)d_in[10]; p.ar1 = (const float*)d_in[11];
    p.gW  = (const float*)d_in[12]; p.gb  = (const float*)d_in[13];
    p.cW  = (const float*)d_in[14]; p.cb  = (const float*)d_in[15];
    p.src = (const int*)d_in[16];   p.dst = (const int*)d_in[17];
    p.out = (float*)d_out;

    char* ws = (char*)d_ws;
    size_t off = 0;
    auto alloc = [&](size_t bytes) -> void* {
        void* r = ws + off;
        off = (off + bytes + 255) & ~(size_t)255;
        return r;
    };
    // ---- zeroed region (must stay first/contiguous) ----
    p.Zacc  = (double*)alloc(8);
    p.racc  = (double*)alloc(32 * 8);
    p.cnt   = (int*)alloc(4);
    p.gmaxk = (unsigned*)alloc(4);
    p.rs    = (unsigned*)alloc(16);
    p.binsHi = (unsigned*)alloc(65536 * 4);
    p.binsLo = (unsigned*)alloc(65536 * 4);
    size_t zbytes = off;
    // ---- big buffers (no zeroing needed; fully overwritten) ----
    p.degc_i = (unsigned char*)alloc((size_t)BCH * NN);
    p.degc_o = (unsigned char*)alloc((size_t)BCH * NN);
    p.degc1  = p.degc_i;                 // alias: degc_i dead after k_fscan0
    p.cb0 = (unsigned*)alloc((size_t)BCH * NN * 4);
    p.cb1 = p.cb0;                       // alias: cb0 dead after k_g0sc
    p.dsum = (int*)alloc((size_t)NN * 4);
    p.ens  = (int*)alloc((size_t)EE * 4);
    p.end_ = (int*)alloc((size_t)EE * 4);
    p.z0 = (float*)alloc((size_t)NN * HD * 4);
    p.xk = (float*)alloc((size_t)KK * HD * 4);
    p.z1 = (float*)alloc((size_t)KK * HD * 4);
    p.csr_src = (int*)alloc((size_t)EE * 4);
    p.rank    = (int*)alloc((size_t)EE * 4);
    p.el0 = (float*)alloc((size_t)NN * 4 * 4);
    p.er0 = (float*)alloc((size_t)NN * 4 * 4);
    p.q4  = (float*)alloc((size_t)NN * 4 * 4);
    p.m0f = (float*)alloc((size_t)NN * 4 * 4);
    p.s0f = (float*)alloc((size_t)NN * 4 * 4);
    p.b0wc = (float*)alloc(4);
    p.off0 = (int*)alloc((size_t)(NN + 1) * 4);
    p.off1 = (int*)alloc((size_t)(KK + 1) * 4);
    p.bsum = (int*)alloc(256 * 4);
    p.boff = (int*)alloc(256 * 4);
    p.hc    = (float*)alloc((size_t)NN * 4);
    p.score = (float*)alloc((size_t)NN * 4);
    p.keys  = (unsigned*)alloc((size_t)NN * 4);
    p.sel   = (int*)alloc((size_t)NN * 4);
    p.slot  = (int*)alloc((size_t)NN * 4);
    p.list  = (int*)alloc((size_t)KK * 4);
    p.tscale = (float*)alloc((size_t)KK * 4);
    p.el1 = (float*)alloc((size_t)KK * 4 * 4);
    p.er1 = (float*)alloc((size_t)KK * 4 * 4);
    p.m1f = (float*)alloc((size_t)KK * 4 * 4);
    p.s1f = (float*)alloc((size_t)KK * 4 * 4);
    p.res = (float*)alloc((size_t)KK * DD * 4);
    p.g   = (float*)alloc((size_t)KK * 4);

    const int GB_N = (NN + 255) / 256;        // 196
    const int GB_K = (KK + 255) / 256;        // 98

    hipMemsetAsync(d_ws, 0, zbytes, stream);

    // ---- GAT layer 0: count -> scan(+bases) -> (gemm0 || scatter0) ----
    k_count0<<<2 * BCH, 256, 0, stream>>>(p);
    k_bsum<<<GB_N, 256, 0, stream>>>(p.degc_i, p.bsum, NN, NN);
    k_bscan<<<1, 256, 0, stream>>>(p.bsum, GB_N, p.boff, p.off0, NN);
    k_fscan0<<<GB_N, 256, 0, stream>>>(p);
    k_g0sc<<<G0B + GB_E + 1, 256, 0, stream>>>(p);
    k_fgatlite<<<NN / 4, 256, 0, stream>>>(p.off0, p.csr_src, p.el0, p.er0, p.q4,
                                           p.dsum, p.b0wc, p.hc, p.m0f, p.s0f);

    // ---- SAGPool ----
    k_score<<<GB_N, 256, 0, stream>>>(p);
    k_hist2<<<GB_N, 256, 0, stream>>>(p, 0);
    k_rsel2<<<1, 1024, 0, stream>>>(p, 0);
    k_hist2<<<GB_N, 256, 0, stream>>>(p, 1);
    k_rsel2<<<1, 1024, 0, stream>>>(p, 1);
    k_sel<<<GB_N, 256, 0, stream>>>(p);
    k_ties<<<1, 1024, 0, stream>>>(p);
    k_list<<<GB_N, 256, 0, stream>>>(p);

    // ---- GAT layer 1: map -> count -> scan(+bases) -> fgatx -> (gemm1 || scatter1) ----
    k_emap<<<GB_E, 256, 0, stream>>>(p);
    k_count1<<<BCH, 256, 0, stream>>>(p);
    k_bsum<<<GB_K, 256, 0, stream>>>(p.degc1, p.bsum, KK, KK);
    k_bscan<<<1, 256, 0, stream>>>(p.bsum, GB_K, p.boff, p.off1, KK);
    k_fscan1<<<GB_K, 256, 0, stream>>>(p);
    k_fgatx<<<KK / 4, 256, 0, stream>>>(p.list, p.tscale, p.off0, p.csr_src,
                                        p.el0, p.er0, p.m0f, p.s0f, p.z0, p.b0, p.xk);
    k_g1sc<<<G1B + GB_E, 256, 0, stream>>>(p);
    k_fgat2<<<KK / 4, 256, 0, stream>>>(p.off1, p.csr_src, p.el1, p.er1, p.z1, p.b1,
                                        p.m1f, p.s1f, p.gW, p.gb, p.res, p.g);
    k_ealpha1<<<GB_E, 256, 0, stream>>>(p);

    // ---- readout ----
    k_gmax<<<98, 256, 0, stream>>>(p);
    k_wsum<<<WSUM_BLOCKS, 256, 0, stream>>>(p);
    k_final<<<1, 64, 0, stream>>>(p);
}

// Round 4
// 619.585 us; speedup vs baseline: 1.3952x; 1.0167x over previous
//
#include <hip/hip_runtime.h>
#include <stdint.h>

#define NN 50000
#define EE 800000
#define FIN 256
#define HD 128
#define DD 32
#define KK 25000
#define SLOPEF 0.4f
#define NEGF (-1e9f)
#define ATT_OFF 34
#define STR_OFF (34 + EE * 4)
#define CW 128             // LDS-cached edges per node (deg ~Poisson(16); recompute fallback)

// counting-sort CSR build (layer 0 only; layer 1 reuses it via slot-filtering)
#define BCH 32             // edge chunks
#define EPC (EE / BCH)     // 25000 edges per chunk

// ---------- helpers ----------
__device__ __forceinline__ unsigned fkey(float x) {
    unsigned u = __float_as_uint(x);
    return (u & 0x80000000u) ? ~u : (u | 0x80000000u);   // monotone float->uint
}
__device__ __forceinline__ float unfkey(unsigned k) {
    unsigned u = (k & 0x80000000u) ? (k ^ 0x80000000u) : ~k;
    return __uint_as_float(u);
}
__device__ __forceinline__ float lrelu(float v) { return v > 0.f ? v : SLOPEF * v; }

// device-scope (agent) atomic access: bypasses non-coherent per-XCD L2
__device__ __forceinline__ void ast(int* pp, int v) {
    __hip_atomic_store(pp, v, __ATOMIC_RELAXED, __HIP_MEMORY_SCOPE_AGENT);
}
__device__ __forceinline__ int ald(const int* pp) {
    return __hip_atomic_load(pp, __ATOMIC_RELAXED, __HIP_MEMORY_SCOPE_AGENT);
}
__device__ __forceinline__ void astu(unsigned* pp, unsigned v) {
    __hip_atomic_store(pp, v, __ATOMIC_RELAXED, __HIP_MEMORY_SCOPE_AGENT);
}
__device__ __forceinline__ unsigned aldu(const unsigned* pp) {
    return __hip_atomic_load(pp, __ATOMIC_RELAXED, __HIP_MEMORY_SCOPE_AGENT);
}

// grid barrier: distinct (cnt,flag) pair per barrier instance, zero-init'd each
// launch by the memset. Grids are <= 104 blocks (one per CU -> co-resident).
__device__ __forceinline__ void gridbar(int* cnt, int* flag, int nb) {
    __syncthreads();
    __threadfence();                      // flush this XCD's prior plain writes
    if (threadIdx.x == 0) {
        int old = __hip_atomic_fetch_add(cnt, 1, __ATOMIC_ACQ_REL, __HIP_MEMORY_SCOPE_AGENT);
        if (old == nb - 1) {
            __hip_atomic_store(flag, 1, __ATOMIC_RELEASE, __HIP_MEMORY_SCOPE_AGENT);
        } else {
            while (__hip_atomic_load(flag, __ATOMIC_ACQUIRE, __HIP_MEMORY_SCOPE_AGENT) == 0) {
                __builtin_amdgcn_s_sleep(8);
            }
        }
    }
    __syncthreads();
}

// inclusive prefix over a 1024-thread block (16 waves)
__device__ __forceinline__ int blockscan(int v, int* lds) {
    int lane = threadIdx.x & 63, w = threadIdx.x >> 6;
    int incl = v;
#pragma unroll
    for (int o = 1; o < 64; o <<= 1) { int u = __shfl_up(incl, o); if (lane >= o) incl += u; }
    __syncthreads();              // protect lds reuse across calls
    if (lane == 63) lds[w] = incl;
    __syncthreads();
    int add = 0;
    for (int i = 0; i < w; i++) add += lds[i];
    return incl + add;
}

// ---------- pointer bundle ----------
struct P {
    // inputs
    const float *feature, *strength, *W0, *b0, *al0, *ar0, *Wc0, *bc0;
    const float *W1, *b1, *al1, *ar1, *gW, *gb, *cW, *cb;
    const int *src, *dst;
    // zeroed scratch
    double *Zacc, *racc;
    int *cnt;
    unsigned *gmaxk;
    unsigned *rs;                 // [0]=pivot,[1]=need | [64]=hi bin,[65]=hi need (separate lines)
    int *bar;                     // grid-barrier (cnt,flag) pairs
    unsigned *binsHi, *binsLo;
    // other scratch
    unsigned *keys;
    unsigned char *degc_i, *degc_o;   // per-(chunk,node) u8 counts [BCH][NN]
    unsigned *cb0;                // per-(chunk,node) CSR base cursors
    int *dsum;                    // out-degree totals
    int *csr_src, *rank, *off0, *sel, *slot, *list, *bsum;
    float *z0, *el0, *er0, *q4, *m0f, *s0f, *b0wc, *hc, *score, *xk, *z1;
    float *el1, *er1, *m1f, *s1f, *res, *g, *tscale;
    float *out;                   // d_out (float32)
};

// ---------- fp32 tiled GEMM body: C[M,128] = A[M,Kd] @ B[Kd,128] ----------
#define BM 128
#define BN 64
#define BK 16
__device__ void gemm_body(
    const float* __restrict__ A, const float* __restrict__ B, float* __restrict__ C,
    int M, int Kd,
    const float* __restrict__ al, const float* __restrict__ ar,
    float* __restrict__ el, float* __restrict__ er,
    const float* __restrict__ Wc, float* __restrict__ q4,
    int bx, int by) {
    __shared__ float As[BK][BM + 4];
    __shared__ float Bs[BK][BN];
    int bm = by * BM, bn = bx * BN;
    int tid = threadIdx.x;
    int tr = tid >> 4, tc = tid & 15;
    int lrow = tid >> 1;
    int arow = (bm + lrow < M) ? (bm + lrow) : -1;
    float acc[8][4] = {};
    for (int k0 = 0; k0 < Kd; k0 += BK) {
        {
            int col = (tid & 1) << 3;
            float4 v0 = {0.f,0.f,0.f,0.f}, v1 = {0.f,0.f,0.f,0.f};
            if (arow >= 0) {
                const float* ap = A + (size_t)arow * Kd + k0 + col;
                v0 = *(const float4*)ap; v1 = *(const float4*)(ap + 4);
            }
            As[col + 0][lrow] = v0.x; As[col + 1][lrow] = v0.y;
            As[col + 2][lrow] = v0.z; As[col + 3][lrow] = v0.w;
            As[col + 4][lrow] = v1.x; As[col + 5][lrow] = v1.y;
            As[col + 6][lrow] = v1.z; As[col + 7][lrow] = v1.w;
        }
        {
            int kr = tid >> 4, col = (tid & 15) << 2;
            float4 v = *(const float4*)(B + (size_t)(k0 + kr) * HD + bn + col);
            *(float4*)&Bs[kr][col] = v;
        }
        __syncthreads();
#pragma unroll
        for (int kk = 0; kk < BK; kk++) {
            float a[8], b[4];
#pragma unroll
            for (int i = 0; i < 8; i++) a[i] = As[kk][tr * 8 + i];
#pragma unroll
            for (int j = 0; j < 4; j++) b[j] = Bs[kk][tc * 4 + j];
#pragma unroll
            for (int i = 0; i < 8; i++)
#pragma unroll
                for (int j = 0; j < 4; j++) acc[i][j] = fmaf(a[i], b[j], acc[i][j]);
        }
        __syncthreads();
    }
#pragma unroll
    for (int i = 0; i < 8; i++) {
        int gr = bm + tr * 8 + i;
        if (gr < M) {
            float4 v = {acc[i][0], acc[i][1], acc[i][2], acc[i][3]};
            *(float4*)(C + (size_t)gr * HD + bn + tc * 4) = v;
        }
    }
    int head = bx * 2 + (tc >> 3);
    int dbase = (tc & 7) * 4;
    const float* alh = al + head * 32 + dbase;
    const float* arh = ar + head * 32 + dbase;
    float a0 = alh[0], a1 = alh[1], a2 = alh[2], a3 = alh[3];
    float r0 = arh[0], r1 = arh[1], r2 = arh[2], r3 = arh[3];
    float w0 = 0.f, w1 = 0.f, w2 = 0.f, w3 = 0.f;
    if (Wc) {
        const float* wch = Wc + head * 32 + dbase;
        w0 = wch[0]; w1 = wch[1]; w2 = wch[2]; w3 = wch[3];
    }
#pragma unroll
    for (int i = 0; i < 8; i++) {
        int gr = bm + tr * 8 + i;
        float pe = acc[i][0]*a0 + acc[i][1]*a1 + acc[i][2]*a2 + acc[i][3]*a3;
        float pr = acc[i][0]*r0 + acc[i][1]*r1 + acc[i][2]*r2 + acc[i][3]*r3;
        float pq = acc[i][0]*w0 + acc[i][1]*w1 + acc[i][2]*w2 + acc[i][3]*w3;
#pragma unroll
        for (int o = 1; o < 8; o <<= 1) {
            pe += __shfl_xor(pe, o); pr += __shfl_xor(pr, o); pq += __shfl_xor(pq, o);
        }
        if ((tc & 7) == 0 && gr < M) {
            el[gr * 4 + head] = pe; er[gr * 4 + head] = pr;
            if (Wc) q4[gr * 4 + head] = pq;
        }
    }
}

// ---------- layer-0 count: full-range u8 LDS histogram; rank = old field ----------
__global__ __launch_bounds__(256) void k_count0(P p) {
    __shared__ unsigned hist[NN / 4];         // 12500 words = 50 KB, u8 counters
    int blk = blockIdx.x;
    int isD = blk < BCH;
    int c = isD ? blk : blk - BCH;
    for (int w = threadIdx.x; w < NN / 4; w += 256) hist[w] = 0u;
    __syncthreads();
    int j0 = c * EPC, j1 = j0 + EPC;
    if (isD) {
        for (int e = j0 + (int)threadIdx.x; e < j1; e += 256) {
            int d = p.dst[e];
            unsigned sh = (unsigned)(d & 3) * 8u;
            unsigned old = atomicAdd(&hist[d >> 2], 1u << sh);
            p.rank[e] = (int)((old >> sh) & 0xffu);
        }
    } else {
        for (int e = j0 + (int)threadIdx.x; e < j1; e += 256) {
            int s = p.src[e];
            atomicAdd(&hist[s >> 2], 1u << ((unsigned)(s & 3) * 8u));
        }
    }
    __syncthreads();
    unsigned* o32 = (unsigned*)((isD ? p.degc_i : p.degc_o) + (size_t)c * NN);
    for (int w = threadIdx.x; w < NN / 4; w += 256) o32[w] = hist[w];
}

// ---------- fused scan: off0 + per-chunk bases cb0 + out-degree dsum (1 bar) ----------
#define SB 64
__global__ __launch_bounds__(1024) void k_scan0(P p) {
    __shared__ int lds[16];
    __shared__ int ldsg[SB];
    __shared__ int ldsb[2];
    int tid = threadIdx.x, blk = blockIdx.x;
    int i = blk * 1024 + tid;
    int tot = 0;
    if (i < NN) {
#pragma unroll
        for (int c = 0; c < BCH; c++) tot += p.degc_i[(size_t)c * NN + i];
    }
    int incl = blockscan(tot, lds);
    if (tid == 1023) ast(&p.bsum[blk], incl);
    gridbar(&p.bar[14], &p.bar[15], SB);
    if (tid < SB) ldsg[tid] = ald(&p.bsum[tid]);
    __syncthreads();
    if (tid == 0) {
        int pre = 0, all = 0;
        for (int b2 = 0; b2 < SB; b2++) { if (b2 < blk) pre += ldsg[b2]; all += ldsg[b2]; }
        ldsb[0] = pre; ldsb[1] = all;
    }
    __syncthreads();
    if (i < NN) {
        int base = ldsb[0] + incl - tot;
        p.off0[i] = base;
        unsigned run = (unsigned)base;
        int s = 0;
#pragma unroll
        for (int c = 0; c < BCH; c++) {
            p.cb0[(size_t)c * NN + i] = run;
            run += p.degc_i[(size_t)c * NN + i];
            s += p.degc_o[(size_t)c * NN + i];
        }
        p.dsum[i] = s;
    }
    if (blk == 0 && tid == 0) p.off0[NN] = ldsb[1];
}

// ---------- MERGED: gemm0 || CSR scatter0 || b0.Wc0 prep ----------
#define G0B 782            // 2 x 391 gemm blocks
#define GB_E 3125
__global__ __launch_bounds__(256) void k_g0sc(P p) {
    int blk = blockIdx.x;
    if (blk < G0B) {
        gemm_body(p.feature, p.W0, p.z0, NN, FIN, p.al0, p.ar0, p.el0, p.er0,
                  p.Wc0, p.q4, blk & 1, blk >> 1);
    } else if (blk < G0B + GB_E) {
        int e = (blk - G0B) * 256 + threadIdx.x;
        if (e < EE) {
            int c = e / EPC;
            int d = p.dst[e];
            unsigned pos = p.cb0[(size_t)c * NN + d] + (unsigned)p.rank[e];
            p.csr_src[pos] = p.src[e];
        }
    } else {
        int l = threadIdx.x;
        if (l < 64) {
            float t = p.b0[l] * p.Wc0[l] + p.b0[l + 64] * p.Wc0[l + 64];
#pragma unroll
            for (int o = 1; o < 64; o <<= 1) t += __shfl_xor(t, o);
            if (l == 0) p.b0wc[0] = t;
        }
    }
}

// ---------- layer-0 softmax + SCALAR q-gather (all nodes) ----------
__global__ __launch_bounds__(256) void k_fgatlite(
    const int* __restrict__ off, const int* __restrict__ csrs,
    const float* __restrict__ el, const float* __restrict__ er,
    const float* __restrict__ q4, const int* __restrict__ dsum,
    const float* __restrict__ b0wc,
    float* __restrict__ hc, float* __restrict__ m0f, float* __restrict__ s0f) {
    int wv = threadIdx.x >> 6, lane = threadIdx.x & 63;
    int v = blockIdx.x * 4 + wv;
    int b = off[v], e = off[v + 1], deg = e - b;
    int h = lane >> 4, sub = lane & 15;
    float erh = er[(size_t)v * 4 + h];
    float m = NEGF;
    for (int li = sub; li < deg; li += 16) {
        int s = csrs[b + li];
        m = fmaxf(m, lrelu(el[(size_t)s * 4 + h] + erh));
    }
#pragma unroll
    for (int o = 1; o < 16; o <<= 1) m = fmaxf(m, __shfl_xor(m, o));
    float ssum = 0.f, hq = 0.f;
    for (int li = sub; li < deg; li += 16) {
        int s = csrs[b + li];
        float ex = expf(lrelu(el[(size_t)s * 4 + h] + erh) - m);
        ssum += ex;
        hq = fmaf(ex, q4[(size_t)s * 4 + h], hq);
    }
#pragma unroll
    for (int o = 1; o < 16; o <<= 1) { ssum += __shfl_xor(ssum, o); hq += __shfl_xor(hq, o); }
    if (sub == 0) { m0f[v * 4 + h] = m; s0f[v * 4 + h] = ssum; }
    float t = hq / fmaxf(ssum, 1e-16f);
    t += __shfl_xor(t, 16);
    t += __shfl_xor(t, 32);
    if (lane == 0)
        hc[v] = (t + b0wc[0]) / sqrtf(fmaxf((float)dsum[v], 1.f));
}

// ---------- fused SAGPool: score + radix-select + ties + list (7 bars) ----------
#define PB 64
__global__ __launch_bounds__(1024) void k_pool(P p) {
    __shared__ int lds[16];
    __shared__ int ldsg[PB];
    __shared__ int ldsb[2];
    int tid = threadIdx.x, blk = blockIdx.x;
    int gtid = blk * 1024 + tid;
    // phase0: SAGPool score + key + hi histogram
    if (gtid < NN) {
        int b = p.off0[gtid], en = p.off0[gtid + 1];
        float acc = 0.f;
        for (int i = b; i < en; i++) acc += p.hc[p.csr_src[i]];
        float dg = fmaxf((float)(en - b), 1.f);
        float sc = acc / sqrtf(dg) + p.bc0[0];
        p.score[gtid] = sc;
        unsigned k_ = fkey(sc);
        p.keys[gtid] = k_;
        atomicAdd(&p.binsHi[k_ >> 16], 1u);
    }
    gridbar(&p.bar[0], &p.bar[1], PB);
    // phase1: select hi bin (thread t owns bin t; above = count in strictly higher bins)
    {
        int cnt = (int)p.binsHi[gtid];
        int incl = blockscan(cnt, lds);
        if (tid == 1023) ast(&p.bsum[64 + blk], incl);
        gridbar(&p.bar[2], &p.bar[3], PB);
        if (tid < PB) ldsg[tid] = ald(&p.bsum[64 + tid]);
        __syncthreads();
        if (tid == 0) {
            int ab = 0;
            for (int b2 = PB - 1; b2 > blk; b2--) ab += ldsg[b2];
            ldsb[0] = ab; ldsb[1] = ldsg[blk];
        }
        __syncthreads();
        int above = ldsb[0] + (ldsb[1] - incl);
        if (above < KK && above + cnt >= KK) {
            astu(&p.rs[64], (unsigned)gtid);
            astu(&p.rs[65], (unsigned)(KK - above));
        }
    }
    gridbar(&p.bar[4], &p.bar[5], PB);
    // phase2: lo histogram (keys within hi bin)
    unsigned hib = aldu(&p.rs[64]);
    if (gtid < NN) {
        unsigned k_ = p.keys[gtid];
        if ((k_ >> 16) == hib) atomicAdd(&p.binsLo[k_ & 0xFFFFu], 1u);
    }
    gridbar(&p.bar[6], &p.bar[7], PB);
    // phase3: select lo bin
    int K2 = (int)aldu(&p.rs[65]);
    {
        int cnt = (int)p.binsLo[gtid];
        int incl = blockscan(cnt, lds);
        if (tid == 1023) ast(&p.bsum[128 + blk], incl);
        gridbar(&p.bar[8], &p.bar[9], PB);
        if (tid < PB) ldsg[tid] = ald(&p.bsum[128 + tid]);
        __syncthreads();
        if (tid == 0) {
            int ab = 0;
            for (int b2 = PB - 1; b2 > blk; b2--) ab += ldsg[b2];
            ldsb[0] = ab; ldsb[1] = ldsg[blk];
        }
        __syncthreads();
        int above = ldsb[0] + (ldsb[1] - incl);
        if (above < K2 && above + cnt >= K2) {
            astu(&p.rs[0], (hib << 16) | (unsigned)gtid);
            astu(&p.rs[1], (unsigned)(K2 - above));
        }
    }
    gridbar(&p.bar[10], &p.bar[11], PB);
    // phase4: tie rank (lowest-index, matches top_k) + select + list/slot/tscale
    unsigned pivot = aldu(&p.rs[0]);
    int need = (int)aldu(&p.rs[1]);
    unsigned k_ = (gtid < NN) ? p.keys[gtid] : 0u;
    int tie = (gtid < NN && k_ == pivot) ? 1 : 0;
    int incl = blockscan(tie, lds);
    if (tid == 1023) ast(&p.bsum[192 + blk], incl);
    gridbar(&p.bar[12], &p.bar[13], PB);
    if (tid < PB) ldsg[tid] = ald(&p.bsum[192 + tid]);
    __syncthreads();
    if (tid == 0) {
        int pre = 0;
        for (int b2 = 0; b2 < blk; b2++) pre += ldsg[b2];
        ldsb[0] = pre;
    }
    __syncthreads();
    int rank = ldsb[0] + incl - tie;   // exclusive prefix of ties
    if (gtid < NN) {
        int selv = (k_ > pivot) || (tie && rank < need);
        if (selv) {
            int idx = atomicAdd(p.cnt, 1);
            p.list[idx] = gtid;
            p.slot[gtid] = idx;
            p.tscale[idx] = tanhf(p.score[gtid]);
        } else {
            p.slot[gtid] = -1;
        }
    }
}

// ---------- full x for SELECTED nodes only ----------
__global__ __launch_bounds__(256) void k_fgatx(
    const int* __restrict__ list, const float* __restrict__ tscale,
    const int* __restrict__ off, const int* __restrict__ csrs,
    const float* __restrict__ el, const float* __restrict__ er,
    const float* __restrict__ m0f, const float* __restrict__ s0f,
    const float* __restrict__ z, const float* __restrict__ b0,
    float* __restrict__ xk) {
    __shared__ int ssrc[4][CW];
    __shared__ float sexp[4][CW][4];
    int wv = threadIdx.x >> 6, lane = threadIdx.x & 63;
    int i = blockIdx.x * 4 + wv;
    int v = list[i];
    int b = off[v], e = off[v + 1], deg = e - b;
    int h = lane >> 4, sub = lane & 15;
    float erh = er[(size_t)v * 4 + h];
    float mh = m0f[v * 4 + h];
    for (int li = sub; li < deg; li += 16) {
        int s = csrs[b + li];
        if (h == 0 && li < CW) ssrc[wv][li] = s;
        if (li < CW) sexp[wv][li][h] = expf(lrelu(el[(size_t)s * 4 + h] + erh) - mh);
    }
    __syncthreads();
    int h0 = lane >> 5, h1 = h0 + 2;
    float s0 = s0f[v * 4 + h0], s1 = s0f[v * 4 + h1];
    float m0 = m0f[v * 4 + h0], m1 = m0f[v * 4 + h1];
    float er0v = er[(size_t)v * 4 + h0], er1v = er[(size_t)v * 4 + h1];
    int c0 = lane, c1 = lane + 64;
    float acc0 = 0.f, acc1 = 0.f;
    for (int li = 0; li < deg; li++) {
        int s; float w0, w1;
        if (li < CW) {
            s = ssrc[wv][li];
            w0 = sexp[wv][li][h0]; w1 = sexp[wv][li][h1];
        } else {
            s = csrs[b + li];
            w0 = expf(lrelu(el[(size_t)s * 4 + h0] + er0v) - m0);
            w1 = expf(lrelu(el[(size_t)s * 4 + h1] + er1v) - m1);
        }
        int su = __builtin_amdgcn_readfirstlane(s);
        const float* zr = z + (size_t)su * HD;
        acc0 = fmaf(w0, zr[c0], acc0);
        acc1 = fmaf(w1, zr[c1], acc1);
    }
    float ts = tscale[i];
    float* xr = xk + (size_t)i * HD;
    xr[c0] = (acc0 / fmaxf(s0, 1e-16f) + b0[c0]) * ts;
    xr[c1] = (acc1 / fmaxf(s1, 1e-16f) + b0[c1]) * ts;
}

// ---------- pure gemm1 (scatter/count for layer 1 eliminated) ----------
#define G1B 392
__global__ __launch_bounds__(256) void k_gemm1(P p) {
    gemm_body(p.xk, p.W1, p.z1, KK, HD, p.al1, p.ar1, p.el1, p.er1,
              nullptr, nullptr, blockIdx.x & 1, blockIdx.x >> 1);
}

// ---------- layer-1 fused GAT: reuses LAYER-0 CSR, filters by slot ----------
__global__ __launch_bounds__(256) void k_fgat2(P p) {
    __shared__ int ssrc[4][CW];
    __shared__ float sexp[4][CW][4];
    int wv = threadIdx.x >> 6, lane = threadIdx.x & 63;
    int i = blockIdx.x * 4 + wv;          // slot index
    int v = p.list[i];                    // original node id
    int b = p.off0[v], e = p.off0[v + 1], deg = e - b;
    int h = lane >> 4, sub = lane & 15;
    float4 er4 = *(const float4*)(p.er1 + (size_t)i * 4);
    float erh = ((const float*)&er4)[h];
    float m = NEGF;
    for (int li = sub; li < deg; li += 16) {
        int so = p.csr_src[b + li];
        int ss = p.slot[so];
        if (h == 0 && li < CW) ssrc[wv][li] = ss;
        if (ss >= 0) m = fmaxf(m, lrelu(p.el1[(size_t)ss * 4 + h] + erh));
    }
#pragma unroll
    for (int o = 1; o < 16; o <<= 1) m = fmaxf(m, __shfl_xor(m, o));
    float ssum = 0.f;
    for (int li = sub; li < deg; li += 16) {
        int so = p.csr_src[b + li];
        int ss = p.slot[so];
        float x = (ss >= 0) ? expf(lrelu(p.el1[(size_t)ss * 4 + h] + erh) - m) : 0.f;
        if (li < CW) sexp[wv][li][h] = x;
        ssum += x;
    }
#pragma unroll
    for (int o = 1; o < 16; o <<= 1) ssum += __shfl_xor(ssum, o);
    if (sub == 0) { p.m1f[i * 4 + h] = m; p.s1f[i * 4 + h] = ssum; }
    __syncthreads();
    int h0 = lane >> 5, h1 = h0 + 2;
    float m0 = __shfl(m, h0 << 4), m1 = __shfl(m, h1 << 4);
    float s0 = __shfl(ssum, h0 << 4), s1 = __shfl(ssum, h1 << 4);
    int c0 = lane, c1 = lane + 64;
    float acc0 = 0.f, acc1 = 0.f;
    for (int li = 0; li < deg; li++) {
        int s; float w0, w1;
        if (li < CW) {
            s = ssrc[wv][li];
            if (s < 0) continue;          // invalid edge (wave-uniform)
            w0 = sexp[wv][li][h0]; w1 = sexp[wv][li][h1];
        } else {
            int so = p.csr_src[b + li];
            s = p.slot[so];
            if (s < 0) continue;
            w0 = expf(lrelu(p.el1[(size_t)s * 4 + h0] + ((const float*)&er4)[h0]) - m0);
            w1 = expf(lrelu(p.el1[(size_t)s * 4 + h1] + ((const float*)&er4)[h1]) - m1);
        }
        int su = __builtin_amdgcn_readfirstlane(s);
        const float* zr = p.z1 + (size_t)su * HD;
        acc0 = fmaf(w0, zr[c0], acc0);
        acc1 = fmaf(w1, zr[c1], acc1);
    }
    float xc0 = acc0 / fmaxf(s0, 1e-16f) + p.b1[c0];
    float xc1 = acc1 / fmaxf(s1, 1e-16f) + p.b1[c1];
    float t = xc0 + xc1;
    t += __shfl_xor(t, 32);
    float pg = 0.f;
    if (lane < 32) {
        float r = 0.25f * t;
        p.res[(size_t)i * 32 + lane] = r;
        pg = r * p.gW[lane];
    }
#pragma unroll
    for (int o = 1; o < 32; o <<= 1) pg += __shfl_xor(pg, o);
    if (lane == 0) p.g[i] = pg + p.gb[0];
}

// per-edge alpha outputs: slot lookups inline (emap eliminated)
__global__ void k_ealpha1(P p) {
    int e = blockIdx.x * blockDim.x + threadIdx.x;
    if (e >= EE) return;
    int ds = p.slot[p.src[e]], dd = p.slot[p.dst[e]];
    float a[4] = {0.f, 0.f, 0.f, 0.f};
    float st = 0.f;
    if (ds >= 0 && dd >= 0) {
        float4 es = *(const float4*)(p.el1 + ds * 4);
        float4 ed = *(const float4*)(p.er1 + dd * 4);
        float l[4] = {lrelu(es.x + ed.x), lrelu(es.y + ed.y), lrelu(es.z + ed.z), lrelu(es.w + ed.w)};
#pragma unroll
        for (int h = 0; h < 4; h++) {
            float m = p.m1f[dd * 4 + h];
            float ex = expf(l[h] - m);
            a[h] = ex / fmaxf(p.s1f[dd * 4 + h], 1e-16f);
        }
        st = p.strength[e];
    }
    float* o = p.out + ATT_OFF + (size_t)e * 4;
    *(float2*)(o) = make_float2(a[0], a[1]);
    *(float2*)(o + 2) = make_float2(a[2], a[3]);
    p.out[STR_OFF + e] = st;
}

// ---------- fused readout: gmax + wsum + final (2 bars) ----------
#define RB 104
__global__ __launch_bounds__(256) void k_read(P p) {
    __shared__ float redf[256];
    __shared__ double vred[256];
    __shared__ double zred[8];
    __shared__ float rb2[32];
    int t = threadIdx.x;
    // phase: global max of g
    float m = -3.4e38f;
    for (int i = blockIdx.x * 256 + t; i < KK; i += RB * 256) m = fmaxf(m, p.g[i]);
    redf[t] = m;
    __syncthreads();
    for (int o = 128; o > 0; o >>= 1) { if (t < o) redf[t] = fmaxf(redf[t], redf[t + o]); __syncthreads(); }
    if (t == 0) atomicMax(p.gmaxk, fkey(redf[0]));
    gridbar(&p.bar[16], &p.bar[17], RB);
    // phase: weighted sums
    int il = t >> 5, d = t & 31;
    float gm = unfkey(aldu(p.gmaxk));
    double accv = 0.0, accw = 0.0;
    for (int i = blockIdx.x * 8 + il; i < KK; i += RB * 8) {
        float w = expf(p.g[i] - gm);
        accv += (double)(w * p.res[(size_t)i * 32 + d]);
        if (d == 0) accw += (double)w;
    }
    vred[t] = accv;
    if (d == 0) zred[il] = accw;
    __syncthreads();
    if (il == 0) {
        double s = 0;
#pragma unroll
        for (int k2 = 0; k2 < 8; k2++) s += vred[k2 * 32 + d];
        atomicAdd(&p.racc[d], s);
    }
    if (t == 32) {
        double z2 = 0;
#pragma unroll
        for (int k2 = 0; k2 < 8; k2++) z2 += zred[k2];
        atomicAdd(p.Zacc, z2);
    }
    gridbar(&p.bar[18], &p.bar[19], RB);
    // phase: final (block 0)
    if (blockIdx.x == 0) {
        double Z = *p.Zacc;
        if (t < 32) {
            float r = (float)(p.racc[t] / Z);
            p.out[t] = r;
            rb2[t] = r;
        }
        __syncthreads();
        if (t < 2) {
            float s = 0.f;
            for (int dd2 = 0; dd2 < 32; dd2++) s += rb2[dd2] * p.cW[dd2 * 2 + t];
            p.out[32 + t] = s + p.cb[t];
        }
    }
}

// ---------- host ----------
extern "C" void kernel_launch(void* const* d_in, const int* in_sizes, int n_in,
                              void* d_out, int out_size, void* d_ws, size_t ws_size,
                              hipStream_t stream) {
    (void)in_sizes; (void)n_in; (void)out_size; (void)ws_size;
    P p;
    p.feature  = (const float*)d_in[0];
    p.strength = (const float*)d_in[1];
    p.W0  = (const float*)d_in[2];  p.b0  = (const float*)d_in[3];
    p.al0 = (const float*)d_in[4];  p.ar0 = (const float*)d_in[5];
    p.Wc0 = (const float*)d_in[6];  p.bc0 = (const float*)d_in[7];
    p.W1  = (const float*)d_in[8];  p.b1  = (const float*)d_in[9];
    p.al1 = (const float*)d_in[10]; p.ar1 = (const float*)d_in[11];
    p.gW  = (const float*)d_in[12]; p.gb  = (const float*)d_in[13];
    p.cW  = (const float*)d_in[14]; p.cb  = (const float*)d_in[15];
    p.src = (const int*)d_in[16];   p.dst = (const int*)d_in[17];
    p.out = (float*)d_out;

    char* ws = (char*)d_ws;
    size_t off = 0;
    auto alloc = [&](size_t bytes) -> void* {
        void* r = ws + off;
        off = (off + bytes + 255) & ~(size_t)255;
        return r;
    };
    // ---- zeroed region (must stay first/contiguous) ----
    p.Zacc  = (double*)alloc(8);
    p.racc  = (double*)alloc(32 * 8);
    p.cnt   = (int*)alloc(4);
    p.gmaxk = (unsigned*)alloc(4);
    p.rs    = (unsigned*)alloc(128 * 4);   // [0..1] on line 0, [64..65] on line 1
    p.bar   = (int*)alloc(32 * 4);         // grid-barrier pairs
    p.binsHi = (unsigned*)alloc(65536 * 4);
    p.binsLo = (unsigned*)alloc(65536 * 4);
    size_t zbytes = off;
    // ---- big buffers (fully overwritten each run) ----
    p.degc_i = (unsigned char*)alloc((size_t)BCH * NN);
    p.degc_o = (unsigned char*)alloc((size_t)BCH * NN);
    p.cb0 = (unsigned*)alloc((size_t)BCH * NN * 4);
    p.dsum = (int*)alloc((size_t)NN * 4);
    p.z0 = (float*)alloc((size_t)NN * HD * 4);
    p.xk = (float*)alloc((size_t)KK * HD * 4);
    p.z1 = (float*)alloc((size_t)KK * HD * 4);
    p.csr_src = (int*)alloc((size_t)EE * 4);
    p.rank    = (int*)alloc((size_t)EE * 4);
    p.el0 = (float*)alloc((size_t)NN * 4 * 4);
    p.er0 = (float*)alloc((size_t)NN * 4 * 4);
    p.q4  = (float*)alloc((size_t)NN * 4 * 4);
    p.m0f = (float*)alloc((size_t)NN * 4 * 4);
    p.s0f = (float*)alloc((size_t)NN * 4 * 4);
    p.b0wc = (float*)alloc(4);
    p.off0 = (int*)alloc((size_t)(NN + 1) * 4);
    p.bsum = (int*)alloc(256 * 4);
    p.hc    = (float*)alloc((size_t)NN * 4);
    p.score = (float*)alloc((size_t)NN * 4);
    p.keys  = (unsigned*)alloc((size_t)NN * 4);
    p.sel   = (int*)alloc((size_t)NN * 4);
    p.slot  = (int*)alloc((size_t)NN * 4);
    p.list  = (int*)alloc((size_t)KK * 4);
    p.tscale = (float*)alloc((size_t)KK * 4);
    p.el1 = (float*)alloc((size_t)KK * 4 * 4);
    p.er1 = (float*)alloc((size_t)KK * 4 * 4);
    p.m1f = (float*)alloc((size_t)KK * 4 * 4);
    p.s1f = (float*)alloc((size_t)KK * 4 * 4);
    p.res = (float*)alloc((size_t)KK * DD * 4);
    p.g   = (float*)alloc((size_t)KK * 4);

    hipMemsetAsync(d_ws, 0, zbytes, stream);

    // ---- GAT layer 0: count -> fused scan -> (gemm0 || scatter0) -> fgatlite ----
    k_count0<<<2 * BCH, 256, 0, stream>>>(p);
    k_scan0<<<SB, 1024, 0, stream>>>(p);
    k_g0sc<<<G0B + GB_E + 1, 256, 0, stream>>>(p);
    k_fgatlite<<<NN / 4, 256, 0, stream>>>(p.off0, p.csr_src, p.el0, p.er0, p.q4,
                                           p.dsum, p.b0wc, p.hc, p.m0f, p.s0f);

    // ---- SAGPool (single fused kernel) ----
    k_pool<<<PB, 1024, 0, stream>>>(p);

    // ---- GAT layer 1: fgatx -> gemm1 -> fgat2 (layer-0 CSR reused) ----
    k_fgatx<<<KK / 4, 256, 0, stream>>>(p.list, p.tscale, p.off0, p.csr_src,
                                        p.el0, p.er0, p.m0f, p.s0f, p.z0, p.b0, p.xk);
    k_gemm1<<<G1B, 256, 0, stream>>>(p);
    k_fgat2<<<KK / 4, 256, 0, stream>>>(p);
    k_ealpha1<<<GB_E, 256, 0, stream>>>(p);

    // ---- readout (single fused kernel) ----
    k_read<<<RB, 256, 0, stream>>>(p);
}

// Round 5
// 588.848 us; speedup vs baseline: 1.4680x; 1.0522x over previous
//
#include <hip/hip_runtime.h>
#include <stdint.h>

#define NN 50000
#define EE 800000
#define FIN 256
#define HD 128
#define DD 32
#define KK 25000
#define SLOPEF 0.4f
#define NEGF (-1e9f)
#define ATT_OFF 34
#define STR_OFF (34 + EE * 4)
#define CW 128             // LDS-cached edges per node (deg ~Poisson(16); recompute fallback)

// counting-sort CSR build (layer 0 only; layer 1 reuses it via slot-filtering)
#define BCH 32             // edge chunks
#define EPC (EE / BCH)     // 25000 edges per chunk

// ---------- helpers ----------
__device__ __forceinline__ unsigned fkey(float x) {
    unsigned u = __float_as_uint(x);
    return (u & 0x80000000u) ? ~u : (u | 0x80000000u);   // monotone float->uint
}
__device__ __forceinline__ float unfkey(unsigned k) {
    unsigned u = (k & 0x80000000u) ? (k ^ 0x80000000u) : ~k;
    return __uint_as_float(u);
}
__device__ __forceinline__ float lrelu(float v) { return v > 0.f ? v : SLOPEF * v; }

// device-scope (agent) atomic access: bypasses non-coherent per-XCD L2
__device__ __forceinline__ void ast(int* pp, int v) {
    __hip_atomic_store(pp, v, __ATOMIC_RELAXED, __HIP_MEMORY_SCOPE_AGENT);
}
__device__ __forceinline__ int ald(const int* pp) {
    return __hip_atomic_load(pp, __ATOMIC_RELAXED, __HIP_MEMORY_SCOPE_AGENT);
}
__device__ __forceinline__ unsigned aldu(const unsigned* pp) {
    return __hip_atomic_load(pp, __ATOMIC_RELAXED, __HIP_MEMORY_SCOPE_AGENT);
}

// grid barrier: distinct (cnt,flag) pair per barrier instance, zero-init'd each
// launch by the memset. Grids are <= 104 blocks (co-resident).
__device__ __forceinline__ void gridbar(int* cnt, int* flag, int nb) {
    __syncthreads();
    __threadfence();
    if (threadIdx.x == 0) {
        int old = __hip_atomic_fetch_add(cnt, 1, __ATOMIC_ACQ_REL, __HIP_MEMORY_SCOPE_AGENT);
        if (old == nb - 1) {
            __hip_atomic_store(flag, 1, __ATOMIC_RELEASE, __HIP_MEMORY_SCOPE_AGENT);
        } else {
            while (__hip_atomic_load(flag, __ATOMIC_ACQUIRE, __HIP_MEMORY_SCOPE_AGENT) == 0) {
                __builtin_amdgcn_s_sleep(8);
            }
        }
    }
    __syncthreads();
}

// inclusive prefix over a 1024-thread block (16 waves)
__device__ __forceinline__ int blockscan(int v, int* lds) {
    int lane = threadIdx.x & 63, w = threadIdx.x >> 6;
    int incl = v;
#pragma unroll
    for (int o = 1; o < 64; o <<= 1) { int u = __shfl_up(incl, o); if (lane >= o) incl += u; }
    __syncthreads();              // protect lds reuse across calls
    if (lane == 63) lds[w] = incl;
    __syncthreads();
    int add = 0;
    for (int i = 0; i < w; i++) add += lds[i];
    return incl + add;
}

// ---------- pointer bundle ----------
struct P {
    // inputs
    const float *feature, *strength, *W0, *b0, *al0, *ar0, *Wc0, *bc0;
    const float *W1, *b1, *al1, *ar1, *gW, *gb, *cW, *cb;
    const int *src, *dst;
    // zeroed scratch
    double *Zacc, *racc;
    int *cnt;
    unsigned *gmaxk;
    int *bar;                     // grid-barrier (cnt,flag) pairs
    unsigned *bins4;              // 4 levels x 256 bins (8-bit radix select)
    // other scratch
    unsigned char *degc_i, *degc_o;   // per-(chunk,node) u8 counts [BCH][NN]
    unsigned *cb0;                // per-(chunk,node) CSR base cursors
    int *dsum;                    // out-degree totals
    int *csr_src, *rank, *off0, *slot, *list, *bsum;
    float *z0, *el0, *er0, *q4, *m0f, *s0f, *b0wc, *hc, *xk, *z1;
    float *el1, *er1, *m1f, *s1f, *res, *g, *tscale;
    float *out;                   // d_out (float32)
};

// ---------- fp32 tiled GEMM body: C[M,128] = A[M,Kd] @ B[Kd,128] ----------
#define BM 128
#define BN 64
#define BK 16
__device__ void gemm_body(
    const float* __restrict__ A, const float* __restrict__ B, float* __restrict__ C,
    int M, int Kd,
    const float* __restrict__ al, const float* __restrict__ ar,
    float* __restrict__ el, float* __restrict__ er,
    const float* __restrict__ Wc, float* __restrict__ q4,
    int bx, int by) {
    __shared__ float As[BK][BM + 4];
    __shared__ float Bs[BK][BN];
    int bm = by * BM, bn = bx * BN;
    int tid = threadIdx.x;
    int tr = tid >> 4, tc = tid & 15;
    int lrow = tid >> 1;
    int arow = (bm + lrow < M) ? (bm + lrow) : -1;
    float acc[8][4] = {};
    for (int k0 = 0; k0 < Kd; k0 += BK) {
        {
            int col = (tid & 1) << 3;
            float4 v0 = {0.f,0.f,0.f,0.f}, v1 = {0.f,0.f,0.f,0.f};
            if (arow >= 0) {
                const float* ap = A + (size_t)arow * Kd + k0 + col;
                v0 = *(const float4*)ap; v1 = *(const float4*)(ap + 4);
            }
            As[col + 0][lrow] = v0.x; As[col + 1][lrow] = v0.y;
            As[col + 2][lrow] = v0.z; As[col + 3][lrow] = v0.w;
            As[col + 4][lrow] = v1.x; As[col + 5][lrow] = v1.y;
            As[col + 6][lrow] = v1.z; As[col + 7][lrow] = v1.w;
        }
        {
            int kr = tid >> 4, col = (tid & 15) << 2;
            float4 v = *(const float4*)(B + (size_t)(k0 + kr) * HD + bn + col);
            *(float4*)&Bs[kr][col] = v;
        }
        __syncthreads();
#pragma unroll
        for (int kk = 0; kk < BK; kk++) {
            float a[8], b[4];
#pragma unroll
            for (int i = 0; i < 8; i++) a[i] = As[kk][tr * 8 + i];
#pragma unroll
            for (int j = 0; j < 4; j++) b[j] = Bs[kk][tc * 4 + j];
#pragma unroll
            for (int i = 0; i < 8; i++)
#pragma unroll
                for (int j = 0; j < 4; j++) acc[i][j] = fmaf(a[i], b[j], acc[i][j]);
        }
        __syncthreads();
    }
#pragma unroll
    for (int i = 0; i < 8; i++) {
        int gr = bm + tr * 8 + i;
        if (gr < M) {
            float4 v = {acc[i][0], acc[i][1], acc[i][2], acc[i][3]};
            *(float4*)(C + (size_t)gr * HD + bn + tc * 4) = v;
        }
    }
    int head = bx * 2 + (tc >> 3);
    int dbase = (tc & 7) * 4;
    const float* alh = al + head * 32 + dbase;
    const float* arh = ar + head * 32 + dbase;
    float a0 = alh[0], a1 = alh[1], a2 = alh[2], a3 = alh[3];
    float r0 = arh[0], r1 = arh[1], r2 = arh[2], r3 = arh[3];
    float w0 = 0.f, w1 = 0.f, w2 = 0.f, w3 = 0.f;
    if (Wc) {
        const float* wch = Wc + head * 32 + dbase;
        w0 = wch[0]; w1 = wch[1]; w2 = wch[2]; w3 = wch[3];
    }
#pragma unroll
    for (int i = 0; i < 8; i++) {
        int gr = bm + tr * 8 + i;
        float pe = acc[i][0]*a0 + acc[i][1]*a1 + acc[i][2]*a2 + acc[i][3]*a3;
        float pr = acc[i][0]*r0 + acc[i][1]*r1 + acc[i][2]*r2 + acc[i][3]*r3;
        float pq = acc[i][0]*w0 + acc[i][1]*w1 + acc[i][2]*w2 + acc[i][3]*w3;
#pragma unroll
        for (int o = 1; o < 8; o <<= 1) {
            pe += __shfl_xor(pe, o); pr += __shfl_xor(pr, o); pq += __shfl_xor(pq, o);
        }
        if ((tc & 7) == 0 && gr < M) {
            el[gr * 4 + head] = pe; er[gr * 4 + head] = pr;
            if (Wc) q4[gr * 4 + head] = pq;
        }
    }
}

// ---------- layer-0 count: full-range u8 LDS histogram; rank = old field ----------
__global__ __launch_bounds__(256) void k_count0(P p) {
    __shared__ unsigned hist[NN / 4];         // 12500 words = 50 KB, u8 counters
    int blk = blockIdx.x;
    int isD = blk < BCH;
    int c = isD ? blk : blk - BCH;
    for (int w = threadIdx.x; w < NN / 4; w += 256) hist[w] = 0u;
    __syncthreads();
    int j0 = c * EPC, j1 = j0 + EPC;
    if (isD) {
        for (int e = j0 + (int)threadIdx.x; e < j1; e += 256) {
            int d = p.dst[e];
            unsigned sh = (unsigned)(d & 3) * 8u;
            unsigned old = atomicAdd(&hist[d >> 2], 1u << sh);
            p.rank[e] = (int)((old >> sh) & 0xffu);
        }
    } else {
        for (int e = j0 + (int)threadIdx.x; e < j1; e += 256) {
            int s = p.src[e];
            atomicAdd(&hist[s >> 2], 1u << ((unsigned)(s & 3) * 8u));
        }
    }
    __syncthreads();
    unsigned* o32 = (unsigned*)((isD ? p.degc_i : p.degc_o) + (size_t)c * NN);
    for (int w = threadIdx.x; w < NN / 4; w += 256) o32[w] = hist[w];
}

// ---------- fused scan: off0 + per-chunk bases cb0 + out-degree dsum (1 bar) ----------
#define SB 64
__global__ __launch_bounds__(1024) void k_scan0(P p) {
    __shared__ int lds[16];
    __shared__ int ldsg[SB];
    __shared__ int ldsb[2];
    int tid = threadIdx.x, blk = blockIdx.x;
    int i = blk * 1024 + tid;
    int tot = 0;
    if (i < NN) {
#pragma unroll
        for (int c = 0; c < BCH; c++) tot += p.degc_i[(size_t)c * NN + i];
    }
    int incl = blockscan(tot, lds);
    if (tid == 1023) ast(&p.bsum[blk], incl);
    gridbar(&p.bar[14], &p.bar[15], SB);
    if (tid < SB) ldsg[tid] = ald(&p.bsum[tid]);
    __syncthreads();
    if (tid == 0) {
        int pre = 0, all = 0;
        for (int b2 = 0; b2 < SB; b2++) { if (b2 < blk) pre += ldsg[b2]; all += ldsg[b2]; }
        ldsb[0] = pre; ldsb[1] = all;
    }
    __syncthreads();
    if (i < NN) {
        int base = ldsb[0] + incl - tot;
        p.off0[i] = base;
        unsigned run = (unsigned)base;
        int s = 0;
#pragma unroll
        for (int c = 0; c < BCH; c++) {
            p.cb0[(size_t)c * NN + i] = run;
            run += p.degc_i[(size_t)c * NN + i];
            s += p.degc_o[(size_t)c * NN + i];
        }
        p.dsum[i] = s;
    }
    if (blk == 0 && tid == 0) p.off0[NN] = ldsb[1];
}

// ---------- MERGED: gemm0 || CSR scatter0 || b0.Wc0 prep ----------
#define G0B 782            // 2 x 391 gemm blocks
#define GB_E 3125
__global__ __launch_bounds__(256) void k_g0sc(P p) {
    int blk = blockIdx.x;
    if (blk < G0B) {
        gemm_body(p.feature, p.W0, p.z0, NN, FIN, p.al0, p.ar0, p.el0, p.er0,
                  p.Wc0, p.q4, blk & 1, blk >> 1);
    } else if (blk < G0B + GB_E) {
        int e = (blk - G0B) * 256 + threadIdx.x;
        if (e < EE) {
            int c = e / EPC;
            int d = p.dst[e];
            unsigned pos = p.cb0[(size_t)c * NN + d] + (unsigned)p.rank[e];
            p.csr_src[pos] = p.src[e];
        }
    } else {
        int l = threadIdx.x;
        if (l < 64) {
            float t = p.b0[l] * p.Wc0[l] + p.b0[l + 64] * p.Wc0[l + 64];
#pragma unroll
            for (int o = 1; o < 64; o <<= 1) t += __shfl_xor(t, o);
            if (l == 0) p.b0wc[0] = t;
        }
    }
}

// ---------- layer-0 softmax + SCALAR q-gather (all nodes) ----------
__global__ __launch_bounds__(256) void k_fgatlite(
    const int* __restrict__ off, const int* __restrict__ csrs,
    const float* __restrict__ el, const float* __restrict__ er,
    const float* __restrict__ q4, const int* __restrict__ dsum,
    const float* __restrict__ b0wc,
    float* __restrict__ hc, float* __restrict__ m0f, float* __restrict__ s0f) {
    int wv = threadIdx.x >> 6, lane = threadIdx.x & 63;
    int v = blockIdx.x * 4 + wv;
    int b = off[v], e = off[v + 1], deg = e - b;
    int h = lane >> 4, sub = lane & 15;
    float erh = er[(size_t)v * 4 + h];
    float m = NEGF;
    for (int li = sub; li < deg; li += 16) {
        int s = csrs[b + li];
        m = fmaxf(m, lrelu(el[(size_t)s * 4 + h] + erh));
    }
#pragma unroll
    for (int o = 1; o < 16; o <<= 1) m = fmaxf(m, __shfl_xor(m, o));
    float ssum = 0.f, hq = 0.f;
    for (int li = sub; li < deg; li += 16) {
        int s = csrs[b + li];
        float ex = expf(lrelu(el[(size_t)s * 4 + h] + erh) - m);
        ssum += ex;
        hq = fmaf(ex, q4[(size_t)s * 4 + h], hq);
    }
#pragma unroll
    for (int o = 1; o < 16; o <<= 1) { ssum += __shfl_xor(ssum, o); hq += __shfl_xor(hq, o); }
    if (sub == 0) { m0f[v * 4 + h] = m; s0f[v * 4 + h] = ssum; }
    float t = hq / fmaxf(ssum, 1e-16f);
    t += __shfl_xor(t, 16);
    t += __shfl_xor(t, 32);
    if (lane == 0)
        hc[v] = (t + b0wc[0]) / sqrtf(fmaxf((float)dsum[v], 1.f));
}

// ---------- fused SAGPool: score + 4x8-bit LDS-radix-select + ties + list ----------
// (5 grid barriers; no hot-address global atomics: per-block 256-bin LDS hist,
//  merged with <=256 atomics/block spread over 256 addresses)
#define PB 64
__global__ __launch_bounds__(1024) void k_pool(P p) {
    __shared__ int lds[16];
    __shared__ unsigned sb[256];
    __shared__ int ldsg[PB];
    __shared__ int ldsb[2];
    __shared__ unsigned selres[2];
    int tid = threadIdx.x, blk = blockIdx.x;
    int gtid = blk * 1024 + tid;
    int valid = (gtid < NN);
    // phase0: SAGPool score + key, all in registers
    float sc = 0.f;
    unsigned key = 0u;
    if (valid) {
        int b = p.off0[gtid], en = p.off0[gtid + 1];
        float acc = 0.f;
        for (int i = b; i < en; i++) acc += p.hc[p.csr_src[i]];
        float dg = fmaxf((float)(en - b), 1.f);
        sc = acc / sqrtf(dg) + p.bc0[0];
        key = fkey(sc);
    }
    // 4-level 8-bit radix select (every block computes pivot redundantly)
    unsigned pref = 0u;
    int K = KK;
#pragma unroll
    for (int l = 0; l < 4; l++) {
        int sh = 24 - 8 * l;
        if (tid < 256) sb[tid] = 0u;
        __syncthreads();
        int cand = valid && ((l == 0) || ((key >> (sh + 8)) == pref));
        if (cand) atomicAdd(&sb[(key >> sh) & 0xFFu], 1u);
        __syncthreads();
        if (tid < 256 && sb[tid]) atomicAdd(&p.bins4[l * 256 + tid], sb[tid]);
        gridbar(&p.bar[2 * l], &p.bar[2 * l + 1], PB);
        unsigned cnt = (tid < 256) ? aldu(&p.bins4[l * 256 + tid]) : 0u;
        int incl = blockscan((int)cnt, lds);
        if (tid == 255) ldsb[0] = incl;          // total over 256 bins
        __syncthreads();
        int total = ldsb[0];
        int above = total - incl;                // strictly higher bins
        if (tid < 256 && above < K && above + (int)cnt >= K) {
            selres[0] = (unsigned)tid;
            selres[1] = (unsigned)(K - above);
        }
        __syncthreads();
        pref = (pref << 8) | selres[0];
        K = (int)selres[1];
        __syncthreads();
    }
    unsigned pivot = pref;
    int need = K;
    // tie phase: lowest-index ties (matches top_k) + select + list/slot/tscale
    int tie = (valid && key == pivot) ? 1 : 0;
    int incl2 = blockscan(tie, lds);
    if (tid == 1023) ast(&p.bsum[blk], incl2);
    gridbar(&p.bar[8], &p.bar[9], PB);
    if (tid < PB) ldsg[tid] = ald(&p.bsum[tid]);
    __syncthreads();
    if (tid == 0) {
        int pre = 0;
        for (int b2 = 0; b2 < blk; b2++) pre += ldsg[b2];
        ldsb[0] = pre;
    }
    __syncthreads();
    int rank = ldsb[0] + incl2 - tie;            // exclusive prefix of ties
    if (valid) {
        int selv = (key > pivot) || (tie && rank < need);
        if (selv) {
            int idx = atomicAdd(p.cnt, 1);       // uniform addr -> wave-coalesced
            p.list[idx] = gtid;
            p.slot[gtid] = idx;
            p.tscale[idx] = tanhf(sc);
        } else {
            p.slot[gtid] = -1;
        }
    }
}

// ---------- full x for SELECTED nodes only ----------
__global__ __launch_bounds__(256) void k_fgatx(
    const int* __restrict__ list, const float* __restrict__ tscale,
    const int* __restrict__ off, const int* __restrict__ csrs,
    const float* __restrict__ el, const float* __restrict__ er,
    const float* __restrict__ m0f, const float* __restrict__ s0f,
    const float* __restrict__ z, const float* __restrict__ b0,
    float* __restrict__ xk) {
    __shared__ int ssrc[4][CW];
    __shared__ float sexp[4][CW][4];
    int wv = threadIdx.x >> 6, lane = threadIdx.x & 63;
    int i = blockIdx.x * 4 + wv;
    int v = list[i];
    int b = off[v], e = off[v + 1], deg = e - b;
    int h = lane >> 4, sub = lane & 15;
    float erh = er[(size_t)v * 4 + h];
    float mh = m0f[v * 4 + h];
    for (int li = sub; li < deg; li += 16) {
        int s = csrs[b + li];
        if (h == 0 && li < CW) ssrc[wv][li] = s;
        if (li < CW) sexp[wv][li][h] = expf(lrelu(el[(size_t)s * 4 + h] + erh) - mh);
    }
    __syncthreads();
    int h0 = lane >> 5, h1 = h0 + 2;
    float s0 = s0f[v * 4 + h0], s1 = s0f[v * 4 + h1];
    float m0 = m0f[v * 4 + h0], m1 = m0f[v * 4 + h1];
    float er0v = er[(size_t)v * 4 + h0], er1v = er[(size_t)v * 4 + h1];
    int c0 = lane, c1 = lane + 64;
    float acc0 = 0.f, acc1 = 0.f;
    for (int li = 0; li < deg; li++) {
        int s; float w0, w1;
        if (li < CW) {
            s = ssrc[wv][li];
            w0 = sexp[wv][li][h0]; w1 = sexp[wv][li][h1];
        } else {
            s = csrs[b + li];
            w0 = expf(lrelu(el[(size_t)s * 4 + h0] + er0v) - m0);
            w1 = expf(lrelu(el[(size_t)s * 4 + h1] + er1v) - m1);
        }
        int su = __builtin_amdgcn_readfirstlane(s);
        const float* zr = z + (size_t)su * HD;
        acc0 = fmaf(w0, zr[c0], acc0);
        acc1 = fmaf(w1, zr[c1], acc1);
    }
    float ts = tscale[i];
    float* xr = xk + (size_t)i * HD;
    xr[c0] = (acc0 / fmaxf(s0, 1e-16f) + b0[c0]) * ts;
    xr[c1] = (acc1 / fmaxf(s1, 1e-16f) + b0[c1]) * ts;
}

// ---------- pure gemm1 ----------
#define G1B 392
__global__ __launch_bounds__(256) void k_gemm1(P p) {
    gemm_body(p.xk, p.W1, p.z1, KK, HD, p.al1, p.ar1, p.el1, p.er1,
              nullptr, nullptr, blockIdx.x & 1, blockIdx.x >> 1);
}

// ---------- layer-1 fused GAT: reuses LAYER-0 CSR, filters by slot ----------
__global__ __launch_bounds__(256) void k_fgat2(P p) {
    __shared__ int ssrc[4][CW];
    __shared__ float sexp[4][CW][4];
    int wv = threadIdx.x >> 6, lane = threadIdx.x & 63;
    int i = blockIdx.x * 4 + wv;          // slot index
    int v = p.list[i];                    // original node id
    int b = p.off0[v], e = p.off0[v + 1], deg = e - b;
    int h = lane >> 4, sub = lane & 15;
    float4 er4 = *(const float4*)(p.er1 + (size_t)i * 4);
    float erh = ((const float*)&er4)[h];
    float m = NEGF;
    for (int li = sub; li < deg; li += 16) {
        int so = p.csr_src[b + li];
        int ss = p.slot[so];
        if (h == 0 && li < CW) ssrc[wv][li] = ss;
        if (ss >= 0) m = fmaxf(m, lrelu(p.el1[(size_t)ss * 4 + h] + erh));
    }
#pragma unroll
    for (int o = 1; o < 16; o <<= 1) m = fmaxf(m, __shfl_xor(m, o));
    float ssum = 0.f;
    for (int li = sub; li < deg; li += 16) {
        int so = p.csr_src[b + li];
        int ss = p.slot[so];
        float x = (ss >= 0) ? expf(lrelu(p.el1[(size_t)ss * 4 + h] + erh) - m) : 0.f;
        if (li < CW) sexp[wv][li][h] = x;
        ssum += x;
    }
#pragma unroll
    for (int o = 1; o < 16; o <<= 1) ssum += __shfl_xor(ssum, o);
    if (sub == 0) { p.m1f[i * 4 + h] = m; p.s1f[i * 4 + h] = ssum; }
    __syncthreads();
    int h0 = lane >> 5, h1 = h0 + 2;
    float m0 = __shfl(m, h0 << 4), m1 = __shfl(m, h1 << 4);
    float s0 = __shfl(ssum, h0 << 4), s1 = __shfl(ssum, h1 << 4);
    int c0 = lane, c1 = lane + 64;
    float acc0 = 0.f, acc1 = 0.f;
    for (int li = 0; li < deg; li++) {
        int s; float w0, w1;
        if (li < CW) {
            s = ssrc[wv][li];
            if (s < 0) continue;
            w0 = sexp[wv][li][h0]; w1 = sexp[wv][li][h1];
        } else {
            int so = p.csr_src[b + li];
            s = p.slot[so];
            if (s < 0) continue;
            w0 = expf(lrelu(p.el1[(size_t)s * 4 + h0] + ((const float*)&er4)[h0]) - m0);
            w1 = expf(lrelu(p.el1[(size_t)s * 4 + h1] + ((const float*)&er4)[h1]) - m1);
        }
        int su = __builtin_amdgcn_readfirstlane(s);
        const float* zr = p.z1 + (size_t)su * HD;
        acc0 = fmaf(w0, zr[c0], acc0);
        acc1 = fmaf(w1, zr[c1], acc1);
    }
    float xc0 = acc0 / fmaxf(s0, 1e-16f) + p.b1[c0];
    float xc1 = acc1 / fmaxf(s1, 1e-16f) + p.b1[c1];
    float t = xc0 + xc1;
    t += __shfl_xor(t, 32);
    float pg = 0.f;
    if (lane < 32) {
        float r = 0.25f * t;
        p.res[(size_t)i * 32 + lane] = r;
        pg = r * p.gW[lane];
    }
#pragma unroll
    for (int o = 1; o < 32; o <<= 1) pg += __shfl_xor(pg, o);
    if (lane == 0) p.g[i] = pg + p.gb[0];
}

// per-edge alpha outputs
__global__ void k_ealpha1(P p) {
    int e = blockIdx.x * blockDim.x + threadIdx.x;
    if (e >= EE) return;
    int ds = p.slot[p.src[e]], dd = p.slot[p.dst[e]];
    float a[4] = {0.f, 0.f, 0.f, 0.f};
    float st = 0.f;
    if (ds >= 0 && dd >= 0) {
        float4 es = *(const float4*)(p.el1 + ds * 4);
        float4 ed = *(const float4*)(p.er1 + dd * 4);
        float l[4] = {lrelu(es.x + ed.x), lrelu(es.y + ed.y), lrelu(es.z + ed.z), lrelu(es.w + ed.w)};
#pragma unroll
        for (int h = 0; h < 4; h++) {
            float m = p.m1f[dd * 4 + h];
            float ex = expf(l[h] - m);
            a[h] = ex / fmaxf(p.s1f[dd * 4 + h], 1e-16f);
        }
        st = p.strength[e];
    }
    float* o = p.out + ATT_OFF + (size_t)e * 4;
    *(float2*)(o) = make_float2(a[0], a[1]);
    *(float2*)(o + 2) = make_float2(a[2], a[3]);
    p.out[STR_OFF + e] = st;
}

// ---------- fused readout: gmax + wsum + final (2 bars) ----------
#define RB 104
__global__ __launch_bounds__(256) void k_read(P p) {
    __shared__ float redf[256];
    __shared__ double vred[256];
    __shared__ double zred[8];
    __shared__ float rb2[32];
    int t = threadIdx.x;
    float m = -3.4e38f;
    for (int i = blockIdx.x * 256 + t; i < KK; i += RB * 256) m = fmaxf(m, p.g[i]);
    redf[t] = m;
    __syncthreads();
    for (int o = 128; o > 0; o >>= 1) { if (t < o) redf[t] = fmaxf(redf[t], redf[t + o]); __syncthreads(); }
    if (t == 0) atomicMax(p.gmaxk, fkey(redf[0]));
    gridbar(&p.bar[16], &p.bar[17], RB);
    int il = t >> 5, d = t & 31;
    float gm = unfkey(aldu(p.gmaxk));
    double accv = 0.0, accw = 0.0;
    for (int i = blockIdx.x * 8 + il; i < KK; i += RB * 8) {
        float w = expf(p.g[i] - gm);
        accv += (double)(w * p.res[(size_t)i * 32 + d]);
        if (d == 0) accw += (double)w;
    }
    vred[t] = accv;
    if (d == 0) zred[il] = accw;
    __syncthreads();
    if (il == 0) {
        double s = 0;
#pragma unroll
        for (int k2 = 0; k2 < 8; k2++) s += vred[k2 * 32 + d];
        atomicAdd(&p.racc[d], s);
    }
    if (t == 32) {
        double z2 = 0;
#pragma unroll
        for (int k2 = 0; k2 < 8; k2++) z2 += zred[k2];
        atomicAdd(p.Zacc, z2);
    }
    gridbar(&p.bar[18], &p.bar[19], RB);
    if (blockIdx.x == 0) {
        double Z = *p.Zacc;
        if (t < 32) {
            float r = (float)(p.racc[t] / Z);
            p.out[t] = r;
            rb2[t] = r;
        }
        __syncthreads();
        if (t < 2) {
            float s = 0.f;
            for (int dd2 = 0; dd2 < 32; dd2++) s += rb2[dd2] * p.cW[dd2 * 2 + t];
            p.out[32 + t] = s + p.cb[t];
        }
    }
}

// ---------- host ----------
extern "C" void kernel_launch(void* const* d_in, const int* in_sizes, int n_in,
                              void* d_out, int out_size, void* d_ws, size_t ws_size,
                              hipStream_t stream) {
    (void)in_sizes; (void)n_in; (void)out_size; (void)ws_size;
    P p;
    p.feature  = (const float*)d_in[0];
    p.strength = (const float*)d_in[1];
    p.W0  = (const float*)d_in[2];  p.b0  = (const float*)d_in[3];
    p.al0 = (const float*)d_in[4];  p.ar0 = (const float*)d_in[5];
    p.Wc0 = (const float*)d_in[6];  p.bc0 = (const float*)d_in[7];
    p.W1  = (const float*)d_in[8];  p.b1  = (const float*)d_in[9];
    p.al1 = (const float*)d_in[10]; p.ar1 = (const float*)d_in[11];
    p.gW  = (const float*)d_in[12]; p.gb  = (const float*)d_in[13];
    p.cW  = (const float*)d_in[14]; p.cb  = (const float*)d_in[15];
    p.src = (const int*)d_in[16];   p.dst = (const int*)d_in[17];
    p.out = (float*)d_out;

    char* ws = (char*)d_ws;
    size_t off = 0;
    auto alloc = [&](size_t bytes) -> void* {
        void* r = ws + off;
        off = (off + bytes + 255) & ~(size_t)255;
        return r;
    };
    // ---- zeroed region (must stay first/contiguous) ----
    p.Zacc  = (double*)alloc(8);
    p.racc  = (double*)alloc(32 * 8);
    p.cnt   = (int*)alloc(4);
    p.gmaxk = (unsigned*)alloc(4);
    p.bar   = (int*)alloc(32 * 4);         // grid-barrier pairs
    p.bins4 = (unsigned*)alloc(4 * 256 * 4);
    size_t zbytes = off;
    // ---- big buffers (fully overwritten each run) ----
    p.degc_i = (unsigned char*)alloc((size_t)BCH * NN);
    p.degc_o = (unsigned char*)alloc((size_t)BCH * NN);
    p.cb0 = (unsigned*)alloc((size_t)BCH * NN * 4);
    p.dsum = (int*)alloc((size_t)NN * 4);
    p.z0 = (float*)alloc((size_t)NN * HD * 4);
    p.xk = (float*)alloc((size_t)KK * HD * 4);
    p.z1 = (float*)alloc((size_t)KK * HD * 4);
    p.csr_src = (int*)alloc((size_t)EE * 4);
    p.rank    = (int*)alloc((size_t)EE * 4);
    p.el0 = (float*)alloc((size_t)NN * 4 * 4);
    p.er0 = (float*)alloc((size_t)NN * 4 * 4);
    p.q4  = (float*)alloc((size_t)NN * 4 * 4);
    p.m0f = (float*)alloc((size_t)NN * 4 * 4);
    p.s0f = (float*)alloc((size_t)NN * 4 * 4);
    p.b0wc = (float*)alloc(4);
    p.off0 = (int*)alloc((size_t)(NN + 1) * 4);
    p.bsum = (int*)alloc(256 * 4);
    p.hc    = (float*)alloc((size_t)NN * 4);
    p.slot  = (int*)alloc((size_t)NN * 4);
    p.list  = (int*)alloc((size_t)KK * 4);
    p.tscale = (float*)alloc((size_t)KK * 4);
    p.el1 = (float*)alloc((size_t)KK * 4 * 4);
    p.er1 = (float*)alloc((size_t)KK * 4 * 4);
    p.m1f = (float*)alloc((size_t)KK * 4 * 4);
    p.s1f = (float*)alloc((size_t)KK * 4 * 4);
    p.res = (float*)alloc((size_t)KK * DD * 4);
    p.g   = (float*)alloc((size_t)KK * 4);

    hipMemsetAsync(d_ws, 0, zbytes, stream);

    // ---- GAT layer 0: count -> fused scan -> (gemm0 || scatter0) -> fgatlite ----
    k_count0<<<2 * BCH, 256, 0, stream>>>(p);
    k_scan0<<<SB, 1024, 0, stream>>>(p);
    k_g0sc<<<G0B + GB_E + 1, 256, 0, stream>>>(p);
    k_fgatlite<<<NN / 4, 256, 0, stream>>>(p.off0, p.csr_src, p.el0, p.er0, p.q4,
                                           p.dsum, p.b0wc, p.hc, p.m0f, p.s0f);

    // ---- SAGPool (single fused kernel, LDS-radix) ----
    k_pool<<<PB, 1024, 0, stream>>>(p);

    // ---- GAT layer 1: fgatx -> gemm1 -> fgat2 (layer-0 CSR reused) ----
    k_fgatx<<<KK / 4, 256, 0, stream>>>(p.list, p.tscale, p.off0, p.csr_src,
                                        p.el0, p.er0, p.m0f, p.s0f, p.z0, p.b0, p.xk);
    k_gemm1<<<G1B, 256, 0, stream>>>(p);
    k_fgat2<<<KK / 4, 256, 0, stream>>>(p);
    k_ealpha1<<<GB_E, 256, 0, stream>>>(p);

    // ---- readout (single fused kernel) ----
    k_read<<<RB, 256, 0, stream>>>(p);
}

// Round 6
// 579.726 us; speedup vs baseline: 1.4911x; 1.0157x over previous
//
#include <hip/hip_runtime.h>
#include <stdint.h>

#define NN 50000
#define EE 800000
#define FIN 256
#define HD 128
#define DD 32
#define KK 25000
#define SLOPEF 0.4f
#define NEGF (-1e9f)
#define ATT_OFF 34
#define STR_OFF (34 + EE * 4)
#define CW 128             // LDS-cached edges per node (deg ~Poisson(16); recompute fallback)

// counting-sort CSR build (layer 0 only; layer 1 reuses it via slot-filtering)
#define BCH 32             // edge chunks
#define EPC (EE / BCH)     // 25000 edges per chunk

// ---------- helpers ----------
__device__ __forceinline__ unsigned fkey(float x) {
    unsigned u = __float_as_uint(x);
    return (u & 0x80000000u) ? ~u : (u | 0x80000000u);   // monotone float->uint
}
__device__ __forceinline__ float unfkey(unsigned k) {
    unsigned u = (k & 0x80000000u) ? (k ^ 0x80000000u) : ~k;
    return __uint_as_float(u);
}
__device__ __forceinline__ float lrelu(float v) { return v > 0.f ? v : SLOPEF * v; }

// ---------- pointer bundle ----------
struct P {
    // inputs
    const float *feature, *strength, *W0, *b0, *al0, *ar0, *Wc0, *bc0;
    const float *W1, *b1, *al1, *ar1, *gW, *gb, *cW, *cb;
    const int *src, *dst;
    // zeroed scratch
    double *Zacc, *racc;
    int *cnt;
    unsigned *gmaxk;
    unsigned *rs;                 // [0]=pivot,[1]=need,[2]=hi bin,[3]=hi remaining
    unsigned *binsHi, *binsLo;    // 65536 u32 bins each
    // other scratch
    unsigned *keys;
    unsigned char *degc_i, *degc_o;   // per-(chunk,node) u8 counts [BCH][NN]
    unsigned *cb0;                // per-(chunk,node) CSR base cursors
    int *dsum;                    // out-degree totals
    int *csr_src, *rank, *off0, *sel, *slot, *list, *bsum, *boff;
    float *z0, *el0, *er0, *q4, *m0f, *s0f, *b0wc, *hc, *xk, *z1;
    float *el1, *er1, *m1f, *s1f, *res, *g, *tscale;
    float *out;                   // d_out (float32)
};

// ---------- fp32 tiled GEMM body: C[M,128] = A[M,Kd] @ B[Kd,128] ----------
#define BM 128
#define BN 64
#define BK 16
__device__ void gemm_body(
    const float* __restrict__ A, const float* __restrict__ B, float* __restrict__ C,
    int M, int Kd,
    const float* __restrict__ al, const float* __restrict__ ar,
    float* __restrict__ el, float* __restrict__ er,
    const float* __restrict__ Wc, float* __restrict__ q4,
    int bx, int by) {
    __shared__ float As[BK][BM + 4];
    __shared__ float Bs[BK][BN];
    int bm = by * BM, bn = bx * BN;
    int tid = threadIdx.x;
    int tr = tid >> 4, tc = tid & 15;
    int lrow = tid >> 1;
    int arow = (bm + lrow < M) ? (bm + lrow) : -1;
    float acc[8][4] = {};
    for (int k0 = 0; k0 < Kd; k0 += BK) {
        {
            int col = (tid & 1) << 3;
            float4 v0 = {0.f,0.f,0.f,0.f}, v1 = {0.f,0.f,0.f,0.f};
            if (arow >= 0) {
                const float* ap = A + (size_t)arow * Kd + k0 + col;
                v0 = *(const float4*)ap; v1 = *(const float4*)(ap + 4);
            }
            As[col + 0][lrow] = v0.x; As[col + 1][lrow] = v0.y;
            As[col + 2][lrow] = v0.z; As[col + 3][lrow] = v0.w;
            As[col + 4][lrow] = v1.x; As[col + 5][lrow] = v1.y;
            As[col + 6][lrow] = v1.z; As[col + 7][lrow] = v1.w;
        }
        {
            int kr = tid >> 4, col = (tid & 15) << 2;
            float4 v = *(const float4*)(B + (size_t)(k0 + kr) * HD + bn + col);
            *(float4*)&Bs[kr][col] = v;
        }
        __syncthreads();
#pragma unroll
        for (int kk = 0; kk < BK; kk++) {
            float a[8], b[4];
#pragma unroll
            for (int i = 0; i < 8; i++) a[i] = As[kk][tr * 8 + i];
#pragma unroll
            for (int j = 0; j < 4; j++) b[j] = Bs[kk][tc * 4 + j];
#pragma unroll
            for (int i = 0; i < 8; i++)
#pragma unroll
                for (int j = 0; j < 4; j++) acc[i][j] = fmaf(a[i], b[j], acc[i][j]);
        }
        __syncthreads();
    }
#pragma unroll
    for (int i = 0; i < 8; i++) {
        int gr = bm + tr * 8 + i;
        if (gr < M) {
            float4 v = {acc[i][0], acc[i][1], acc[i][2], acc[i][3]};
            *(float4*)(C + (size_t)gr * HD + bn + tc * 4) = v;
        }
    }
    int head = bx * 2 + (tc >> 3);
    int dbase = (tc & 7) * 4;
    const float* alh = al + head * 32 + dbase;
    const float* arh = ar + head * 32 + dbase;
    float a0 = alh[0], a1 = alh[1], a2 = alh[2], a3 = alh[3];
    float r0 = arh[0], r1 = arh[1], r2 = arh[2], r3 = arh[3];
    float w0 = 0.f, w1 = 0.f, w2 = 0.f, w3 = 0.f;
    if (Wc) {
        const float* wch = Wc + head * 32 + dbase;
        w0 = wch[0]; w1 = wch[1]; w2 = wch[2]; w3 = wch[3];
    }
#pragma unroll
    for (int i = 0; i < 8; i++) {
        int gr = bm + tr * 8 + i;
        float pe = acc[i][0]*a0 + acc[i][1]*a1 + acc[i][2]*a2 + acc[i][3]*a3;
        float pr = acc[i][0]*r0 + acc[i][1]*r1 + acc[i][2]*r2 + acc[i][3]*r3;
        float pq = acc[i][0]*w0 + acc[i][1]*w1 + acc[i][2]*w2 + acc[i][3]*w3;
#pragma unroll
        for (int o = 1; o < 8; o <<= 1) {
            pe += __shfl_xor(pe, o); pr += __shfl_xor(pr, o); pq += __shfl_xor(pq, o);
        }
        if ((tc & 7) == 0 && gr < M) {
            el[gr * 4 + head] = pe; er[gr * 4 + head] = pr;
            if (Wc) q4[gr * 4 + head] = pq;
        }
    }
}

// ---------- layer-0 count: full-range u8 LDS histogram; rank = old field ----------
__global__ __launch_bounds__(256) void k_count0(P p) {
    __shared__ unsigned hist[NN / 4];         // 12500 words = 50 KB, u8 counters
    int blk = blockIdx.x;
    int isD = blk < BCH;
    int c = isD ? blk : blk - BCH;
    for (int w = threadIdx.x; w < NN / 4; w += 256) hist[w] = 0u;
    __syncthreads();
    int j0 = c * EPC, j1 = j0 + EPC;
    if (isD) {
        for (int e = j0 + (int)threadIdx.x; e < j1; e += 256) {
            int d = p.dst[e];
            unsigned sh = (unsigned)(d & 3) * 8u;
            unsigned old = atomicAdd(&hist[d >> 2], 1u << sh);
            p.rank[e] = (int)((old >> sh) & 0xffu);
        }
    } else {
        for (int e = j0 + (int)threadIdx.x; e < j1; e += 256) {
            int s = p.src[e];
            atomicAdd(&hist[s >> 2], 1u << ((unsigned)(s & 3) * 8u));
        }
    }
    __syncthreads();
    unsigned* o32 = (unsigned*)((isD ? p.degc_i : p.degc_o) + (size_t)c * NN);
    for (int w = threadIdx.x; w < NN / 4; w += 256) o32[w] = hist[w];
}

// ---------- two-level exclusive scan over node totals (stream-ordered) ----------
__global__ __launch_bounds__(256) void k_bsum(const unsigned char* __restrict__ deg,
                                              int* __restrict__ bsum, int n, int nn) {
    int i = blockIdx.x * 256 + threadIdx.x;
    int v = 0;
    if (i < n) {
#pragma unroll
        for (int c = 0; c < BCH; c++) v += deg[(size_t)c * nn + i];
    }
    int lane = threadIdx.x & 63, w = threadIdx.x >> 6;
    __shared__ int ws[4];
#pragma unroll
    for (int o = 1; o < 64; o <<= 1) v += __shfl_xor(v, o);
    if (lane == 0) ws[w] = v;
    __syncthreads();
    if (threadIdx.x == 0) bsum[blockIdx.x] = ws[0] + ws[1] + ws[2] + ws[3];
}
__global__ __launch_bounds__(256) void k_bscan(const int* __restrict__ bsum, int nb,
                                               int* __restrict__ boff,
                                               int* __restrict__ off, int n) {
    __shared__ int ws[4];
    __shared__ int wo[5];
    int t = threadIdx.x;
    int v = (t < nb) ? bsum[t] : 0;
    int lane = t & 63, w = t >> 6;
    int incl = v;
    for (int o = 1; o < 64; o <<= 1) { int u = __shfl_up(incl, o); if (lane >= o) incl += u; }
    if (lane == 63) ws[w] = incl;
    __syncthreads();
    if (t == 0) { int a = 0; for (int i = 0; i < 4; i++) { wo[i] = a; a += ws[i]; } wo[4] = a; }
    __syncthreads();
    if (t < nb) boff[t] = wo[w] + incl - v;
    if (t == 0) off[n] = wo[4];
}
// final scan: off0 + per-chunk bases cb0 + out-degree totals dsum
__global__ __launch_bounds__(256) void k_fscan0(P p) {
    __shared__ int ws[4];
    __shared__ int wo[4];
    int i = blockIdx.x * 256 + threadIdx.x;
    int v = 0;
    if (i < NN) {
#pragma unroll
        for (int c = 0; c < BCH; c++) v += p.degc_i[(size_t)c * NN + i];
    }
    int lane = threadIdx.x & 63, w = threadIdx.x >> 6;
    int incl = v;
    for (int o = 1; o < 64; o <<= 1) { int u = __shfl_up(incl, o); if (lane >= o) incl += u; }
    if (lane == 63) ws[w] = incl;
    __syncthreads();
    if (threadIdx.x == 0) { int a = 0; for (int k = 0; k < 4; k++) { wo[k] = a; a += ws[k]; } }
    __syncthreads();
    if (i < NN) {
        int base = p.boff[blockIdx.x] + wo[w] + incl - v;
        p.off0[i] = base;
        unsigned run = (unsigned)base;
        int s = 0;
#pragma unroll
        for (int c = 0; c < BCH; c++) {
            p.cb0[(size_t)c * NN + i] = run;
            run += p.degc_i[(size_t)c * NN + i];
            s += p.degc_o[(size_t)c * NN + i];
        }
        p.dsum[i] = s;
    }
}

// ---------- MERGED: gemm0 || CSR scatter0 || b0.Wc0 prep ----------
#define G0B 782            // 2 x 391 gemm blocks
#define GB_E 3125
__global__ __launch_bounds__(256) void k_g0sc(P p) {
    int blk = blockIdx.x;
    if (blk < G0B) {
        gemm_body(p.feature, p.W0, p.z0, NN, FIN, p.al0, p.ar0, p.el0, p.er0,
                  p.Wc0, p.q4, blk & 1, blk >> 1);
    } else if (blk < G0B + GB_E) {
        int e = (blk - G0B) * 256 + threadIdx.x;
        if (e < EE) {
            int c = e / EPC;
            int d = p.dst[e];
            unsigned pos = p.cb0[(size_t)c * NN + d] + (unsigned)p.rank[e];
            p.csr_src[pos] = p.src[e];
        }
    } else {
        int l = threadIdx.x;
        if (l < 64) {
            float t = p.b0[l] * p.Wc0[l] + p.b0[l + 64] * p.Wc0[l + 64];
#pragma unroll
            for (int o = 1; o < 64; o <<= 1) t += __shfl_xor(t, o);
            if (l == 0) p.b0wc[0] = t;
        }
    }
}

// ---------- layer-0 softmax + SCALAR q-gather (all nodes) ----------
__global__ __launch_bounds__(256) void k_fgatlite(
    const int* __restrict__ off, const int* __restrict__ csrs,
    const float* __restrict__ el, const float* __restrict__ er,
    const float* __restrict__ q4, const int* __restrict__ dsum,
    const float* __restrict__ b0wc,
    float* __restrict__ hc, float* __restrict__ m0f, float* __restrict__ s0f) {
    int wv = threadIdx.x >> 6, lane = threadIdx.x & 63;
    int v = blockIdx.x * 4 + wv;
    int b = off[v], e = off[v + 1], deg = e - b;
    int h = lane >> 4, sub = lane & 15;
    float erh = er[(size_t)v * 4 + h];
    float m = NEGF;
    for (int li = sub; li < deg; li += 16) {
        int s = csrs[b + li];
        m = fmaxf(m, lrelu(el[(size_t)s * 4 + h] + erh));
    }
#pragma unroll
    for (int o = 1; o < 16; o <<= 1) m = fmaxf(m, __shfl_xor(m, o));
    float ssum = 0.f, hq = 0.f;
    for (int li = sub; li < deg; li += 16) {
        int s = csrs[b + li];
        float ex = expf(lrelu(el[(size_t)s * 4 + h] + erh) - m);
        ssum += ex;
        hq = fmaf(ex, q4[(size_t)s * 4 + h], hq);
    }
#pragma unroll
    for (int o = 1; o < 16; o <<= 1) { ssum += __shfl_xor(ssum, o); hq += __shfl_xor(hq, o); }
    if (sub == 0) { m0f[v * 4 + h] = m; s0f[v * 4 + h] = ssum; }
    float t = hq / fmaxf(ssum, 1e-16f);
    t += __shfl_xor(t, 16);
    t += __shfl_xor(t, 32);
    if (lane == 0)
        hc[v] = (t + b0wc[0]) / sqrtf(fmaxf((float)dsum[v], 1.f));
}

// ---------- SAGPool score -> keys (sel zeroed here; no histogram) ----------
__global__ __launch_bounds__(256) void k_score(P p) {
    int v = blockIdx.x * blockDim.x + threadIdx.x;
    if (v >= NN) return;
    int b = p.off0[v], en = p.off0[v + 1];
    float acc = 0.f;
    for (int i = b; i < en; i++) acc += p.hc[p.csr_src[i]];
    float dg = fmaxf((float)(en - b), 1.f);
    float sc = acc / sqrtf(dg) + p.bc0[0];
    p.keys[v] = fkey(sc);
    p.sel[v] = 0;
}

// ---------- hi-16 histogram: per-block u16-packed LDS (two 64KB half-passes) ----------
#define HB 49              // ceil(NN/1024)
__global__ __launch_bounds__(1024) void k_h0(P p) {
    __shared__ unsigned hist[16384];     // 64 KB: 32768 bins u16-packed per half
    int i = blockIdx.x * 1024 + (int)threadIdx.x;
    unsigned key = (i < NN) ? p.keys[i] : 0xFFFFFFFFu;  // sentinel: never counted
    unsigned b16 = key >> 16;
#pragma unroll
    for (int half = 0; half < 2; half++) {
        for (int w = threadIdx.x; w < 16384; w += 1024) hist[w] = 0u;
        __syncthreads();
        if (i < NN && (int)(b16 >> 15) == half) {
            unsigned bb = b16 & 0x7FFFu;
            atomicAdd(&hist[bb >> 1], 1u << (16u * (bb & 1u)));
        }
        __syncthreads();
        for (int w = threadIdx.x; w < 16384; w += 1024) {
            unsigned hv = hist[w];
            unsigned lo = hv & 0xFFFFu, hi = hv >> 16;
            if (lo) atomicAdd(&p.binsHi[half * 32768 + 2 * w], lo);
            if (hi) atomicAdd(&p.binsHi[half * 32768 + 2 * w + 1], hi);
        }
        __syncthreads();
    }
}

// ---------- lo-16 histogram among hi-bin candidates ----------
__global__ __launch_bounds__(1024) void k_h1(P p) {
    __shared__ unsigned hist[16384];
    int i = blockIdx.x * 1024 + (int)threadIdx.x;
    unsigned hib = p.rs[2];
    unsigned key = (i < NN) ? p.keys[i] : 0u;
    int cand = (i < NN) && ((key >> 16) == hib);
    unsigned b16 = key & 0xFFFFu;
#pragma unroll
    for (int half = 0; half < 2; half++) {
        for (int w = threadIdx.x; w < 16384; w += 1024) hist[w] = 0u;
        __syncthreads();
        if (cand && (int)(b16 >> 15) == half) {
            unsigned bb = b16 & 0x7FFFu;
            atomicAdd(&hist[bb >> 1], 1u << (16u * (bb & 1u)));
        }
        __syncthreads();
        for (int w = threadIdx.x; w < 16384; w += 1024) {
            unsigned hv = hist[w];
            unsigned lo = hv & 0xFFFFu, hi = hv >> 16;
            if (lo) atomicAdd(&p.binsLo[half * 32768 + 2 * w], lo);
            if (hi) atomicAdd(&p.binsLo[half * 32768 + 2 * w + 1], hi);
        }
        __syncthreads();
    }
}

// ---------- radix pick: 1 block scans 65536 bins (validated R0 kernel) ----------
__global__ __launch_bounds__(1024) void k_rsel2(P p, int level) {
    const unsigned* bins = level ? p.binsLo : p.binsHi;
    int K = level ? (int)p.rs[3] : KK;
    __shared__ unsigned wsm[16];
    __shared__ unsigned wpre[17];
    int t = threadIdx.x;
    unsigned base = (unsigned)t * 64;
    const uint4* b4 = (const uint4*)(bins + base);
    unsigned S = 0;
#pragma unroll
    for (int i = 0; i < 16; i++) {
        uint4 u = b4[i];
        S += u.x + u.y + u.z + u.w;
    }
    int lane = t & 63, w = t >> 6;
    unsigned val = S;
    for (int o = 1; o < 64; o <<= 1) { unsigned u = __shfl_up(val, o); if (lane >= o) val += u; }
    if (lane == 63) wsm[w] = val;
    __syncthreads();
    if (t == 0) { unsigned a = 0; for (int i = 0; i < 16; i++) { wpre[i] = a; a += wsm[i]; } wpre[16] = a; }
    __syncthreads();
    unsigned incl = wpre[w] + val;
    unsigned running = wpre[16] - incl;    // keys in strictly higher bins
    for (int i = 63; i >= 0; i--) {
        unsigned c = bins[base + i];
        unsigned above = running;
        running += c;
        if ((int)above < K && (int)running >= K) {
            if (level == 0) { p.rs[2] = base + (unsigned)i; p.rs[3] = (unsigned)(K - (int)above); }
            else { p.rs[0] = (p.rs[2] << 16) | (base + (unsigned)i); p.rs[1] = (unsigned)(K - (int)above); }
        }
    }
}

// ---------- lowest-index ties (matches top_k); sel pre-zeroed by k_score ----------
__global__ __launch_bounds__(1024) void k_ties(P p) {
    __shared__ int base;
    __shared__ int wsums[16];
    unsigned pivot = p.rs[0];
    int need = (int)p.rs[1];
    if (threadIdx.x == 0) base = 0;
    __syncthreads();
    for (int st = 0; st < NN; st += 1024) {
        int v = st + (int)threadIdx.x;
        int flag = (v < NN && p.keys[v] == pivot) ? 1 : 0;
        unsigned long long m = __ballot(flag);
        int lane = threadIdx.x & 63, w = threadIdx.x >> 6;
        int pre = __popcll(m & ((1ull << lane) - 1ull));
        if (lane == 0) wsums[w] = __popcll(m);
        __syncthreads();
        int woff = 0;
        for (int i = 0; i < w; i++) woff += wsums[i];
        int rank = base + woff + pre;
        if (flag && rank < need) p.sel[v] = 1;
        __syncthreads();
        if (threadIdx.x == 0) {
            int s = 0;
            for (int i = 0; i < 16; i++) s += wsums[i];
            base += s;
        }
        __syncthreads();
    }
}

// ---------- list build (ticket order; outputs are row-permutation invariant) ----------
__global__ void k_list(P p) {
    int v = blockIdx.x * blockDim.x + threadIdx.x;
    if (v >= NN) return;
    unsigned k = p.keys[v];
    int selv = (k > p.rs[0]) || p.sel[v];
    if (selv) {
        int i = atomicAdd(p.cnt, 1);
        p.list[i] = v;
        p.slot[v] = i;
        p.tscale[i] = tanhf(unfkey(k));
    } else {
        p.slot[v] = -1;
    }
}

// ---------- full x for SELECTED nodes only ----------
__global__ __launch_bounds__(256) void k_fgatx(
    const int* __restrict__ list, const float* __restrict__ tscale,
    const int* __restrict__ off, const int* __restrict__ csrs,
    const float* __restrict__ el, const float* __restrict__ er,
    const float* __restrict__ m0f, const float* __restrict__ s0f,
    const float* __restrict__ z, const float* __restrict__ b0,
    float* __restrict__ xk) {
    __shared__ int ssrc[4][CW];
    __shared__ float sexp[4][CW][4];
    int wv = threadIdx.x >> 6, lane = threadIdx.x & 63;
    int i = blockIdx.x * 4 + wv;
    int v = list[i];
    int b = off[v], e = off[v + 1], deg = e - b;
    int h = lane >> 4, sub = lane & 15;
    float erh = er[(size_t)v * 4 + h];
    float mh = m0f[v * 4 + h];
    for (int li = sub; li < deg; li += 16) {
        int s = csrs[b + li];
        if (h == 0 && li < CW) ssrc[wv][li] = s;
        if (li < CW) sexp[wv][li][h] = expf(lrelu(el[(size_t)s * 4 + h] + erh) - mh);
    }
    __syncthreads();
    int h0 = lane >> 5, h1 = h0 + 2;
    float s0 = s0f[v * 4 + h0], s1 = s0f[v * 4 + h1];
    float m0 = m0f[v * 4 + h0], m1 = m0f[v * 4 + h1];
    float er0v = er[(size_t)v * 4 + h0], er1v = er[(size_t)v * 4 + h1];
    int c0 = lane, c1 = lane + 64;
    float acc0 = 0.f, acc1 = 0.f;
    for (int li = 0; li < deg; li++) {
        int s; float w0, w1;
        if (li < CW) {
            s = ssrc[wv][li];
            w0 = sexp[wv][li][h0]; w1 = sexp[wv][li][h1];
        } else {
            s = csrs[b + li];
            w0 = expf(lrelu(el[(size_t)s * 4 + h0] + er0v) - m0);
            w1 = expf(lrelu(el[(size_t)s * 4 + h1] + er1v) - m1);
        }
        int su = __builtin_amdgcn_readfirstlane(s);
        const float* zr = z + (size_t)su * HD;
        acc0 = fmaf(w0, zr[c0], acc0);
        acc1 = fmaf(w1, zr[c1], acc1);
    }
    float ts = tscale[i];
    float* xr = xk + (size_t)i * HD;
    xr[c0] = (acc0 / fmaxf(s0, 1e-16f) + b0[c0]) * ts;
    xr[c1] = (acc1 / fmaxf(s1, 1e-16f) + b0[c1]) * ts;
}

// ---------- pure gemm1 ----------
#define G1B 392
__global__ __launch_bounds__(256) void k_gemm1(P p) {
    gemm_body(p.xk, p.W1, p.z1, KK, HD, p.al1, p.ar1, p.el1, p.er1,
              nullptr, nullptr, blockIdx.x & 1, blockIdx.x >> 1);
}

// ---------- layer-1 fused GAT: reuses LAYER-0 CSR, filters by slot ----------
__global__ __launch_bounds__(256) void k_fgat2(P p) {
    __shared__ int ssrc[4][CW];
    __shared__ float sexp[4][CW][4];
    int wv = threadIdx.x >> 6, lane = threadIdx.x & 63;
    int i = blockIdx.x * 4 + wv;          // slot index
    int v = p.list[i];                    // original node id
    int b = p.off0[v], e = p.off0[v + 1], deg = e - b;
    int h = lane >> 4, sub = lane & 15;
    float4 er4 = *(const float4*)(p.er1 + (size_t)i * 4);
    float erh = ((const float*)&er4)[h];
    float m = NEGF;
    for (int li = sub; li < deg; li += 16) {
        int so = p.csr_src[b + li];
        int ss = p.slot[so];
        if (h == 0 && li < CW) ssrc[wv][li] = ss;
        if (ss >= 0) m = fmaxf(m, lrelu(p.el1[(size_t)ss * 4 + h] + erh));
    }
#pragma unroll
    for (int o = 1; o < 16; o <<= 1) m = fmaxf(m, __shfl_xor(m, o));
    float ssum = 0.f;
    for (int li = sub; li < deg; li += 16) {
        int so = p.csr_src[b + li];
        int ss = p.slot[so];
        float x = (ss >= 0) ? expf(lrelu(p.el1[(size_t)ss * 4 + h] + erh) - m) : 0.f;
        if (li < CW) sexp[wv][li][h] = x;
        ssum += x;
    }
#pragma unroll
    for (int o = 1; o < 16; o <<= 1) ssum += __shfl_xor(ssum, o);
    if (sub == 0) { p.m1f[i * 4 + h] = m; p.s1f[i * 4 + h] = ssum; }
    __syncthreads();
    int h0 = lane >> 5, h1 = h0 + 2;
    float m0 = __shfl(m, h0 << 4), m1 = __shfl(m, h1 << 4);
    float s0 = __shfl(ssum, h0 << 4), s1 = __shfl(ssum, h1 << 4);
    int c0 = lane, c1 = lane + 64;
    float acc0 = 0.f, acc1 = 0.f;
    for (int li = 0; li < deg; li++) {
        int s; float w0, w1;
        if (li < CW) {
            s = ssrc[wv][li];
            if (s < 0) continue;
            w0 = sexp[wv][li][h0]; w1 = sexp[wv][li][h1];
        } else {
            int so = p.csr_src[b + li];
            s = p.slot[so];
            if (s < 0) continue;
            w0 = expf(lrelu(p.el1[(size_t)s * 4 + h0] + ((const float*)&er4)[h0]) - m0);
            w1 = expf(lrelu(p.el1[(size_t)s * 4 + h1] + ((const float*)&er4)[h1]) - m1);
        }
        int su = __builtin_amdgcn_readfirstlane(s);
        const float* zr = p.z1 + (size_t)su * HD;
        acc0 = fmaf(w0, zr[c0], acc0);
        acc1 = fmaf(w1, zr[c1], acc1);
    }
    float xc0 = acc0 / fmaxf(s0, 1e-16f) + p.b1[c0];
    float xc1 = acc1 / fmaxf(s1, 1e-16f) + p.b1[c1];
    float t = xc0 + xc1;
    t += __shfl_xor(t, 32);
    float pg = 0.f;
    if (lane < 32) {
        float r = 0.25f * t;
        p.res[(size_t)i * 32 + lane] = r;
        pg = r * p.gW[lane];
    }
#pragma unroll
    for (int o = 1; o < 32; o <<= 1) pg += __shfl_xor(pg, o);
    if (lane == 0) p.g[i] = pg + p.gb[0];
}

// per-edge alpha outputs
__global__ void k_ealpha1(P p) {
    int e = blockIdx.x * blockDim.x + threadIdx.x;
    if (e >= EE) return;
    int ds = p.slot[p.src[e]], dd = p.slot[p.dst[e]];
    float a[4] = {0.f, 0.f, 0.f, 0.f};
    float st = 0.f;
    if (ds >= 0 && dd >= 0) {
        float4 es = *(const float4*)(p.el1 + ds * 4);
        float4 ed = *(const float4*)(p.er1 + dd * 4);
        float l[4] = {lrelu(es.x + ed.x), lrelu(es.y + ed.y), lrelu(es.z + ed.z), lrelu(es.w + ed.w)};
#pragma unroll
        for (int h = 0; h < 4; h++) {
            float m = p.m1f[dd * 4 + h];
            float ex = expf(l[h] - m);
            a[h] = ex / fmaxf(p.s1f[dd * 4 + h], 1e-16f);
        }
        st = p.strength[e];
    }
    float* o = p.out + ATT_OFF + (size_t)e * 4;
    *(float2*)(o) = make_float2(a[0], a[1]);
    *(float2*)(o + 2) = make_float2(a[2], a[3]);
    p.out[STR_OFF + e] = st;
}

// ---------- readout (stream-ordered) ----------
__global__ void k_gmax(P p) {
    __shared__ float red[256];
    int t = threadIdx.x;
    float m = -3.4e38f;
    for (int i = blockIdx.x * 256 + t; i < KK; i += gridDim.x * 256) m = fmaxf(m, p.g[i]);
    red[t] = m;
    __syncthreads();
    for (int o = 128; o > 0; o >>= 1) { if (t < o) red[t] = fmaxf(red[t], red[t + o]); __syncthreads(); }
    if (t == 0) atomicMax(p.gmaxk, fkey(red[0]));   // memset-0 identity ok
}
#define WSUM_BLOCKS 104
__global__ __launch_bounds__(256) void k_wsum(P p) {
    __shared__ double vred[256];
    __shared__ double zred[8];
    int t = threadIdx.x, il = t >> 5, d = t & 31;
    float gm = unfkey(*p.gmaxk);
    double accv = 0.0, accw = 0.0;
    for (int i = blockIdx.x * 8 + il; i < KK; i += WSUM_BLOCKS * 8) {
        float w = expf(p.g[i] - gm);
        accv += (double)(w * p.res[(size_t)i * 32 + d]);
        if (d == 0) accw += (double)w;
    }
    vred[t] = accv;
    if (d == 0) zred[il] = accw;
    __syncthreads();
    if (il == 0) {
        double s = 0;
#pragma unroll
        for (int k2 = 0; k2 < 8; k2++) s += vred[k2 * 32 + d];
        atomicAdd(&p.racc[d], s);
    }
    if (t == 32) {
        double z2 = 0;
#pragma unroll
        for (int k2 = 0; k2 < 8; k2++) z2 += zred[k2];
        atomicAdd(p.Zacc, z2);
    }
}
__global__ void k_final(P p) {
    __shared__ float rb[32];
    int t = threadIdx.x;
    double Z = *p.Zacc;
    if (t < 32) {
        float r = (float)(p.racc[t] / Z);
        p.out[t] = r;
        rb[t] = r;
    }
    __syncthreads();
    if (t < 2) {
        float s = 0.f;
        for (int d = 0; d < 32; d++) s += rb[d] * p.cW[d * 2 + t];
        p.out[32 + t] = s + p.cb[t];
    }
}

// ---------- host ----------
extern "C" void kernel_launch(void* const* d_in, const int* in_sizes, int n_in,
                              void* d_out, int out_size, void* d_ws, size_t ws_size,
                              hipStream_t stream) {
    (void)in_sizes; (void)n_in; (void)out_size; (void)ws_size;
    P p;
    p.feature  = (const float*)d_in[0];
    p.strength = (const float*)d_in[1];
    p.W0  = (const float*)d_in[2];  p.b0  = (const float*)d_in[3];
    p.al0 = (const float*)d_in[4];  p.ar0 = (const float*)d_in[5];
    p.Wc0 = (const float*)d_in[6];  p.bc0 = (const float*)d_in[7];
    p.W1  = (const float*)d_in[8];  p.b1  = (const float*)d_in[9];
    p.al1 = (const float*)d_in[10]; p.ar1 = (const float*)d_in[11];
    p.gW  = (const float*)d_in[12]; p.gb  = (const float*)d_in[13];
    p.cW  = (const float*)d_in[14]; p.cb  = (const float*)d_in[15];
    p.src = (const int*)d_in[16];   p.dst = (const int*)d_in[17];
    p.out = (float*)d_out;

    char* ws = (char*)d_ws;
    size_t off = 0;
    auto alloc = [&](size_t bytes) -> void* {
        void* r = ws + off;
        off = (off + bytes + 255) & ~(size_t)255;
        return r;
    };
    // ---- zeroed region (must stay first/contiguous) ----
    p.Zacc  = (double*)alloc(8);
    p.racc  = (double*)alloc(32 * 8);
    p.cnt   = (int*)alloc(4);
    p.gmaxk = (unsigned*)alloc(4);
    p.rs    = (unsigned*)alloc(16);
    p.binsHi = (unsigned*)alloc(65536 * 4);
    p.binsLo = (unsigned*)alloc(65536 * 4);
    size_t zbytes = off;
    // ---- big buffers (fully overwritten each run) ----
    p.degc_i = (unsigned char*)alloc((size_t)BCH * NN);
    p.degc_o = (unsigned char*)alloc((size_t)BCH * NN);
    p.cb0 = (unsigned*)alloc((size_t)BCH * NN * 4);
    p.dsum = (int*)alloc((size_t)NN * 4);
    p.z0 = (float*)alloc((size_t)NN * HD * 4);
    p.xk = (float*)alloc((size_t)KK * HD * 4);
    p.z1 = (float*)alloc((size_t)KK * HD * 4);
    p.csr_src = (int*)alloc((size_t)EE * 4);
    p.rank    = (int*)alloc((size_t)EE * 4);
    p.el0 = (float*)alloc((size_t)NN * 4 * 4);
    p.er0 = (float*)alloc((size_t)NN * 4 * 4);
    p.q4  = (float*)alloc((size_t)NN * 4 * 4);
    p.m0f = (float*)alloc((size_t)NN * 4 * 4);
    p.s0f = (float*)alloc((size_t)NN * 4 * 4);
    p.b0wc = (float*)alloc(4);
    p.off0 = (int*)alloc((size_t)(NN + 1) * 4);
    p.bsum = (int*)alloc(256 * 4);
    p.boff = (int*)alloc(256 * 4);
    p.hc    = (float*)alloc((size_t)NN * 4);
    p.keys  = (unsigned*)alloc((size_t)NN * 4);
    p.sel   = (int*)alloc((size_t)NN * 4);
    p.slot  = (int*)alloc((size_t)NN * 4);
    p.list  = (int*)alloc((size_t)KK * 4);
    p.tscale = (float*)alloc((size_t)KK * 4);
    p.el1 = (float*)alloc((size_t)KK * 4 * 4);
    p.er1 = (float*)alloc((size_t)KK * 4 * 4);
    p.m1f = (float*)alloc((size_t)KK * 4 * 4);
    p.s1f = (float*)alloc((size_t)KK * 4 * 4);
    p.res = (float*)alloc((size_t)KK * DD * 4);
    p.g   = (float*)alloc((size_t)KK * 4);

    const int GB_N = (NN + 255) / 256;        // 196

    hipMemsetAsync(d_ws, 0, zbytes, stream);

    // ---- GAT layer 0: count -> scan -> (gemm0 || scatter0) -> fgatlite ----
    k_count0<<<2 * BCH, 256, 0, stream>>>(p);
    k_bsum<<<GB_N, 256, 0, stream>>>(p.degc_i, p.bsum, NN, NN);
    k_bscan<<<1, 256, 0, stream>>>(p.bsum, GB_N, p.boff, p.off0, NN);
    k_fscan0<<<GB_N, 256, 0, stream>>>(p);
    k_g0sc<<<G0B + GB_E + 1, 256, 0, stream>>>(p);
    k_fgatlite<<<NN / 4, 256, 0, stream>>>(p.off0, p.csr_src, p.el0, p.er0, p.q4,
                                           p.dsum, p.b0wc, p.hc, p.m0f, p.s0f);

    // ---- SAGPool: stream-ordered select (LDS-preagg radix, no grid barriers) ----
    k_score<<<GB_N, 256, 0, stream>>>(p);
    k_h0<<<HB, 1024, 0, stream>>>(p);
    k_rsel2<<<1, 1024, 0, stream>>>(p, 0);
    k_h1<<<HB, 1024, 0, stream>>>(p);
    k_rsel2<<<1, 1024, 0, stream>>>(p, 1);
    k_ties<<<1, 1024, 0, stream>>>(p);
    k_list<<<GB_N, 256, 0, stream>>>(p);

    // ---- GAT layer 1: fgatx -> gemm1 -> fgat2 (layer-0 CSR reused) ----
    k_fgatx<<<KK / 4, 256, 0, stream>>>(p.list, p.tscale, p.off0, p.csr_src,
                                        p.el0, p.er0, p.m0f, p.s0f, p.z0, p.b0, p.xk);
    k_gemm1<<<G1B, 256, 0, stream>>>(p);
    k_fgat2<<<KK / 4, 256, 0, stream>>>(p);
    k_ealpha1<<<GB_E, 256, 0, stream>>>(p);

    // ---- readout ----
    k_gmax<<<98, 256, 0, stream>>>(p);
    k_wsum<<<WSUM_BLOCKS, 256, 0, stream>>>(p);
    k_final<<<1, 64, 0, stream>>>(p);
}

// Round 7
// 532.632 us; speedup vs baseline: 1.6230x; 1.0884x over previous
//
#include <hip/hip_runtime.h>
#include <stdint.h>

#define NN 50000
#define EE 800000
#define FIN 256
#define HD 128
#define DD 32
#define KK 25000
#define SLOPEF 0.4f
#define NEGF (-1e9f)
#define ATT_OFF 34
#define STR_OFF (34 + EE * 4)
#define CW 128             // LDS-cached edges per node (deg ~Poisson(16); recompute fallback)

// counting-sort CSR build (layer 0 only; layer 1 reuses it via slot-filtering)
#define BCH 32             // edge chunks
#define EPC (EE / BCH)     // 25000 edges per chunk
#define NRQ 12500          // node-range quarter for count blocks (4 x 12500 = NN)

// ---------- helpers ----------
__device__ __forceinline__ unsigned fkey(float x) {
    unsigned u = __float_as_uint(x);
    return (u & 0x80000000u) ? ~u : (u | 0x80000000u);   // monotone float->uint
}
__device__ __forceinline__ float unfkey(unsigned k) {
    unsigned u = (k & 0x80000000u) ? (k ^ 0x80000000u) : ~k;
    return __uint_as_float(u);
}
__device__ __forceinline__ float lrelu(float v) { return v > 0.f ? v : SLOPEF * v; }

// ---------- pointer bundle ----------
struct P {
    // inputs
    const float *feature, *strength, *W0, *b0, *al0, *ar0, *Wc0, *bc0;
    const float *W1, *b1, *al1, *ar1, *gW, *gb, *cW, *cb;
    const int *src, *dst;
    // zeroed scratch
    double *Zacc, *racc;
    int *cnt;
    unsigned *gmaxk;
    unsigned *rs;                 // [0]=pivot,[1]=need,[2]=hi bin,[3]=hi remaining
    unsigned *binsHi, *binsLo;    // 65536 u32 bins each
    // other scratch
    unsigned *keys;
    unsigned char *degc_i, *degc_o;   // per-(chunk,node) u8 counts [BCH][NN]
    unsigned *cb0;                // per-(chunk,node) CSR base cursors
    int *dsum;                    // out-degree totals
    int *csr_src, *rank, *off0, *slot, *list, *bsum, *boff;
    float *z0, *el0, *er0, *q4, *m0f, *s0f, *b0wc, *hc, *xk, *z1;
    float *el1, *er1, *m1f, *s1f, *res, *g, *tscale;
    float *out;                   // d_out (float32)
};

// ---------- fp32 tiled GEMM body: C[M,128] = A[M,Kd] @ B[Kd,128] ----------
#define BM 128
#define BN 64
#define BK 16
__device__ void gemm_body(
    const float* __restrict__ A, const float* __restrict__ B, float* __restrict__ C,
    int M, int Kd,
    const float* __restrict__ al, const float* __restrict__ ar,
    float* __restrict__ el, float* __restrict__ er,
    const float* __restrict__ Wc, float* __restrict__ q4,
    int bx, int by) {
    __shared__ float As[BK][BM + 4];
    __shared__ float Bs[BK][BN];
    int bm = by * BM, bn = bx * BN;
    int tid = threadIdx.x;
    int tr = tid >> 4, tc = tid & 15;
    int lrow = tid >> 1;
    int arow = (bm + lrow < M) ? (bm + lrow) : -1;
    float acc[8][4] = {};
    for (int k0 = 0; k0 < Kd; k0 += BK) {
        {
            int col = (tid & 1) << 3;
            float4 v0 = {0.f,0.f,0.f,0.f}, v1 = {0.f,0.f,0.f,0.f};
            if (arow >= 0) {
                const float* ap = A + (size_t)arow * Kd + k0 + col;
                v0 = *(const float4*)ap; v1 = *(const float4*)(ap + 4);
            }
            As[col + 0][lrow] = v0.x; As[col + 1][lrow] = v0.y;
            As[col + 2][lrow] = v0.z; As[col + 3][lrow] = v0.w;
            As[col + 4][lrow] = v1.x; As[col + 5][lrow] = v1.y;
            As[col + 6][lrow] = v1.z; As[col + 7][lrow] = v1.w;
        }
        {
            int kr = tid >> 4, col = (tid & 15) << 2;
            float4 v = *(const float4*)(B + (size_t)(k0 + kr) * HD + bn + col);
            *(float4*)&Bs[kr][col] = v;
        }
        __syncthreads();
#pragma unroll
        for (int kk = 0; kk < BK; kk++) {
            float a[8], b[4];
#pragma unroll
            for (int i = 0; i < 8; i++) a[i] = As[kk][tr * 8 + i];
#pragma unroll
            for (int j = 0; j < 4; j++) b[j] = Bs[kk][tc * 4 + j];
#pragma unroll
            for (int i = 0; i < 8; i++)
#pragma unroll
                for (int j = 0; j < 4; j++) acc[i][j] = fmaf(a[i], b[j], acc[i][j]);
        }
        __syncthreads();
    }
#pragma unroll
    for (int i = 0; i < 8; i++) {
        int gr = bm + tr * 8 + i;
        if (gr < M) {
            float4 v = {acc[i][0], acc[i][1], acc[i][2], acc[i][3]};
            *(float4*)(C + (size_t)gr * HD + bn + tc * 4) = v;
        }
    }
    int head = bx * 2 + (tc >> 3);
    int dbase = (tc & 7) * 4;
    const float* alh = al + head * 32 + dbase;
    const float* arh = ar + head * 32 + dbase;
    float a0 = alh[0], a1 = alh[1], a2 = alh[2], a3 = alh[3];
    float r0 = arh[0], r1 = arh[1], r2 = arh[2], r3 = arh[3];
    float w0 = 0.f, w1 = 0.f, w2 = 0.f, w3 = 0.f;
    if (Wc) {
        const float* wch = Wc + head * 32 + dbase;
        w0 = wch[0]; w1 = wch[1]; w2 = wch[2]; w3 = wch[3];
    }
#pragma unroll
    for (int i = 0; i < 8; i++) {
        int gr = bm + tr * 8 + i;
        float pe = acc[i][0]*a0 + acc[i][1]*a1 + acc[i][2]*a2 + acc[i][3]*a3;
        float pr = acc[i][0]*r0 + acc[i][1]*r1 + acc[i][2]*r2 + acc[i][3]*r3;
        float pq = acc[i][0]*w0 + acc[i][1]*w1 + acc[i][2]*w2 + acc[i][3]*w3;
#pragma unroll
        for (int o = 1; o < 8; o <<= 1) {
            pe += __shfl_xor(pe, o); pr += __shfl_xor(pr, o); pq += __shfl_xor(pq, o);
        }
        if ((tc & 7) == 0 && gr < M) {
            el[gr * 4 + head] = pe; er[gr * 4 + head] = pr;
            if (Wc) q4[gr * 4 + head] = pq;
        }
    }
}

// ---------- layer-0 count: (chunk x node-quarter) u8 LDS histogram ----------
// 256 blocks (vs 64): each owns (chunk c, node range rq). Edges re-read 4x
// (L2-shared) but LDS is 12.5 KB and the device fills all CUs.
__global__ __launch_bounds__(256) void k_count0(P p) {
    __shared__ unsigned hist[NRQ / 4];        // 12500 u8 counters
    int blk = blockIdx.x;
    int isD = blk < 128;
    int c = blk & 31, rq = (blk >> 5) & 3;
    int nbase = rq * NRQ;
    for (int w = threadIdx.x; w < NRQ / 4; w += 256) hist[w] = 0u;
    __syncthreads();
    int j0 = c * EPC, j1 = j0 + EPC;
    if (isD) {
        for (int e = j0 + (int)threadIdx.x; e < j1; e += 256) {
            int d = p.dst[e] - nbase;
            if ((unsigned)d < (unsigned)NRQ) {
                unsigned sh = (unsigned)(d & 3) * 8u;
                unsigned old = atomicAdd(&hist[d >> 2], 1u << sh);
                p.rank[e] = (int)((old >> sh) & 0xffu);
            }
        }
    } else {
        for (int e = j0 + (int)threadIdx.x; e < j1; e += 256) {
            int s = p.src[e] - nbase;
            if ((unsigned)s < (unsigned)NRQ)
                atomicAdd(&hist[s >> 2], 1u << ((unsigned)(s & 3) * 8u));
        }
    }
    __syncthreads();
    unsigned* o32 = (unsigned*)((isD ? p.degc_i : p.degc_o) + (size_t)c * NN + nbase);
    for (int w = threadIdx.x; w < NRQ / 4; w += 256) o32[w] = hist[w];
}

// ---------- two-level exclusive scan over node totals (stream-ordered) ----------
__global__ __launch_bounds__(256) void k_bsum(const unsigned char* __restrict__ deg,
                                              int* __restrict__ bsum, int n, int nn) {
    int i = blockIdx.x * 256 + threadIdx.x;
    int v = 0;
    if (i < n) {
#pragma unroll
        for (int c = 0; c < BCH; c++) v += deg[(size_t)c * nn + i];
    }
    int lane = threadIdx.x & 63, w = threadIdx.x >> 6;
    __shared__ int ws[4];
#pragma unroll
    for (int o = 1; o < 64; o <<= 1) v += __shfl_xor(v, o);
    if (lane == 0) ws[w] = v;
    __syncthreads();
    if (threadIdx.x == 0) bsum[blockIdx.x] = ws[0] + ws[1] + ws[2] + ws[3];
}
__global__ __launch_bounds__(256) void k_bscan(const int* __restrict__ bsum, int nb,
                                               int* __restrict__ boff,
                                               int* __restrict__ off, int n) {
    __shared__ int ws[4];
    __shared__ int wo[5];
    int t = threadIdx.x;
    int v = (t < nb) ? bsum[t] : 0;
    int lane = t & 63, w = t >> 6;
    int incl = v;
    for (int o = 1; o < 64; o <<= 1) { int u = __shfl_up(incl, o); if (lane >= o) incl += u; }
    if (lane == 63) ws[w] = incl;
    __syncthreads();
    if (t == 0) { int a = 0; for (int i = 0; i < 4; i++) { wo[i] = a; a += ws[i]; } wo[4] = a; }
    __syncthreads();
    if (t < nb) boff[t] = wo[w] + incl - v;
    if (t == 0) off[n] = wo[4];
}
// final scan: off0 + per-chunk bases cb0 + out-degree totals dsum
__global__ __launch_bounds__(256) void k_fscan0(P p) {
    __shared__ int ws[4];
    __shared__ int wo[4];
    int i = blockIdx.x * 256 + threadIdx.x;
    int v = 0;
    if (i < NN) {
#pragma unroll
        for (int c = 0; c < BCH; c++) v += p.degc_i[(size_t)c * NN + i];
    }
    int lane = threadIdx.x & 63, w = threadIdx.x >> 6;
    int incl = v;
    for (int o = 1; o < 64; o <<= 1) { int u = __shfl_up(incl, o); if (lane >= o) incl += u; }
    if (lane == 63) ws[w] = incl;
    __syncthreads();
    if (threadIdx.x == 0) { int a = 0; for (int k = 0; k < 4; k++) { wo[k] = a; a += ws[k]; } }
    __syncthreads();
    if (i < NN) {
        int base = p.boff[blockIdx.x] + wo[w] + incl - v;
        p.off0[i] = base;
        unsigned run = (unsigned)base;
        int s = 0;
#pragma unroll
        for (int c = 0; c < BCH; c++) {
            p.cb0[(size_t)c * NN + i] = run;
            run += p.degc_i[(size_t)c * NN + i];
            s += p.degc_o[(size_t)c * NN + i];
        }
        p.dsum[i] = s;
    }
}

// ---------- CSR scatter0: OWN kernel (low VGPR -> 8 waves/SIMD latency hiding) ----------
#define GB_E 3125
__global__ __launch_bounds__(256) void k_scat0(P p) {
    int e = blockIdx.x * 256 + threadIdx.x;
    if (e >= EE) return;
    int c = e / EPC;
    int d = p.dst[e];
    unsigned pos = p.cb0[(size_t)c * NN + d] + (unsigned)p.rank[e];
    p.csr_src[pos] = p.src[e];
}

// ---------- gemm0 (+ b0wc prep micro-block) ----------
#define G0B 782            // 2 x 391 gemm blocks
__global__ __launch_bounds__(256) void k_gemm0(P p) {
    int blk = blockIdx.x;
    if (blk < G0B) {
        gemm_body(p.feature, p.W0, p.z0, NN, FIN, p.al0, p.ar0, p.el0, p.er0,
                  p.Wc0, p.q4, blk & 1, blk >> 1);
    } else {
        int l = threadIdx.x;
        if (l < 64) {
            float t = p.b0[l] * p.Wc0[l] + p.b0[l + 64] * p.Wc0[l + 64];
#pragma unroll
            for (int o = 1; o < 64; o <<= 1) t += __shfl_xor(t, o);
            if (l == 0) p.b0wc[0] = t;
        }
    }
}

// ---------- layer-0 softmax + SCALAR q-gather (all nodes) ----------
__global__ __launch_bounds__(256) void k_fgatlite(
    const int* __restrict__ off, const int* __restrict__ csrs,
    const float* __restrict__ el, const float* __restrict__ er,
    const float* __restrict__ q4, const int* __restrict__ dsum,
    const float* __restrict__ b0wc,
    float* __restrict__ hc, float* __restrict__ m0f, float* __restrict__ s0f) {
    int wv = threadIdx.x >> 6, lane = threadIdx.x & 63;
    int v = blockIdx.x * 4 + wv;
    int b = off[v], e = off[v + 1], deg = e - b;
    int h = lane >> 4, sub = lane & 15;
    float erh = er[(size_t)v * 4 + h];
    float m = NEGF;
    for (int li = sub; li < deg; li += 16) {
        int s = csrs[b + li];
        m = fmaxf(m, lrelu(el[(size_t)s * 4 + h] + erh));
    }
#pragma unroll
    for (int o = 1; o < 16; o <<= 1) m = fmaxf(m, __shfl_xor(m, o));
    float ssum = 0.f, hq = 0.f;
    for (int li = sub; li < deg; li += 16) {
        int s = csrs[b + li];
        float ex = expf(lrelu(el[(size_t)s * 4 + h] + erh) - m);
        ssum += ex;
        hq = fmaf(ex, q4[(size_t)s * 4 + h], hq);
    }
#pragma unroll
    for (int o = 1; o < 16; o <<= 1) { ssum += __shfl_xor(ssum, o); hq += __shfl_xor(hq, o); }
    if (sub == 0) { m0f[v * 4 + h] = m; s0f[v * 4 + h] = ssum; }
    float t = hq / fmaxf(ssum, 1e-16f);
    t += __shfl_xor(t, 16);
    t += __shfl_xor(t, 32);
    if (lane == 0)
        hc[v] = (t + b0wc[0]) / sqrtf(fmaxf((float)dsum[v], 1.f));
}

// ---------- SAGPool score -> keys ----------
__global__ __launch_bounds__(256) void k_score(P p) {
    int v = blockIdx.x * blockDim.x + threadIdx.x;
    if (v >= NN) return;
    int b = p.off0[v], en = p.off0[v + 1];
    float acc = 0.f;
    for (int i = b; i < en; i++) acc += p.hc[p.csr_src[i]];
    float dg = fmaxf((float)(en - b), 1.f);
    float sc = acc / sqrtf(dg) + p.bc0[0];
    p.keys[v] = fkey(sc);
}

// ---------- hi-16 histogram: per-block u16-packed LDS (two 64KB half-passes) ----------
#define HB 49              // ceil(NN/1024)
__global__ __launch_bounds__(1024) void k_h0(P p) {
    __shared__ unsigned hist[16384];     // 64 KB: 32768 bins u16-packed per half
    int i = blockIdx.x * 1024 + (int)threadIdx.x;
    unsigned key = (i < NN) ? p.keys[i] : 0xFFFFFFFFu;  // sentinel: never counted
    unsigned b16 = key >> 16;
#pragma unroll
    for (int half = 0; half < 2; half++) {
        for (int w = threadIdx.x; w < 16384; w += 1024) hist[w] = 0u;
        __syncthreads();
        if (i < NN && (int)(b16 >> 15) == half) {
            unsigned bb = b16 & 0x7FFFu;
            atomicAdd(&hist[bb >> 1], 1u << (16u * (bb & 1u)));
        }
        __syncthreads();
        for (int w = threadIdx.x; w < 16384; w += 1024) {
            unsigned hv = hist[w];
            unsigned lo = hv & 0xFFFFu, hi = hv >> 16;
            if (lo) atomicAdd(&p.binsHi[half * 32768 + 2 * w], lo);
            if (hi) atomicAdd(&p.binsHi[half * 32768 + 2 * w + 1], hi);
        }
        __syncthreads();
    }
}

// ---------- lo-16 histogram among hi-bin candidates ----------
__global__ __launch_bounds__(1024) void k_h1(P p) {
    __shared__ unsigned hist[16384];
    int i = blockIdx.x * 1024 + (int)threadIdx.x;
    unsigned hib = p.rs[2];
    unsigned key = (i < NN) ? p.keys[i] : 0u;
    int cand = (i < NN) && ((key >> 16) == hib);
    unsigned b16 = key & 0xFFFFu;
#pragma unroll
    for (int half = 0; half < 2; half++) {
        for (int w = threadIdx.x; w < 16384; w += 1024) hist[w] = 0u;
        __syncthreads();
        if (cand && (int)(b16 >> 15) == half) {
            unsigned bb = b16 & 0x7FFFu;
            atomicAdd(&hist[bb >> 1], 1u << (16u * (bb & 1u)));
        }
        __syncthreads();
        for (int w = threadIdx.x; w < 16384; w += 1024) {
            unsigned hv = hist[w];
            unsigned lo = hv & 0xFFFFu, hi = hv >> 16;
            if (lo) atomicAdd(&p.binsLo[half * 32768 + 2 * w], lo);
            if (hi) atomicAdd(&p.binsLo[half * 32768 + 2 * w + 1], hi);
        }
        __syncthreads();
    }
}

// ---------- radix pick: 1 block scans 65536 bins ----------
__global__ __launch_bounds__(1024) void k_rsel2(P p, int level) {
    const unsigned* bins = level ? p.binsLo : p.binsHi;
    int K = level ? (int)p.rs[3] : KK;
    __shared__ unsigned wsm[16];
    __shared__ unsigned wpre[17];
    int t = threadIdx.x;
    unsigned base = (unsigned)t * 64;
    const uint4* b4 = (const uint4*)(bins + base);
    unsigned S = 0;
#pragma unroll
    for (int i = 0; i < 16; i++) {
        uint4 u = b4[i];
        S += u.x + u.y + u.z + u.w;
    }
    int lane = t & 63, w = t >> 6;
    unsigned val = S;
    for (int o = 1; o < 64; o <<= 1) { unsigned u = __shfl_up(val, o); if (lane >= o) val += u; }
    if (lane == 63) wsm[w] = val;
    __syncthreads();
    if (t == 0) { unsigned a = 0; for (int i = 0; i < 16; i++) { wpre[i] = a; a += wsm[i]; } wpre[16] = a; }
    __syncthreads();
    unsigned incl = wpre[w] + val;
    unsigned running = wpre[16] - incl;    // keys in strictly higher bins
    for (int i = 63; i >= 0; i--) {
        unsigned c = bins[base + i];
        unsigned above = running;
        running += c;
        if ((int)above < K && (int)running >= K) {
            if (level == 0) { p.rs[2] = base + (unsigned)i; p.rs[3] = (unsigned)(K - (int)above); }
            else { p.rs[0] = (p.rs[2] << 16) | (base + (unsigned)i); p.rs[1] = (unsigned)(K - (int)above); }
        }
    }
}

// ---------- parallel tie counting (replaces 1-block k_ties) ----------
__global__ __launch_bounds__(256) void k_tcnt(P p) {
    __shared__ int ws[4];
    int v = blockIdx.x * 256 + (int)threadIdx.x;
    int flag = (v < NN && p.keys[v] == p.rs[0]) ? 1 : 0;
    unsigned long long m = __ballot(flag);
    int lane = threadIdx.x & 63, w = threadIdx.x >> 6;
    if (lane == 0) ws[w] = __popcll(m);
    __syncthreads();
    if (threadIdx.x == 0) p.bsum[blockIdx.x] = ws[0] + ws[1] + ws[2] + ws[3];
}

// ---------- list build: select + lowest-index tie ranks inline ----------
__global__ __launch_bounds__(256) void k_list(P p) {
    __shared__ int pre0;
    __shared__ int ws[4];
    int blk = blockIdx.x, tid = threadIdx.x;
    unsigned pivot = p.rs[0];
    int need = (int)p.rs[1];
    int v = blk * 256 + tid;
    unsigned k = (v < NN) ? p.keys[v] : 0u;
    int flag = (v < NN && k == pivot) ? 1 : 0;
    unsigned long long mask = __ballot(flag);
    int lane = tid & 63, w = tid >> 6;
    if (lane == 0) ws[w] = __popcll(mask);
    if (tid == 0) {
        int s = 0;
        for (int b2 = 0; b2 < blk; b2++) s += p.bsum[b2];
        pre0 = s;
    }
    __syncthreads();
    int woff = 0;
    for (int i = 0; i < w; i++) woff += ws[i];
    int rank = pre0 + woff + __popcll(mask & ((1ull << lane) - 1ull));
    if (v < NN) {
        int selv = (k > pivot) || (flag && rank < need);
        if (selv) {
            int idx = atomicAdd(p.cnt, 1);
            p.list[idx] = v;
            p.slot[v] = idx;
            p.tscale[idx] = tanhf(unfkey(k));
        } else {
            p.slot[v] = -1;
        }
    }
}

// ---------- full x for SELECTED nodes only ----------
__global__ __launch_bounds__(256) void k_fgatx(
    const int* __restrict__ list, const float* __restrict__ tscale,
    const int* __restrict__ off, const int* __restrict__ csrs,
    const float* __restrict__ el, const float* __restrict__ er,
    const float* __restrict__ m0f, const float* __restrict__ s0f,
    const float* __restrict__ z, const float* __restrict__ b0,
    float* __restrict__ xk) {
    __shared__ int ssrc[4][CW];
    __shared__ float sexp[4][CW][4];
    int wv = threadIdx.x >> 6, lane = threadIdx.x & 63;
    int i = blockIdx.x * 4 + wv;
    int v = list[i];
    int b = off[v], e = off[v + 1], deg = e - b;
    int h = lane >> 4, sub = lane & 15;
    float erh = er[(size_t)v * 4 + h];
    float mh = m0f[v * 4 + h];
    for (int li = sub; li < deg; li += 16) {
        int s = csrs[b + li];
        if (h == 0 && li < CW) ssrc[wv][li] = s;
        if (li < CW) sexp[wv][li][h] = expf(lrelu(el[(size_t)s * 4 + h] + erh) - mh);
    }
    __syncthreads();
    int h0 = lane >> 5, h1 = h0 + 2;
    float s0 = s0f[v * 4 + h0], s1 = s0f[v * 4 + h1];
    float m0 = m0f[v * 4 + h0], m1 = m0f[v * 4 + h1];
    float er0v = er[(size_t)v * 4 + h0], er1v = er[(size_t)v * 4 + h1];
    int c0 = lane, c1 = lane + 64;
    float acc0 = 0.f, acc1 = 0.f;
    for (int li = 0; li < deg; li++) {
        int s; float w0, w1;
        if (li < CW) {
            s = ssrc[wv][li];
            w0 = sexp[wv][li][h0]; w1 = sexp[wv][li][h1];
        } else {
            s = csrs[b + li];
            w0 = expf(lrelu(el[(size_t)s * 4 + h0] + er0v) - m0);
            w1 = expf(lrelu(el[(size_t)s * 4 + h1] + er1v) - m1);
        }
        int su = __builtin_amdgcn_readfirstlane(s);
        const float* zr = z + (size_t)su * HD;
        acc0 = fmaf(w0, zr[c0], acc0);
        acc1 = fmaf(w1, zr[c1], acc1);
    }
    float ts = tscale[i];
    float* xr = xk + (size_t)i * HD;
    xr[c0] = (acc0 / fmaxf(s0, 1e-16f) + b0[c0]) * ts;
    xr[c1] = (acc1 / fmaxf(s1, 1e-16f) + b0[c1]) * ts;
}

// ---------- pure gemm1 ----------
#define G1B 392
__global__ __launch_bounds__(256) void k_gemm1(P p) {
    gemm_body(p.xk, p.W1, p.z1, KK, HD, p.al1, p.ar1, p.el1, p.er1,
              nullptr, nullptr, blockIdx.x & 1, blockIdx.x >> 1);
}

// ---------- layer-1 fused GAT: reuses LAYER-0 CSR, filters by slot ----------
__global__ __launch_bounds__(256) void k_fgat2(P p) {
    __shared__ int ssrc[4][CW];
    __shared__ float sexp[4][CW][4];
    int wv = threadIdx.x >> 6, lane = threadIdx.x & 63;
    int i = blockIdx.x * 4 + wv;          // slot index
    int v = p.list[i];                    // original node id
    int b = p.off0[v], e = p.off0[v + 1], deg = e - b;
    int h = lane >> 4, sub = lane & 15;
    float4 er4 = *(const float4*)(p.er1 + (size_t)i * 4);
    float erh = ((const float*)&er4)[h];
    float m = NEGF;
    for (int li = sub; li < deg; li += 16) {
        int so = p.csr_src[b + li];
        int ss = p.slot[so];
        if (h == 0 && li < CW) ssrc[wv][li] = ss;
        if (ss >= 0) m = fmaxf(m, lrelu(p.el1[(size_t)ss * 4 + h] + erh));
    }
#pragma unroll
    for (int o = 1; o < 16; o <<= 1) m = fmaxf(m, __shfl_xor(m, o));
    float ssum = 0.f;
    for (int li = sub; li < deg; li += 16) {
        int so = p.csr_src[b + li];
        int ss = p.slot[so];
        float x = (ss >= 0) ? expf(lrelu(p.el1[(size_t)ss * 4 + h] + erh) - m) : 0.f;
        if (li < CW) sexp[wv][li][h] = x;
        ssum += x;
    }
#pragma unroll
    for (int o = 1; o < 16; o <<= 1) ssum += __shfl_xor(ssum, o);
    if (sub == 0) { p.m1f[i * 4 + h] = m; p.s1f[i * 4 + h] = ssum; }
    __syncthreads();
    int h0 = lane >> 5, h1 = h0 + 2;
    float m0 = __shfl(m, h0 << 4), m1 = __shfl(m, h1 << 4);
    float s0 = __shfl(ssum, h0 << 4), s1 = __shfl(ssum, h1 << 4);
    int c0 = lane, c1 = lane + 64;
    float acc0 = 0.f, acc1 = 0.f;
    for (int li = 0; li < deg; li++) {
        int s; float w0, w1;
        if (li < CW) {
            s = ssrc[wv][li];
            if (s < 0) continue;
            w0 = sexp[wv][li][h0]; w1 = sexp[wv][li][h1];
        } else {
            int so = p.csr_src[b + li];
            s = p.slot[so];
            if (s < 0) continue;
            w0 = expf(lrelu(p.el1[(size_t)s * 4 + h0] + ((const float*)&er4)[h0]) - m0);
            w1 = expf(lrelu(p.el1[(size_t)s * 4 + h1] + ((const float*)&er4)[h1]) - m1);
        }
        int su = __builtin_amdgcn_readfirstlane(s);
        const float* zr = p.z1 + (size_t)su * HD;
        acc0 = fmaf(w0, zr[c0], acc0);
        acc1 = fmaf(w1, zr[c1], acc1);
    }
    float xc0 = acc0 / fmaxf(s0, 1e-16f) + p.b1[c0];
    float xc1 = acc1 / fmaxf(s1, 1e-16f) + p.b1[c1];
    float t = xc0 + xc1;
    t += __shfl_xor(t, 32);
    float pg = 0.f;
    if (lane < 32) {
        float r = 0.25f * t;
        p.res[(size_t)i * 32 + lane] = r;
        pg = r * p.gW[lane];
    }
#pragma unroll
    for (int o = 1; o < 32; o <<= 1) pg += __shfl_xor(pg, o);
    if (lane == 0) p.g[i] = pg + p.gb[0];
}

// ---------- MERGED: per-edge alpha outputs || gmax (independent consumers of fgat2) ----------
__global__ __launch_bounds__(256) void k_eg(P p) {
    int blk = blockIdx.x;
    if (blk < GB_E) {
        int e = blk * 256 + (int)threadIdx.x;
        if (e >= EE) return;
        int ds = p.slot[p.src[e]], dd = p.slot[p.dst[e]];
        float a[4] = {0.f, 0.f, 0.f, 0.f};
        float st = 0.f;
        if (ds >= 0 && dd >= 0) {
            float4 es = *(const float4*)(p.el1 + ds * 4);
            float4 ed = *(const float4*)(p.er1 + dd * 4);
            float l[4] = {lrelu(es.x + ed.x), lrelu(es.y + ed.y), lrelu(es.z + ed.z), lrelu(es.w + ed.w)};
#pragma unroll
            for (int h = 0; h < 4; h++) {
                float m = p.m1f[dd * 4 + h];
                float ex = expf(l[h] - m);
                a[h] = ex / fmaxf(p.s1f[dd * 4 + h], 1e-16f);
            }
            st = p.strength[e];
        }
        float* o = p.out + ATT_OFF + (size_t)e * 4;
        *(float2*)(o) = make_float2(a[0], a[1]);
        *(float2*)(o + 2) = make_float2(a[2], a[3]);
        p.out[STR_OFF + e] = st;
    } else {
        __shared__ float red[256];
        int t = threadIdx.x;
        float m = -3.4e38f;
        for (int i = (blk - GB_E) * 256 + t; i < KK; i += 98 * 256) m = fmaxf(m, p.g[i]);
        red[t] = m;
        __syncthreads();
        for (int o = 128; o > 0; o >>= 1) { if (t < o) red[t] = fmaxf(red[t], red[t + o]); __syncthreads(); }
        if (t == 0) atomicMax(p.gmaxk, fkey(red[0]));   // memset-0 identity ok
    }
}

#define WSUM_BLOCKS 104
__global__ __launch_bounds__(256) void k_wsum(P p) {
    __shared__ double vred[256];
    __shared__ double zred[8];
    int t = threadIdx.x, il = t >> 5, d = t & 31;
    float gm = unfkey(*p.gmaxk);
    double accv = 0.0, accw = 0.0;
    for (int i = blockIdx.x * 8 + il; i < KK; i += WSUM_BLOCKS * 8) {
        float w = expf(p.g[i] - gm);
        accv += (double)(w * p.res[(size_t)i * 32 + d]);
        if (d == 0) accw += (double)w;
    }
    vred[t] = accv;
    if (d == 0) zred[il] = accw;
    __syncthreads();
    if (il == 0) {
        double s = 0;
#pragma unroll
        for (int k2 = 0; k2 < 8; k2++) s += vred[k2 * 32 + d];
        atomicAdd(&p.racc[d], s);
    }
    if (t == 32) {
        double z2 = 0;
#pragma unroll
        for (int k2 = 0; k2 < 8; k2++) z2 += zred[k2];
        atomicAdd(p.Zacc, z2);
    }
}
__global__ void k_final(P p) {
    __shared__ float rb[32];
    int t = threadIdx.x;
    double Z = *p.Zacc;
    if (t < 32) {
        float r = (float)(p.racc[t] / Z);
        p.out[t] = r;
        rb[t] = r;
    }
    __syncthreads();
    if (t < 2) {
        float s = 0.f;
        for (int d = 0; d < 32; d++) s += rb[d] * p.cW[d * 2 + t];
        p.out[32 + t] = s + p.cb[t];
    }
}

// ---------- host ----------
extern "C" void kernel_launch(void* const* d_in, const int* in_sizes, int n_in,
                              void* d_out, int out_size, void* d_ws, size_t ws_size,
                              hipStream_t stream) {
    (void)in_sizes; (void)n_in; (void)out_size; (void)ws_size;
    P p;
    p.feature  = (const float*)d_in[0];
    p.strength = (const float*)d_in[1];
    p.W0  = (const float*)d_in[2];  p.b0  = (const float*)d_in[3];
    p.al0 = (const float*)d_in[4];  p.ar0 = (const float*)d_in[5];
    p.Wc0 = (const float*)d_in[6];  p.bc0 = (const float*)d_in[7];
    p.W1  = (const float*)d_in[8];  p.b1  = (const float*)d_in[9];
    p.al1 = (const float*)d_in[10]; p.ar1 = (const float*)d_in[11];
    p.gW  = (const float*)d_in[12]; p.gb  = (const float*)d_in[13];
    p.cW  = (const float*)d_in[14]; p.cb  = (const float*)d_in[15];
    p.src = (const int*)d_in[16];   p.dst = (const int*)d_in[17];
    p.out = (float*)d_out;

    char* ws = (char*)d_ws;
    size_t off = 0;
    auto alloc = [&](size_t bytes) -> void* {
        void* r = ws + off;
        off = (off + bytes + 255) & ~(size_t)255;
        return r;
    };
    // ---- zeroed region (must stay first/contiguous) ----
    p.Zacc  = (double*)alloc(8);
    p.racc  = (double*)alloc(32 * 8);
    p.cnt   = (int*)alloc(4);
    p.gmaxk = (unsigned*)alloc(4);
    p.rs    = (unsigned*)alloc(16);
    p.binsHi = (unsigned*)alloc(65536 * 4);
    p.binsLo = (unsigned*)alloc(65536 * 4);
    size_t zbytes = off;
    // ---- big buffers (fully overwritten each run) ----
    p.degc_i = (unsigned char*)alloc((size_t)BCH * NN);
    p.degc_o = (unsigned char*)alloc((size_t)BCH * NN);
    p.cb0 = (unsigned*)alloc((size_t)BCH * NN * 4);
    p.dsum = (int*)alloc((size_t)NN * 4);
    p.z0 = (float*)alloc((size_t)NN * HD * 4);
    p.xk = (float*)alloc((size_t)KK * HD * 4);
    p.z1 = (float*)alloc((size_t)KK * HD * 4);
    p.csr_src = (int*)alloc((size_t)EE * 4);
    p.rank    = (int*)alloc((size_t)EE * 4);
    p.el0 = (float*)alloc((size_t)NN * 4 * 4);
    p.er0 = (float*)alloc((size_t)NN * 4 * 4);
    p.q4  = (float*)alloc((size_t)NN * 4 * 4);
    p.m0f = (float*)alloc((size_t)NN * 4 * 4);
    p.s0f = (float*)alloc((size_t)NN * 4 * 4);
    p.b0wc = (float*)alloc(4);
    p.off0 = (int*)alloc((size_t)(NN + 1) * 4);
    p.bsum = (int*)alloc(256 * 4);
    p.boff = (int*)alloc(256 * 4);
    p.hc    = (float*)alloc((size_t)NN * 4);
    p.keys  = (unsigned*)alloc((size_t)NN * 4);
    p.slot  = (int*)alloc((size_t)NN * 4);
    p.list  = (int*)alloc((size_t)KK * 4);
    p.tscale = (float*)alloc((size_t)KK * 4);
    p.el1 = (float*)alloc((size_t)KK * 4 * 4);
    p.er1 = (float*)alloc((size_t)KK * 4 * 4);
    p.m1f = (float*)alloc((size_t)KK * 4 * 4);
    p.s1f = (float*)alloc((size_t)KK * 4 * 4);
    p.res = (float*)alloc((size_t)KK * DD * 4);
    p.g   = (float*)alloc((size_t)KK * 4);

    const int GB_N = (NN + 255) / 256;        // 196

    hipMemsetAsync(d_ws, 0, zbytes, stream);

    // ---- GAT layer 0: count -> scan -> scatter0 -> gemm0 -> fgatlite ----
    k_count0<<<256, 256, 0, stream>>>(p);
    k_bsum<<<GB_N, 256, 0, stream>>>(p.degc_i, p.bsum, NN, NN);
    k_bscan<<<1, 256, 0, stream>>>(p.bsum, GB_N, p.boff, p.off0, NN);
    k_fscan0<<<GB_N, 256, 0, stream>>>(p);
    k_scat0<<<GB_E, 256, 0, stream>>>(p);
    k_gemm0<<<G0B + 1, 256, 0, stream>>>(p);
    k_fgatlite<<<NN / 4, 256, 0, stream>>>(p.off0, p.csr_src, p.el0, p.er0, p.q4,
                                           p.dsum, p.b0wc, p.hc, p.m0f, p.s0f);

    // ---- SAGPool: stream-ordered select ----
    k_score<<<GB_N, 256, 0, stream>>>(p);
    k_h0<<<HB, 1024, 0, stream>>>(p);
    k_rsel2<<<1, 1024, 0, stream>>>(p, 0);
    k_h1<<<HB, 1024, 0, stream>>>(p);
    k_rsel2<<<1, 1024, 0, stream>>>(p, 1);
    k_tcnt<<<GB_N, 256, 0, stream>>>(p);
    k_list<<<GB_N, 256, 0, stream>>>(p);

    // ---- GAT layer 1: fgatx -> gemm1 -> fgat2 (layer-0 CSR reused) ----
    k_fgatx<<<KK / 4, 256, 0, stream>>>(p.list, p.tscale, p.off0, p.csr_src,
                                        p.el0, p.er0, p.m0f, p.s0f, p.z0, p.b0, p.xk);
    k_gemm1<<<G1B, 256, 0, stream>>>(p);
    k_fgat2<<<KK / 4, 256, 0, stream>>>(p);

    // ---- edge outputs || gmax, then readout ----
    k_eg<<<GB_E + 98, 256, 0, stream>>>(p);
    k_wsum<<<WSUM_BLOCKS, 256, 0, stream>>>(p);
    k_final<<<1, 64, 0, stream>>>(p);
}